// Round 1
// baseline (2493.701 us; speedup 1.0000x reference)
//
#include <hip/hip_runtime.h>
#include <math.h>

// Problem constants
// S=64 segments, B=256 atoms, N=S*B=16384 rows, D=128, H=8, HD=16, DFF=2048, NL=6

// ---------------------------------------------------------------------------
// lin0: x[n,d] = relu(data[n,:3] @ w[d,:3] + b[d])
// ---------------------------------------------------------------------------
__global__ __launch_bounds__(256) void lin0_kernel(
    const float* __restrict__ data, const float* __restrict__ w,
    const float* __restrict__ b, float* __restrict__ x) {
  int i = blockIdx.x * 256 + threadIdx.x;   // over N*128 = 2M
  int n = i >> 7, d = i & 127;
  float v = b[d] + data[n * 3 + 0] * w[d * 3 + 0]
                 + data[n * 3 + 1] * w[d * 3 + 1]
                 + data[n * 3 + 2] * w[d * 3 + 2];
  x[i] = fmaxf(v, 0.0f);
}

// ---------------------------------------------------------------------------
// Generic fp32 GEMM: C[N,M] = A[N,K] @ Bw[M,K]^T + bias (+C resid) (+relu)
// block = 64x64 tile of C, 256 threads, 4x4 micro-tile, BK=16.
// LDS layout transposed [BK][68] so fragment reads are contiguous (b128-able),
// 68 = 17*4 keeps rows 16B-aligned; writes land 2-way max (free on gfx950).
// ---------------------------------------------------------------------------
template <bool RELU, bool RESID>
__global__ __launch_bounds__(256) void gemm64(
    const float* __restrict__ A, const float* __restrict__ Bw,
    const float* __restrict__ bias, float* __restrict__ C,
    int K, int M) {
  __shared__ float As[16][68];
  __shared__ float Bs[16][68];
  int tid = threadIdx.x;
  int tx = tid & 15, ty = tid >> 4;
  int rowBase = blockIdx.x * 64;
  int colBase = blockIdx.y * 64;
  const float* Ab = A + (long)rowBase * K;
  const float* Bb = Bw + (long)colBase * K;
  float acc[4][4] = {};
  for (int k0 = 0; k0 < K; k0 += 16) {
#pragma unroll
    for (int i = 0; i < 4; i++) {
      int idx = tid + i * 256;
      int r = idx >> 4, kk = idx & 15;
      As[kk][r] = Ab[r * K + k0 + kk];
      Bs[kk][r] = Bb[r * K + k0 + kk];
    }
    __syncthreads();
#pragma unroll
    for (int kk = 0; kk < 16; kk++) {
      float ar[4], br[4];
#pragma unroll
      for (int i = 0; i < 4; i++) ar[i] = As[kk][ty * 4 + i];
#pragma unroll
      for (int j = 0; j < 4; j++) br[j] = Bs[kk][tx * 4 + j];
#pragma unroll
      for (int i = 0; i < 4; i++)
#pragma unroll
        for (int j = 0; j < 4; j++) acc[i][j] += ar[i] * br[j];
    }
    __syncthreads();
  }
#pragma unroll
  for (int i = 0; i < 4; i++) {
    int r = rowBase + ty * 4 + i;
#pragma unroll
    for (int j = 0; j < 4; j++) {
      int ci = colBase + tx * 4 + j;
      float v = acc[i][j] + bias[ci];
      if (RESID) v += C[(long)r * M + ci];
      if (RELU) v = fmaxf(v, 0.0f);
      C[(long)r * M + ci] = v;
    }
  }
}

// ---------------------------------------------------------------------------
// LayerNorm in place over last dim (128). One wave per row, 4 rows per block.
// ---------------------------------------------------------------------------
__global__ __launch_bounds__(256) void ln_kernel(
    float* __restrict__ x, const float* __restrict__ g,
    const float* __restrict__ b) {
  int lane = threadIdx.x & 63;
  int row = blockIdx.x * 4 + (threadIdx.x >> 6);
  float* xr = x + (long)row * 128;
  float x0 = xr[lane], x1 = xr[lane + 64];
  float s = x0 + x1;
#pragma unroll
  for (int off = 32; off; off >>= 1) s += __shfl_xor(s, off, 64);
  float mean = s * 0.0078125f;
  float d0 = x0 - mean, d1 = x1 - mean;
  float v = d0 * d0 + d1 * d1;
#pragma unroll
  for (int off = 32; off; off >>= 1) v += __shfl_xor(v, off, 64);
  float inv = rsqrtf(v * 0.0078125f + 1e-5f);
  xr[lane]      = d0 * inv * g[lane] + b[lane];
  xr[lane + 64] = d1 * inv * g[lane + 64] + b[lane + 64];
}

// ---------------------------------------------------------------------------
// Attention for one (b,h): scores[64x64] = QK^T/4, softmax over t, @V.
// qkv layout: [n=s*256+b][384] with q=0:128, k=128:256, v=256:384, head h at
// cols h*16..h*16+15 of each. ao layout: [n][128].
// ---------------------------------------------------------------------------
__global__ __launch_bounds__(256) void attn_kernel(
    const float* __restrict__ qkv, float* __restrict__ ao) {
  __shared__ float Qs[64][17], Ks[64][17], Vs[64][17];
  __shared__ float SC[64][65];
  int tid = threadIdx.x;
  int b = blockIdx.x & 255;
  int h = blockIdx.x >> 8;
  const float* base = qkv + b * 384 + h * 16;
#pragma unroll
  for (int i = 0; i < 4; i++) {
    int idx = tid + i * 256;
    int s = idx >> 4, d = idx & 15;
    const float* p = base + s * (256 * 384);
    Qs[s][d] = p[d];
    Ks[s][d] = p[128 + d];
    Vs[s][d] = p[256 + d];
  }
  __syncthreads();
#pragma unroll
  for (int i = 0; i < 16; i++) {
    int e = tid + i * 256;
    int s = e >> 6, t = e & 63;
    float acc = 0.f;
#pragma unroll
    for (int d = 0; d < 16; d++) acc += Qs[s][d] * Ks[t][d];
    SC[s][t] = acc * 0.25f;  // 1/sqrt(16)
  }
  __syncthreads();
  if (tid < 64) {
    float m = -1e30f;
    for (int t = 0; t < 64; t++) m = fmaxf(m, SC[tid][t]);
    float sum = 0.f;
    for (int t = 0; t < 64; t++) {
      float p = expf(SC[tid][t] - m);
      SC[tid][t] = p;
      sum += p;
    }
    float r = 1.0f / sum;
    for (int t = 0; t < 64; t++) SC[tid][t] *= r;
  }
  __syncthreads();
#pragma unroll
  for (int i = 0; i < 4; i++) {
    int o = tid + i * 256;
    int s = o >> 4, d = o & 15;
    float acc = 0.f;
    for (int t = 0; t < 64; t++) acc += SC[s][t] * Vs[t][d];
    ao[(s * 256 + b) * 128 + h * 16 + d] = acc;
  }
}

// ---------------------------------------------------------------------------
// Set2Set (6 steps) + memory LSTM + lin1 + lin3. One block per segment s.
// x: [64 segments][256 atoms][128]. Writes out[0:64]=v, [64:8256]=hx,
// [8256:16448]=cx.
// ---------------------------------------------------------------------------
__global__ __launch_bounds__(256) void s2s_kernel(
    const float* __restrict__ x,
    const float* __restrict__ wih, const float* __restrict__ whh,
    const float* __restrict__ bih, const float* __restrict__ bhh,
    const float* __restrict__ mwih, const float* __restrict__ mwhh,
    const float* __restrict__ mbih, const float* __restrict__ mbhh,
    const float* __restrict__ l1w, const float* __restrict__ l1b,
    const float* __restrict__ l3w, const float* __restrict__ l3b,
    float* __restrict__ out) {
  __shared__ __align__(16) float h[128];
  __shared__ __align__(16) float c[128];
  __shared__ __align__(16) float qs[256];
  __shared__ __align__(16) float gates[512];
  __shared__ __align__(16) float aw[256];
  __shared__ __align__(16) float red[256];
  int s = blockIdx.x, tid = threadIdx.x;
  const float* xs = x + s * 256 * 128;
  if (tid < 128) { h[tid] = 0.f; c[tid] = 0.f; }
  qs[tid] = 0.f;
  __syncthreads();
  for (int step = 0; step < 6; step++) {
    // gates = q_star @ wih^T + bih + h @ whh^T + bhh   (order i,f,g,o)
    for (int g = tid; g < 512; g += 256) {
      float acc = bih[g] + bhh[g];
      const float4* w4 = (const float4*)(wih + g * 256);
      const float4* q4 = (const float4*)qs;
      for (int k = 0; k < 64; k++) {
        float4 a = w4[k], bb = q4[k];
        acc += a.x * bb.x + a.y * bb.y + a.z * bb.z + a.w * bb.w;
      }
      const float4* u4 = (const float4*)(whh + g * 128);
      const float4* h4 = (const float4*)h;
      for (int k = 0; k < 32; k++) {
        float4 a = u4[k], bb = h4[k];
        acc += a.x * bb.x + a.y * bb.y + a.z * bb.z + a.w * bb.w;
      }
      gates[g] = acc;
    }
    __syncthreads();
    if (tid < 128) {
      float ig = 1.f / (1.f + expf(-gates[tid]));
      float fg = 1.f / (1.f + expf(-gates[128 + tid]));
      float gg = tanhf(gates[256 + tid]);
      float og = 1.f / (1.f + expf(-gates[384 + tid]));
      float cn = fg * c[tid] + ig * gg;
      c[tid] = cn;
      h[tid] = og * tanhf(cn);
    }
    __syncthreads();
    // e[n] = x[s,n,:] . h ; softmax over n ; r = sum a[n] x[s,n,:]
    float e = 0.f;
    {
      const float4* x4 = (const float4*)(xs + tid * 128);
      const float4* h4 = (const float4*)h;
      for (int k = 0; k < 32; k++) {
        float4 a = x4[k], bb = h4[k];
        e += a.x * bb.x + a.y * bb.y + a.z * bb.z + a.w * bb.w;
      }
    }
    red[tid] = e;
    __syncthreads();
    for (int off = 128; off; off >>= 1) {
      if (tid < off) red[tid] = fmaxf(red[tid], red[tid + off]);
      __syncthreads();
    }
    float m = red[0];
    __syncthreads();
    float ex = expf(e - m);
    red[tid] = ex;
    __syncthreads();
    for (int off = 128; off; off >>= 1) {
      if (tid < off) red[tid] += red[tid + off];
      __syncthreads();
    }
    float inv = 1.f / red[0];
    __syncthreads();
    aw[tid] = ex * inv;
    __syncthreads();
    if (tid < 128) {
      qs[tid] = h[tid];
    } else {
      int d = tid - 128;
      float r = 0.f;
      for (int n = 0; n < 256; n++) r += aw[n] * xs[n * 128 + d];
      qs[128 + d] = r;
    }
    __syncthreads();
  }
  // memory LSTM, zero initial state: gates = q_star @ mwih^T + mbih + mbhh
  for (int g = tid; g < 512; g += 256) {
    float acc = mbih[g] + mbhh[g];
    const float4* w4 = (const float4*)(mwih + g * 256);
    const float4* q4 = (const float4*)qs;
    for (int k = 0; k < 64; k++) {
      float4 a = w4[k], bb = q4[k];
      acc += a.x * bb.x + a.y * bb.y + a.z * bb.z + a.w * bb.w;
    }
    gates[g] = acc;
  }
  __syncthreads();
  if (tid < 128) {
    float ig = 1.f / (1.f + expf(-gates[tid]));
    float gg = tanhf(gates[256 + tid]);
    float og = 1.f / (1.f + expf(-gates[384 + tid]));
    float cx = ig * gg;              // f*0 + i*tanh(g)
    float hx = og * tanhf(cx);
    h[tid] = hx;
    out[64 + s * 128 + tid] = hx;
    out[64 + 8192 + s * 128 + tid] = cx;
  }
  __syncthreads();
  if (tid < 128) {
    float acc = l1b[tid];
    const float4* w4 = (const float4*)(l1w + tid * 128);
    const float4* h4 = (const float4*)h;
    for (int k = 0; k < 32; k++) {
      float4 a = w4[k], bb = h4[k];
      acc += a.x * bb.x + a.y * bb.y + a.z * bb.z + a.w * bb.w;
    }
    aw[tid] = fmaxf(acc, 0.f);
  }
  __syncthreads();
  float p = (tid < 128) ? aw[tid] * l3w[tid] : 0.f;
  red[tid] = p;
  __syncthreads();
  for (int off = 128; off; off >>= 1) {
    if (tid < off) red[tid] += red[tid + off];
    __syncthreads();
  }
  if (tid == 0) out[s] = red[0] + l3b[0];
}

// ---------------------------------------------------------------------------
extern "C" void kernel_launch(void* const* d_in, const int* in_sizes, int n_in,
                              void* d_out, int out_size, void* d_ws,
                              size_t ws_size, hipStream_t stream) {
  const float* data       = (const float*)d_in[0];
  const float* lin0_w     = (const float*)d_in[1];
  const float* lin0_b     = (const float*)d_in[2];
  const float* attn_in_w  = (const float*)d_in[3];
  const float* attn_in_b  = (const float*)d_in[4];
  const float* attn_out_w = (const float*)d_in[5];
  const float* attn_out_b = (const float*)d_in[6];
  const float* ln1_g      = (const float*)d_in[7];
  const float* ln1_b      = (const float*)d_in[8];
  const float* ff_w1      = (const float*)d_in[9];
  const float* ff_b1      = (const float*)d_in[10];
  const float* ff_w2      = (const float*)d_in[11];
  const float* ff_b2      = (const float*)d_in[12];
  const float* ln2_g      = (const float*)d_in[13];
  const float* ln2_b      = (const float*)d_in[14];
  const float* s2s_wih    = (const float*)d_in[15];
  const float* s2s_whh    = (const float*)d_in[16];
  const float* s2s_bih    = (const float*)d_in[17];
  const float* s2s_bhh    = (const float*)d_in[18];
  const float* mem_wih    = (const float*)d_in[19];
  const float* mem_whh    = (const float*)d_in[20];
  const float* mem_bih    = (const float*)d_in[21];
  const float* mem_bhh    = (const float*)d_in[22];
  const float* lin1_w     = (const float*)d_in[23];
  const float* lin1_b     = (const float*)d_in[24];
  const float* lin3_w     = (const float*)d_in[25];
  const float* lin3_b     = (const float*)d_in[26];
  float* out = (float*)d_out;

  // Workspace layout (floats): x[2M] | qkv[6M] | ao[2M] | (ff, maybe)
  float* x   = (float*)d_ws;
  float* qkv = x + 16384 * 128;
  float* ao  = qkv + 16384 * 384;
  size_t base_floats = (size_t)16384 * 128 + (size_t)16384 * 384 + (size_t)16384 * 128;
  bool full_ff = ws_size >= (base_floats + (size_t)16384 * 2048) * sizeof(float);
  float* ffbuf = full_ff ? (ao + 16384 * 128) : qkv;  // alias qkv when chunking
  int crow = full_ff ? 16384 : 2048;                  // FFN row chunk
  int nchunk = 16384 / crow;

  lin0_kernel<<<8192, 256, 0, stream>>>(data, lin0_w, lin0_b, x);

  for (int l = 0; l < 6; l++) {
    // qkv = x @ Wqkv^T + b
    gemm64<false, false><<<dim3(256, 6), 256, 0, stream>>>(
        x, attn_in_w + l * 384 * 128, attn_in_b + l * 384, qkv, 128, 384);
    // per-(b,h) SDPA
    attn_kernel<<<2048, 256, 0, stream>>>(qkv, ao);
    // x = x + ao @ Wout^T + b  (in-place residual)
    gemm64<false, true><<<dim3(256, 2), 256, 0, stream>>>(
        ao, attn_out_w + l * 128 * 128, attn_out_b + l * 128, x, 128, 128);
    ln_kernel<<<4096, 256, 0, stream>>>(x, ln1_g + l * 128, ln1_b + l * 128);
    // FFN (chunked over rows if workspace is small; ff aliases qkv then)
    for (int ck = 0; ck < nchunk; ck++) {
      float* xc = x + (size_t)ck * crow * 128;
      gemm64<true, false><<<dim3(crow / 64, 32), 256, 0, stream>>>(
          xc, ff_w1 + l * 2048 * 128, ff_b1 + l * 2048, ffbuf, 128, 2048);
      gemm64<false, true><<<dim3(crow / 64, 2), 256, 0, stream>>>(
          ffbuf, ff_w2 + l * 128 * 2048, ff_b2 + l * 128, xc, 2048, 128);
    }
    ln_kernel<<<4096, 256, 0, stream>>>(x, ln2_g + l * 128, ln2_b + l * 128);
  }

  s2s_kernel<<<64, 256, 0, stream>>>(
      x, s2s_wih, s2s_whh, s2s_bih, s2s_bhh,
      mem_wih, mem_whh, mem_bih, mem_bhh,
      lin1_w, lin1_b, lin3_w, lin3_b, out);
}

// Round 2
// 1046.010 us; speedup vs baseline: 2.3840x; 2.3840x over previous
//
#include <hip/hip_runtime.h>
#include <math.h>

// S=64 segments(seq), B=256 atoms(batch), N=16384 rows, D=128, H=8, HD=16,
// DFF=2048, NL=6.  All heavy GEMMs run as bf16 MFMA (16x16x32), fp32 accum.

typedef __attribute__((ext_vector_type(8))) short bf16x8;
typedef __attribute__((ext_vector_type(4))) float f32x4;

__device__ __forceinline__ unsigned short f2bf(float f) {
  union { float f; unsigned u; } x; x.f = f;
  unsigned r = x.u + 0x7fff + ((x.u >> 16) & 1);
  return (unsigned short)(r >> 16);
}
__device__ __forceinline__ float bf2f(unsigned short u) {
  union { unsigned u; float f; } x; x.u = ((unsigned)u) << 16;
  return x.f;
}
__device__ __forceinline__ float sigf(float x) { return 1.f / (1.f + expf(-x)); }

// async 16B global->LDS. LDS dest is wave-uniform base + lane*16.
__device__ __forceinline__ void gl2lds16(const void* g, void* l) {
  __builtin_amdgcn_global_load_lds(
      (const __attribute__((address_space(1))) unsigned int*)g,
      (__attribute__((address_space(3))) unsigned int*)l, 16, 0, 0);
}

// ---------------------------------------------------------------------------
// weight fp32 -> bf16 conversion (all 6 layers, 4 arrays), one kernel.
// sizes: aiw 294912, aow 98304, w1 1572864, w2 1572864 -> total 3538944
// ---------------------------------------------------------------------------
__global__ __launch_bounds__(256) void convw_kernel(
    const float* __restrict__ aiw, const float* __restrict__ aow,
    const float* __restrict__ w1, const float* __restrict__ w2,
    unsigned short* __restrict__ o0, unsigned short* __restrict__ o1,
    unsigned short* __restrict__ o2, unsigned short* __restrict__ o3) {
  int i = blockIdx.x * 256 + threadIdx.x;
  if (i < 294912) {
    o0[i] = f2bf(aiw[i]);
  } else if (i < 393216) {
    int j = i - 294912; o1[j] = f2bf(aow[j]);
  } else if (i < 1966080) {
    int j = i - 393216; o2[j] = f2bf(w1[j]);
  } else {
    int j = i - 1966080; o3[j] = f2bf(w2[j]);
  }
}

// ---------------------------------------------------------------------------
// lin0: x = relu(data @ w^T + b), writes fp32 x and bf16 xb
// ---------------------------------------------------------------------------
__global__ __launch_bounds__(256) void lin0_kernel(
    const float* __restrict__ data, const float* __restrict__ w,
    const float* __restrict__ b, float* __restrict__ x,
    unsigned short* __restrict__ xb) {
  int i = blockIdx.x * 256 + threadIdx.x;
  int n = i >> 7, d = i & 127;
  float v = b[d] + data[n * 3 + 0] * w[d * 3 + 0]
                 + data[n * 3 + 1] * w[d * 3 + 1]
                 + data[n * 3 + 2] * w[d * 3 + 2];
  v = fmaxf(v, 0.0f);
  x[i] = v;
  xb[i] = f2bf(v);
}

// ---------------------------------------------------------------------------
// MFMA GEMM, 128x128 tile: out_bf16[N,M] = (relu?)(A[N,K] @ W[M,K]^T + bias)
// A, W bf16 row-major (K contiguous). 256 threads = 4 waves (2x2), each wave
// 64x64 = 4x4 mfma tiles. BK=64. LDS chunk-swizzle kq^=(row&7) makes staging
// AND ds_read_b128 fragment reads bank-conflict-free.
// ---------------------------------------------------------------------------
template <bool RELU>
__global__ __launch_bounds__(256) void gemm128(
    const unsigned short* __restrict__ A, const unsigned short* __restrict__ W,
    const float* __restrict__ bias, unsigned short* __restrict__ out,
    int K, int M) {
  __shared__ __align__(16) char As[128 * 128];
  __shared__ __align__(16) char Bs[128 * 128];
  int tid = threadIdx.x;
  int w = tid >> 6, lane = tid & 63;
  int wr = w >> 1, wc = w & 1;
  int rowBase = blockIdx.x * 128, colBase = blockIdx.y * 128;
  f32x4 acc[4][4];
#pragma unroll
  for (int i = 0; i < 4; i++)
#pragma unroll
    for (int j = 0; j < 4; j++) acc[i][j] = (f32x4){0.f, 0.f, 0.f, 0.f};

  int r8 = lane >> 3;       // row within 8-row issue
  int gq = (lane & 7) ^ r8; // swizzled global 16B-chunk index
  int fr = lane & 15, fq = lane >> 4;

  for (int k0 = 0; k0 < K; k0 += 64) {
#pragma unroll
    for (int i = 0; i < 4; i++) {
      int issue = w * 4 + i;
      int row = issue * 8 + r8;
      gl2lds16(A + (size_t)(rowBase + row) * K + k0 + gq * 8, As + issue * 1024);
      gl2lds16(W + (size_t)(colBase + row) * K + k0 + gq * 8, Bs + issue * 1024);
    }
    __syncthreads();
#pragma unroll
    for (int ks = 0; ks < 2; ks++) {
      bf16x8 af[4], bfr[4];
#pragma unroll
      for (int mi = 0; mi < 4; mi++) {
        int row = wr * 64 + mi * 16 + fr;
        int kq = ks * 4 + fq;
        af[mi] = *(const bf16x8*)(As + row * 128 + ((kq ^ (row & 7)) * 16));
      }
#pragma unroll
      for (int ni = 0; ni < 4; ni++) {
        int row = wc * 64 + ni * 16 + fr;
        int kq = ks * 4 + fq;
        bfr[ni] = *(const bf16x8*)(Bs + row * 128 + ((kq ^ (row & 7)) * 16));
      }
#pragma unroll
      for (int mi = 0; mi < 4; mi++)
#pragma unroll
        for (int ni = 0; ni < 4; ni++)
          acc[mi][ni] = __builtin_amdgcn_mfma_f32_16x16x32_bf16(
              af[mi], bfr[ni], acc[mi][ni], 0, 0, 0);
    }
    __syncthreads();
  }
  int cl = lane & 15, quad = lane >> 4;
#pragma unroll
  for (int ni = 0; ni < 4; ni++) {
    int col = colBase + wc * 64 + ni * 16 + cl;
    float bv = bias[col];
#pragma unroll
    for (int mi = 0; mi < 4; mi++) {
      int row0 = rowBase + wr * 64 + mi * 16 + quad * 4;
#pragma unroll
      for (int r = 0; r < 4; r++) {
        float v = acc[mi][ni][r] + bv;
        if (RELU) v = fmaxf(v, 0.f);
        out[(size_t)(row0 + r) * M + col] = f2bf(v);
      }
    }
  }
}

// ---------------------------------------------------------------------------
// MFMA GEMM 64x128 tile with fused residual + LayerNorm epilogue.
// xio (fp32) is residual input AND fp32 output; xbo gets bf16 copy.
// M fixed = 128 (full rows in-block so LN is local). 4 waves 1x4 (cols).
// ---------------------------------------------------------------------------
__global__ __launch_bounds__(256) void gemm_ln(
    const unsigned short* __restrict__ A, const unsigned short* __restrict__ W,
    const float* __restrict__ bias, float* __restrict__ xio,
    unsigned short* __restrict__ xbo, const float* __restrict__ lng,
    const float* __restrict__ lnb, int K) {
  __shared__ __align__(16) char As[64 * 128];
  __shared__ __align__(16) char Bs[128 * 128];
  __shared__ float xsm[64][132];
  int tid = threadIdx.x;
  int w = tid >> 6, lane = tid & 63;
  int rowBase = blockIdx.x * 64;
  f32x4 acc[4][2];
#pragma unroll
  for (int i = 0; i < 4; i++)
#pragma unroll
    for (int j = 0; j < 2; j++) acc[i][j] = (f32x4){0.f, 0.f, 0.f, 0.f};

  int r8 = lane >> 3;
  int gq = (lane & 7) ^ r8;
  int fr = lane & 15, fq = lane >> 4;

  for (int k0 = 0; k0 < K; k0 += 64) {
#pragma unroll
    for (int i = 0; i < 2; i++) {
      int issue = w * 2 + i;
      int row = issue * 8 + r8;
      gl2lds16(A + (size_t)(rowBase + row) * K + k0 + gq * 8, As + issue * 1024);
    }
#pragma unroll
    for (int i = 0; i < 4; i++) {
      int issue = w * 4 + i;
      int row = issue * 8 + r8;
      gl2lds16(W + (size_t)row * K + k0 + gq * 8, Bs + issue * 1024);
    }
    __syncthreads();
#pragma unroll
    for (int ks = 0; ks < 2; ks++) {
      bf16x8 af[4], bfr[2];
#pragma unroll
      for (int mi = 0; mi < 4; mi++) {
        int row = mi * 16 + fr;
        int kq = ks * 4 + fq;
        af[mi] = *(const bf16x8*)(As + row * 128 + ((kq ^ (row & 7)) * 16));
      }
#pragma unroll
      for (int ni = 0; ni < 2; ni++) {
        int row = w * 32 + ni * 16 + fr;
        int kq = ks * 4 + fq;
        bfr[ni] = *(const bf16x8*)(Bs + row * 128 + ((kq ^ (row & 7)) * 16));
      }
#pragma unroll
      for (int mi = 0; mi < 4; mi++)
#pragma unroll
        for (int ni = 0; ni < 2; ni++)
          acc[mi][ni] = __builtin_amdgcn_mfma_f32_16x16x32_bf16(
              af[mi], bfr[ni], acc[mi][ni], 0, 0, 0);
    }
    __syncthreads();
  }
  // epilogue: acc + bias + residual -> LDS rows
  int cl = lane & 15, quad = lane >> 4;
#pragma unroll
  for (int ni = 0; ni < 2; ni++) {
    int col = w * 32 + ni * 16 + cl;
    float bv = bias[col];
#pragma unroll
    for (int mi = 0; mi < 4; mi++) {
      int row0 = mi * 16 + quad * 4;
#pragma unroll
      for (int r = 0; r < 4; r++) {
        int row = row0 + r;
        float v = acc[mi][ni][r] + bv + xio[(size_t)(rowBase + row) * 128 + col];
        xsm[row][col] = v;
      }
    }
  }
  __syncthreads();
  // LayerNorm: 4 threads per row, 32 cols each, combine via shuffles.
  int row = tid >> 2, seg = tid & 3;
  float vals[32];
  const float* xr = &xsm[row][seg * 32];
  float s = 0.f;
#pragma unroll
  for (int j = 0; j < 32; j++) { vals[j] = xr[j]; s += vals[j]; }
  s += __shfl_xor(s, 1); s += __shfl_xor(s, 2);
  float mean = s * (1.f / 128.f);
  float vv = 0.f;
#pragma unroll
  for (int j = 0; j < 32; j++) { float d = vals[j] - mean; vv += d * d; }
  vv += __shfl_xor(vv, 1); vv += __shfl_xor(vv, 2);
  float inv = rsqrtf(vv * (1.f / 128.f) + 1e-5f);
  int c0 = seg * 32;
  size_t obase = (size_t)(rowBase + row) * 128 + c0;
#pragma unroll
  for (int j4 = 0; j4 < 8; j4++) {
    float y[4];
#pragma unroll
    for (int q = 0; q < 4; q++) {
      int j = j4 * 4 + q;
      y[q] = (vals[j] - mean) * inv * lng[c0 + j] + lnb[c0 + j];
    }
    *(float4*)(xio + obase + j4 * 4) = make_float4(y[0], y[1], y[2], y[3]);
    ushort4 ub; ub.x = f2bf(y[0]); ub.y = f2bf(y[1]);
    ub.z = f2bf(y[2]); ub.w = f2bf(y[3]);
    *(ushort4*)(xbo + obase + j4 * 4) = ub;
  }
}

// ---------------------------------------------------------------------------
// Attention for one (b,h): fp32 math from bf16 qkv, writes bf16 ao.
// ---------------------------------------------------------------------------
__global__ __launch_bounds__(256) void attn_kernel(
    const unsigned short* __restrict__ qkv, unsigned short* __restrict__ ao) {
  __shared__ float Qs[64][17], Ks[64][17], Vs[64][17];
  __shared__ float SC[64][65];
  int tid = threadIdx.x;
  int b = blockIdx.x & 255;
  int h = blockIdx.x >> 8;
  const unsigned short* base = qkv + b * 384 + h * 16;
#pragma unroll
  for (int i = 0; i < 4; i++) {
    int idx = tid + i * 256;
    int s = idx >> 4, d = idx & 15;
    const unsigned short* p = base + (size_t)s * (256 * 384);
    Qs[s][d] = bf2f(p[d]);
    Ks[s][d] = bf2f(p[128 + d]);
    Vs[s][d] = bf2f(p[256 + d]);
  }
  __syncthreads();
#pragma unroll
  for (int i = 0; i < 16; i++) {
    int e = tid + i * 256;
    int s = e >> 6, t2 = e & 63;
    float acc = 0.f;
#pragma unroll
    for (int d = 0; d < 16; d++) acc += Qs[s][d] * Ks[t2][d];
    SC[s][t2] = acc * 0.25f;
  }
  __syncthreads();
  {
    int s = tid >> 2, seg = tid & 3;
    float* rowp = &SC[s][seg * 16];
    float m = -1e30f;
#pragma unroll
    for (int j = 0; j < 16; j++) m = fmaxf(m, rowp[j]);
    m = fmaxf(m, __shfl_xor(m, 1));
    m = fmaxf(m, __shfl_xor(m, 2));
    float pv[16], sum = 0.f;
#pragma unroll
    for (int j = 0; j < 16; j++) { pv[j] = expf(rowp[j] - m); sum += pv[j]; }
    sum += __shfl_xor(sum, 1);
    sum += __shfl_xor(sum, 2);
    float rinv = 1.f / sum;
#pragma unroll
    for (int j = 0; j < 16; j++) rowp[j] = pv[j] * rinv;
  }
  __syncthreads();
#pragma unroll
  for (int i = 0; i < 4; i++) {
    int o = tid + i * 256;
    int s = o >> 4, d = o & 15;
    float acc = 0.f;
    for (int t2 = 0; t2 < 64; t2++) acc += SC[s][t2] * Vs[t2][d];
    ao[(size_t)(s * 256 + b) * 128 + h * 16 + d] = f2bf(acc);
  }
}

// ---------------------------------------------------------------------------
// Set2Set (6 steps) + memory LSTM + lin1 + lin3.  One block (512 thr) per
// segment.  Coalesced r-loop (lane = feature dim), gate-per-thread GEMV.
// ---------------------------------------------------------------------------
__global__ __launch_bounds__(512) void s2s_kernel(
    const float* __restrict__ x,
    const float* __restrict__ wih, const float* __restrict__ whh,
    const float* __restrict__ bih, const float* __restrict__ bhh,
    const float* __restrict__ mwih,
    const float* __restrict__ mbih, const float* __restrict__ mbhh,
    const float* __restrict__ l1w, const float* __restrict__ l1b,
    const float* __restrict__ l3w, const float* __restrict__ l3b,
    float* __restrict__ out) {
  __shared__ __align__(16) float h[128], c[128], qs[256], gates[512];
  __shared__ __align__(16) float aw[256], red[256];
  int s = blockIdx.x, t = threadIdx.x;
  const float* xs = x + (size_t)s * 32768;
  if (t < 128) { h[t] = 0.f; c[t] = 0.f; }
  if (t < 256) qs[t] = 0.f;
  __syncthreads();
  for (int step = 0; step < 6; step++) {
    {  // gate t = bih+bhh + wih[t]·q_star + whh[t]·h
      float acc = bih[t] + bhh[t];
      const float4* w4 = (const float4*)(wih + (size_t)t * 256);
      const float4* q4 = (const float4*)qs;
#pragma unroll 8
      for (int k = 0; k < 64; k++) {
        float4 a = w4[k], b = q4[k];
        acc += a.x * b.x + a.y * b.y + a.z * b.z + a.w * b.w;
      }
      const float4* u4 = (const float4*)(whh + (size_t)t * 128);
      const float4* h4 = (const float4*)h;
#pragma unroll 8
      for (int k = 0; k < 32; k++) {
        float4 a = u4[k], b = h4[k];
        acc += a.x * b.x + a.y * b.y + a.z * b.z + a.w * b.w;
      }
      gates[t] = acc;
    }
    __syncthreads();
    if (t < 128) {
      float ig = sigf(gates[t]), fg = sigf(gates[128 + t]);
      float gg = tanhf(gates[256 + t]), og = sigf(gates[384 + t]);
      float cn = fg * c[t] + ig * gg;
      c[t] = cn;
      float hn = og * tanhf(cn);
      h[t] = hn;
      qs[t] = hn;
    }
    __syncthreads();
    float e = 0.f;
    if (t < 256) {
      const float4* x4 = (const float4*)(xs + (size_t)t * 128);
      const float4* h4 = (const float4*)h;
#pragma unroll 8
      for (int k = 0; k < 32; k++) {
        float4 a = x4[k], b = h4[k];
        e += a.x * b.x + a.y * b.y + a.z * b.z + a.w * b.w;
      }
      red[t] = e;
    }
    __syncthreads();
    for (int off = 128; off; off >>= 1) {
      if (t < off) red[t] = fmaxf(red[t], red[t + off]);
      __syncthreads();
    }
    float m = red[0];
    __syncthreads();
    float pe = 0.f;
    if (t < 256) { pe = expf(e - m); red[t] = pe; }
    __syncthreads();
    for (int off = 128; off; off >>= 1) {
      if (t < off) red[t] += red[t + off];
      __syncthreads();
    }
    float inv = 1.f / red[0];
    __syncthreads();
    if (t < 256) aw[t] = pe * inv;
    __syncthreads();
    {  // r[d] = sum_n aw[n]*xs[n][d], coalesced over d
      int d = t & 127, grp = t >> 7;
      const float* xp = xs + (size_t)grp * 64 * 128 + d;
      const float* ap = aw + grp * 64;
      float r = 0.f;
#pragma unroll 8
      for (int n = 0; n < 64; n++) r += ap[n] * xp[n * 128];
      gates[t] = r;
    }
    __syncthreads();
    if (t < 128)
      qs[128 + t] = gates[t] + gates[128 + t] + gates[256 + t] + gates[384 + t];
    __syncthreads();
  }
  {  // memory LSTM (zero init state): gates = q_star @ mwih^T + mbih + mbhh
    float acc = mbih[t] + mbhh[t];
    const float4* w4 = (const float4*)(mwih + (size_t)t * 256);
    const float4* q4 = (const float4*)qs;
#pragma unroll 8
    for (int k = 0; k < 64; k++) {
      float4 a = w4[k], b = q4[k];
      acc += a.x * b.x + a.y * b.y + a.z * b.z + a.w * b.w;
    }
    gates[t] = acc;
  }
  __syncthreads();
  if (t < 128) {
    float ig = sigf(gates[t]);
    float gg = tanhf(gates[256 + t]);
    float og = sigf(gates[384 + t]);
    float cx = ig * gg;
    float hx = og * tanhf(cx);
    h[t] = hx;
    out[64 + s * 128 + t] = hx;
    out[64 + 8192 + s * 128 + t] = cx;
  }
  __syncthreads();
  if (t < 128) {
    float acc = l1b[t];
    const float4* w4 = (const float4*)(l1w + (size_t)t * 128);
    const float4* h4 = (const float4*)h;
#pragma unroll 8
    for (int k = 0; k < 32; k++) {
      float4 a = w4[k], b = h4[k];
      acc += a.x * b.x + a.y * b.y + a.z * b.z + a.w * b.w;
    }
    red[t] = fmaxf(acc, 0.f) * l3w[t];
  } else if (t < 256) {
    red[t] = 0.f;
  }
  __syncthreads();
  for (int off = 128; off; off >>= 1) {
    if (t < off) red[t] += red[t + off];
    __syncthreads();
  }
  if (t == 0) out[s] = red[0] + l3b[0];
}

// ---------------------------------------------------------------------------
extern "C" void kernel_launch(void* const* d_in, const int* in_sizes, int n_in,
                              void* d_out, int out_size, void* d_ws,
                              size_t ws_size, hipStream_t stream) {
  const float* data       = (const float*)d_in[0];
  const float* lin0_w     = (const float*)d_in[1];
  const float* lin0_b     = (const float*)d_in[2];
  const float* attn_in_w  = (const float*)d_in[3];
  const float* attn_in_b  = (const float*)d_in[4];
  const float* attn_out_w = (const float*)d_in[5];
  const float* attn_out_b = (const float*)d_in[6];
  const float* ln1_g      = (const float*)d_in[7];
  const float* ln1_b      = (const float*)d_in[8];
  const float* ff_w1      = (const float*)d_in[9];
  const float* ff_b1      = (const float*)d_in[10];
  const float* ff_w2      = (const float*)d_in[11];
  const float* ff_b2      = (const float*)d_in[12];
  const float* ln2_g      = (const float*)d_in[13];
  const float* ln2_b      = (const float*)d_in[14];
  const float* s2s_wih    = (const float*)d_in[15];
  const float* s2s_whh    = (const float*)d_in[16];
  const float* s2s_bih    = (const float*)d_in[17];
  const float* s2s_bhh    = (const float*)d_in[18];
  const float* mem_wih    = (const float*)d_in[19];
  const float* mem_bih    = (const float*)d_in[21];
  const float* mem_bhh    = (const float*)d_in[22];
  const float* lin1_w     = (const float*)d_in[23];
  const float* lin1_b     = (const float*)d_in[24];
  const float* lin3_w     = (const float*)d_in[25];
  const float* lin3_b     = (const float*)d_in[26];
  float* out = (float*)d_out;

  // Workspace carve (bytes):
  char* p = (char*)d_ws;
  float* x = (float*)p;              p += (size_t)16384 * 128 * 4;   // 8 MB
  unsigned short* xb = (unsigned short*)p;   p += (size_t)16384 * 128 * 2; // 4 MB
  unsigned short* qkvb = (unsigned short*)p; p += (size_t)16384 * 384 * 2; // 12 MB
  unsigned short* aob = (unsigned short*)p;  p += (size_t)16384 * 128 * 2; // 4 MB
  unsigned short* wqkv = (unsigned short*)p; p += (size_t)294912 * 2;
  unsigned short* wout = (unsigned short*)p; p += (size_t)98304 * 2;
  unsigned short* w1b = (unsigned short*)p;  p += (size_t)1572864 * 2;
  unsigned short* w2b = (unsigned short*)p;  p += (size_t)1572864 * 2;
  unsigned short* ffbuf = (unsigned short*)p;
  size_t used = (size_t)(p - (char*)d_ws);
  bool full_ff = ws_size >= used + (size_t)16384 * 2048 * 2;
  int crow = full_ff ? 16384 : 4096;
  int nchunk = 16384 / crow;

  convw_kernel<<<13824, 256, 0, stream>>>(attn_in_w, attn_out_w, ff_w1, ff_w2,
                                          wqkv, wout, w1b, w2b);
  lin0_kernel<<<8192, 256, 0, stream>>>(data, lin0_w, lin0_b, x, xb);

  for (int l = 0; l < 6; l++) {
    gemm128<false><<<dim3(128, 3), 256, 0, stream>>>(
        xb, wqkv + (size_t)l * 49152, attn_in_b + l * 384, qkvb, 128, 384);
    attn_kernel<<<2048, 256, 0, stream>>>(qkvb, aob);
    gemm_ln<<<256, 256, 0, stream>>>(
        aob, wout + (size_t)l * 16384, attn_out_b + l * 128, x, xb,
        ln1_g + l * 128, ln1_b + l * 128, 128);
    for (int ck = 0; ck < nchunk; ck++) {
      float* xc = x + (size_t)ck * crow * 128;
      unsigned short* xbc = xb + (size_t)ck * crow * 128;
      gemm128<true><<<dim3(crow / 128, 16), 256, 0, stream>>>(
          xbc, w1b + (size_t)l * 262144, ff_b1 + l * 2048, ffbuf, 128, 2048);
      gemm_ln<<<crow / 64, 256, 0, stream>>>(
          ffbuf, w2b + (size_t)l * 262144, ff_b2 + l * 128, xc, xbc,
          ln2_g + l * 128, ln2_b + l * 128, 2048);
    }
  }

  s2s_kernel<<<64, 512, 0, stream>>>(
      x, s2s_wih, s2s_whh, s2s_bih, s2s_bhh,
      mem_wih, mem_bih, mem_bhh, lin1_w, lin1_b, lin3_w, lin3_b, out);
}

// Round 3
// 916.135 us; speedup vs baseline: 2.7220x; 1.1418x over previous
//
#include <hip/hip_runtime.h>
#include <math.h>

// S=64 segments(seq), B=256 atoms(batch), N=16384 rows, D=128, H=8, HD=16,
// DFF=2048, NL=6.  Heavy GEMMs: bf16 MFMA 16x16x32, fp32 accum.

typedef __attribute__((ext_vector_type(8))) short bf16x8;
typedef __attribute__((ext_vector_type(4))) float f32x4;

__device__ __forceinline__ unsigned short f2bf(float f) {
  union { float f; unsigned u; } x; x.f = f;
  unsigned r = x.u + 0x7fff + ((x.u >> 16) & 1);
  return (unsigned short)(r >> 16);
}
__device__ __forceinline__ float bf2f(unsigned short u) {
  union { unsigned u; float f; } x; x.u = ((unsigned)u) << 16;
  return x.f;
}
__device__ __forceinline__ float uplo(unsigned u) {
  union { unsigned u; float f; } x; x.u = u << 16; return x.f;
}
__device__ __forceinline__ float uphi(unsigned u) {
  union { unsigned u; float f; } x; x.u = u & 0xffff0000u; return x.f;
}
__device__ __forceinline__ unsigned packbf(float a, float b) {
  return (unsigned)f2bf(a) | ((unsigned)f2bf(b) << 16);
}
__device__ __forceinline__ float sigf(float x) { return 1.f / (1.f + expf(-x)); }

// async 16B global->LDS; LDS base must be wave-uniform (+ lane*16 implicit).
__device__ __forceinline__ void gl2lds16(const void* g, void* l) {
  __builtin_amdgcn_global_load_lds(
      (const __attribute__((address_space(1))) unsigned int*)g,
      (__attribute__((address_space(3))) unsigned int*)l, 16, 0, 0);
}

// ---------------------------------------------------------------------------
// fp32 -> bf16 weight conversion. Layout (element offsets):
// aiw 294912 | aow 98304 | w1 1572864 | w2 1572864 | wih 131072 | whh 65536
// total 3735552
// ---------------------------------------------------------------------------
__global__ __launch_bounds__(256) void convw_kernel(
    const float* __restrict__ aiw, const float* __restrict__ aow,
    const float* __restrict__ w1, const float* __restrict__ w2,
    const float* __restrict__ wih, const float* __restrict__ whh,
    unsigned short* __restrict__ o0, unsigned short* __restrict__ o1,
    unsigned short* __restrict__ o2, unsigned short* __restrict__ o3,
    unsigned short* __restrict__ o4, unsigned short* __restrict__ o5) {
  int i = blockIdx.x * 256 + threadIdx.x;
  if (i < 294912) {
    o0[i] = f2bf(aiw[i]);
  } else if (i < 393216) {
    int j = i - 294912; o1[j] = f2bf(aow[j]);
  } else if (i < 1966080) {
    int j = i - 393216; o2[j] = f2bf(w1[j]);
  } else if (i < 3538944) {
    int j = i - 1966080; o3[j] = f2bf(w2[j]);
  } else if (i < 3670016) {
    int j = i - 3538944; o4[j] = f2bf(wih[j]);
  } else {
    int j = i - 3670016; o5[j] = f2bf(whh[j]);
  }
}

// ---------------------------------------------------------------------------
// lin0: x = relu(data @ w^T + b), writes fp32 x and bf16 xb
// ---------------------------------------------------------------------------
__global__ __launch_bounds__(256) void lin0_kernel(
    const float* __restrict__ data, const float* __restrict__ w,
    const float* __restrict__ b, float* __restrict__ x,
    unsigned short* __restrict__ xb) {
  int i = blockIdx.x * 256 + threadIdx.x;
  int n = i >> 7, d = i & 127;
  float v = b[d] + data[n * 3 + 0] * w[d * 3 + 0]
                 + data[n * 3 + 1] * w[d * 3 + 1]
                 + data[n * 3 + 2] * w[d * 3 + 2];
  v = fmaxf(v, 0.0f);
  x[i] = v;
  xb[i] = f2bf(v);
}

// ---------------------------------------------------------------------------
// Single-shot GEMM for K=128: out[N,M] = (relu?)(A[N,K=128] @ W[M,128]^T + b)
// 128x128 tile, 4 waves 2x2, whole K staged once (64KB LDS), ONE barrier.
// 256B rows, 16x16B chunks, XOR swizzle chunk^=(row&7): staging stays
// coalesced (permutation within each 256B row), ds_read_b128 2-way-free.
// ---------------------------------------------------------------------------
template <bool RELU>
__global__ __launch_bounds__(256) void gemm_k128(
    const unsigned short* __restrict__ A, const unsigned short* __restrict__ W,
    const float* __restrict__ bias, unsigned short* __restrict__ out, int M) {
  __shared__ __align__(16) unsigned short As[128 * 128];
  __shared__ __align__(16) unsigned short Bs[128 * 128];
  int tid = threadIdx.x;
  int w = tid >> 6, lane = tid & 63;
  int wr = w >> 1, wc = w & 1;
  int rowBase = blockIdx.x * 128, colBase = blockIdx.y * 128;
  f32x4 acc[4][4];
#pragma unroll
  for (int i = 0; i < 4; i++)
#pragma unroll
    for (int j = 0; j < 4; j++) acc[i][j] = (f32x4){0.f, 0.f, 0.f, 0.f};

  int r4 = lane >> 4, cs = lane & 15;
#pragma unroll
  for (int i = 0; i < 8; i++) {
    int issue = w * 8 + i;            // 0..31, 4 rows each
    int row = issue * 4 + r4;
    int g = cs ^ (row & 7);           // logical chunk fetched into slot cs
    gl2lds16(A + (size_t)(rowBase + row) * 128 + g * 8, As + issue * 512);
    gl2lds16(W + (size_t)(colBase + row) * 128 + g * 8, Bs + issue * 512);
  }
  __syncthreads();

  int fr = lane & 15, fq = lane >> 4;
#pragma unroll
  for (int ks = 0; ks < 4; ks++) {
    bf16x8 af[4], bf[4];
#pragma unroll
    for (int mi = 0; mi < 4; mi++) {
      int row = wr * 64 + mi * 16 + fr;
      int kq = (ks * 4 + fq) ^ (row & 7);
      af[mi] = *(const bf16x8*)(As + row * 128 + kq * 8);
    }
#pragma unroll
    for (int ni = 0; ni < 4; ni++) {
      int row = wc * 64 + ni * 16 + fr;
      int kq = (ks * 4 + fq) ^ (row & 7);
      bf[ni] = *(const bf16x8*)(Bs + row * 128 + kq * 8);
    }
#pragma unroll
    for (int mi = 0; mi < 4; mi++)
#pragma unroll
      for (int ni = 0; ni < 4; ni++)
        acc[mi][ni] = __builtin_amdgcn_mfma_f32_16x16x32_bf16(
            af[mi], bf[ni], acc[mi][ni], 0, 0, 0);
  }

  int cl = lane & 15, quad = lane >> 4;
#pragma unroll
  for (int ni = 0; ni < 4; ni++) {
    int col = colBase + wc * 64 + ni * 16 + cl;
    float bv = bias[col];
#pragma unroll
    for (int mi = 0; mi < 4; mi++) {
      int row0 = rowBase + wr * 64 + mi * 16 + quad * 4;
#pragma unroll
      for (int r = 0; r < 4; r++) {
        float v = acc[mi][ni][r] + bv;
        if (RELU) v = fmaxf(v, 0.f);
        out[(size_t)(row0 + r) * M + col] = f2bf(v);
      }
    }
  }
}

// ---------------------------------------------------------------------------
// GEMM (64-row tile, M=128 fixed) + residual + LayerNorm, register epilogue.
// K-loop BK=64 (2 iters for K=128, 32 for K=2048). LN stats: per-lane row
// partials -> cl-shuffles -> 4-wave LDS combine -> E[x^2]-m^2.
// ---------------------------------------------------------------------------
__global__ __launch_bounds__(256) void gemm_ln(
    const unsigned short* __restrict__ A, const unsigned short* __restrict__ W,
    const float* __restrict__ bias, float* __restrict__ xio,
    unsigned short* __restrict__ xbo, const float* __restrict__ lng,
    const float* __restrict__ lnb, int K) {
  __shared__ __align__(16) unsigned short As[64 * 64];
  __shared__ __align__(16) unsigned short Bs[128 * 64];
  __shared__ float psum[4][64], psq[4][64];
  __shared__ float2 stats[64];
  int tid = threadIdx.x;
  int w = tid >> 6, lane = tid & 63;
  int rowBase = blockIdx.x * 64;
  f32x4 acc[4][2];
#pragma unroll
  for (int i = 0; i < 4; i++)
#pragma unroll
    for (int j = 0; j < 2; j++) acc[i][j] = (f32x4){0.f, 0.f, 0.f, 0.f};

  int r8 = lane >> 3;
  int gq = (lane & 7) ^ r8;
  int fr = lane & 15, fq = lane >> 4;

  for (int k0 = 0; k0 < K; k0 += 64) {
#pragma unroll
    for (int i = 0; i < 2; i++) {
      int issue = w * 2 + i;
      int row = issue * 8 + r8;
      gl2lds16(A + (size_t)(rowBase + row) * K + k0 + gq * 8, As + issue * 512);
    }
#pragma unroll
    for (int i = 0; i < 4; i++) {
      int issue = w * 4 + i;
      int row = issue * 8 + r8;
      gl2lds16(W + (size_t)row * K + k0 + gq * 8, Bs + issue * 512);
    }
    __syncthreads();
#pragma unroll
    for (int ks = 0; ks < 2; ks++) {
      bf16x8 af[4], bf[2];
#pragma unroll
      for (int mi = 0; mi < 4; mi++) {
        int row = mi * 16 + fr;
        int kq = (ks * 4 + fq) ^ (row & 7);
        af[mi] = *(const bf16x8*)(As + row * 64 + kq * 8);
      }
#pragma unroll
      for (int ni = 0; ni < 2; ni++) {
        int row = w * 32 + ni * 16 + fr;
        int kq = (ks * 4 + fq) ^ (row & 7);
        bf[ni] = *(const bf16x8*)(Bs + row * 64 + kq * 8);
      }
#pragma unroll
      for (int mi = 0; mi < 4; mi++)
#pragma unroll
        for (int ni = 0; ni < 2; ni++)
          acc[mi][ni] = __builtin_amdgcn_mfma_f32_16x16x32_bf16(
              af[mi], bf[ni], acc[mi][ni], 0, 0, 0);
    }
    __syncthreads();
  }

  // epilogue: v = acc + bias + residual (fp32), LN stats in registers
  int cl = lane & 15, quad = lane >> 4;
  float vv[4][2][4];
#pragma unroll
  for (int ni = 0; ni < 2; ni++) {
    int col = w * 32 + ni * 16 + cl;
    float bv = bias[col];
#pragma unroll
    for (int mi = 0; mi < 4; mi++) {
#pragma unroll
      for (int r = 0; r < 4; r++) {
        int row = mi * 16 + quad * 4 + r;
        vv[mi][ni][r] =
            acc[mi][ni][r] + bv + xio[(size_t)(rowBase + row) * 128 + col];
      }
    }
  }
  float sums[4][4], sqs[4][4];
#pragma unroll
  for (int mi = 0; mi < 4; mi++)
#pragma unroll
    for (int r = 0; r < 4; r++) {
      float a = vv[mi][0][r], b = vv[mi][1][r];
      sums[mi][r] = a + b;
      sqs[mi][r] = a * a + b * b;
    }
#pragma unroll
  for (int d = 1; d < 16; d <<= 1) {
#pragma unroll
    for (int mi = 0; mi < 4; mi++)
#pragma unroll
      for (int r = 0; r < 4; r++) {
        sums[mi][r] += __shfl_xor(sums[mi][r], d, 64);
        sqs[mi][r] += __shfl_xor(sqs[mi][r], d, 64);
      }
  }
  if (cl == 0) {
#pragma unroll
    for (int mi = 0; mi < 4; mi++)
#pragma unroll
      for (int r = 0; r < 4; r++) {
        int row = mi * 16 + quad * 4 + r;
        psum[w][row] = sums[mi][r];
        psq[w][row] = sqs[mi][r];
      }
  }
  __syncthreads();
  if (tid < 64) {
    float S = psum[0][tid] + psum[1][tid] + psum[2][tid] + psum[3][tid];
    float Q = psq[0][tid] + psq[1][tid] + psq[2][tid] + psq[3][tid];
    float m = S * (1.f / 128.f);
    float var = Q * (1.f / 128.f) - m * m;
    stats[tid] = make_float2(m, rsqrtf(var + 1e-5f));
  }
  __syncthreads();
#pragma unroll
  for (int ni = 0; ni < 2; ni++) {
    int col = w * 32 + ni * 16 + cl;
    float gl = lng[col], bl = lnb[col];
#pragma unroll
    for (int mi = 0; mi < 4; mi++) {
#pragma unroll
      for (int r = 0; r < 4; r++) {
        int row = mi * 16 + quad * 4 + r;
        float2 st = stats[row];
        float y = (vv[mi][ni][r] - st.x) * st.y * gl + bl;
        size_t o = (size_t)(rowBase + row) * 128 + col;
        xio[o] = y;
        xbo[o] = f2bf(y);
      }
    }
  }
}

// ---------------------------------------------------------------------------
// Attention for one (b,h): fp32 math from bf16 qkv, writes bf16 ao.
// ---------------------------------------------------------------------------
__global__ __launch_bounds__(256) void attn_kernel(
    const unsigned short* __restrict__ qkv, unsigned short* __restrict__ ao) {
  __shared__ float Qs[64][17], Ks[64][17], Vs[64][17];
  __shared__ float SC[64][65];
  int tid = threadIdx.x;
  int b = blockIdx.x & 255;
  int h = blockIdx.x >> 8;
  const unsigned short* base = qkv + b * 384 + h * 16;
#pragma unroll
  for (int i = 0; i < 4; i++) {
    int idx = tid + i * 256;
    int s = idx >> 4, d = idx & 15;
    const unsigned short* p = base + (size_t)s * (256 * 384);
    Qs[s][d] = bf2f(p[d]);
    Ks[s][d] = bf2f(p[128 + d]);
    Vs[s][d] = bf2f(p[256 + d]);
  }
  __syncthreads();
#pragma unroll
  for (int i = 0; i < 16; i++) {
    int e = tid + i * 256;
    int s = e >> 6, t2 = e & 63;
    float acc = 0.f;
#pragma unroll
    for (int d = 0; d < 16; d++) acc += Qs[s][d] * Ks[t2][d];
    SC[s][t2] = acc * 0.25f;
  }
  __syncthreads();
  {
    int s = tid >> 2, seg = tid & 3;
    float* rowp = &SC[s][seg * 16];
    float m = -1e30f;
#pragma unroll
    for (int j = 0; j < 16; j++) m = fmaxf(m, rowp[j]);
    m = fmaxf(m, __shfl_xor(m, 1));
    m = fmaxf(m, __shfl_xor(m, 2));
    float pv[16], sum = 0.f;
#pragma unroll
    for (int j = 0; j < 16; j++) { pv[j] = expf(rowp[j] - m); sum += pv[j]; }
    sum += __shfl_xor(sum, 1);
    sum += __shfl_xor(sum, 2);
    float rinv = 1.f / sum;
#pragma unroll
    for (int j = 0; j < 16; j++) rowp[j] = pv[j] * rinv;
  }
  __syncthreads();
#pragma unroll
  for (int i = 0; i < 4; i++) {
    int o = tid + i * 256;
    int s = o >> 4, d = o & 15;
    float acc = 0.f;
    for (int t2 = 0; t2 < 64; t2++) acc += SC[s][t2] * Vs[t2][d];
    ao[(size_t)(s * 256 + b) * 128 + h * 16 + d] = f2bf(acc);
  }
}

// ---------------------------------------------------------------------------
// Set2Set (6 steps) + memory LSTM + lin1 + lin3. One 512-thread block per
// segment. bf16 weights + bf16 x (xb). Gate GEMV uses shuffle-broadcast of
// packed q_star; e-loop coalesced dword loads + wave-shuffle reduce;
// all-wave redundant softmax (6 barriers/step).
// ---------------------------------------------------------------------------
__global__ __launch_bounds__(512) void s2s_kernel(
    const unsigned short* __restrict__ xb,
    const unsigned short* __restrict__ wihb,
    const unsigned short* __restrict__ whhb,
    const float* __restrict__ bih, const float* __restrict__ bhh,
    const float* __restrict__ mwih, const float* __restrict__ mbih,
    const float* __restrict__ mbhh,
    const float* __restrict__ l1w, const float* __restrict__ l1b,
    const float* __restrict__ l3w, const float* __restrict__ l3b,
    float* __restrict__ out) {
  __shared__ __align__(16) unsigned qu[128];   // q_star packed bf16 pairs
  __shared__ __align__(16) float qsf[256];     // q_star fp32 (tail)
  __shared__ __align__(16) float cst[128];
  __shared__ __align__(16) float gates[512];
  __shared__ __align__(16) float red[256];
  __shared__ __align__(16) float aw[256];
  int s = blockIdx.x, t = threadIdx.x, lane = t & 63, w = t >> 6;
  const unsigned short* xs = xb + (size_t)s * 32768;
  if (t < 128) { cst[t] = 0.f; qu[t] = 0u; }
  if (t < 256) qsf[t] = 0.f;
  __syncthreads();
  const unsigned* wih_u = (const unsigned*)(wihb + (size_t)t * 256);
  const unsigned* whh_u = (const unsigned*)(whhb + (size_t)t * 128);
  float bsum = bih[t] + bhh[t];

  for (int step = 0; step < 6; step++) {
    float acc = bsum;
    if (step > 0) {
#pragma unroll
      for (int ch = 0; ch < 4; ch++) {           // wih . q_star
        unsigned qreg = qu[ch * 32 + (lane & 31)];
        const unsigned* wp = wih_u + ch * 32;
#pragma unroll
        for (int j = 0; j < 32; j++) {
          unsigned qv = __shfl(qreg, j, 64);
          unsigned wv = wp[j];
          acc += uplo(wv) * uplo(qv) + uphi(wv) * uphi(qv);
        }
      }
#pragma unroll
      for (int ch = 0; ch < 2; ch++) {           // whh . h
        unsigned qreg = qu[ch * 32 + (lane & 31)];
        const unsigned* wp = whh_u + ch * 32;
#pragma unroll
        for (int j = 0; j < 32; j++) {
          unsigned qv = __shfl(qreg, j, 64);
          unsigned wv = wp[j];
          acc += uplo(wv) * uplo(qv) + uphi(wv) * uphi(qv);
        }
      }
    }
    gates[t] = acc;
    __syncthreads();
    if (t < 128) {
      float ig = sigf(gates[t]), fg = sigf(gates[128 + t]);
      float gg = tanhf(gates[256 + t]), og = sigf(gates[384 + t]);
      float cn = fg * cst[t] + ig * gg;
      cst[t] = cn;
      float hn = og * tanhf(cn);
      qsf[t] = hn;
      float hp = __shfl_xor(hn, 1, 64);
      if ((t & 1) == 0) qu[t >> 1] = packbf(hn, hp);
    }
    __syncthreads();
    // e[n] = x[n] . h — coalesced dword (2 bf16) per lane, shuffle reduce
    {
      unsigned hreg = qu[lane];
      float h0 = uplo(hreg), h1 = uphi(hreg);
      float ev = 0.f;
      int n0 = w * 32;
#pragma unroll 4
      for (int i = 0; i < 32; i++) {
        unsigned xv = *(const unsigned*)(xs + (size_t)(n0 + i) * 128 + lane * 2);
        float e = uplo(xv) * h0 + uphi(xv) * h1;
#pragma unroll
        for (int d = 1; d < 64; d <<= 1) e += __shfl_xor(e, d, 64);
        if (lane == i) ev = e;
      }
      if (lane < 32) red[n0 + lane] = ev;
    }
    __syncthreads();
    // softmax over 256 — every wave redundantly reduces (no extra barrier)
    float p0, p1, p2, p3, Sinv;
    {
      float v0 = red[lane], v1 = red[64 + lane];
      float v2 = red[128 + lane], v3 = red[192 + lane];
      float m = fmaxf(fmaxf(v0, v1), fmaxf(v2, v3));
#pragma unroll
      for (int d = 1; d < 64; d <<= 1) m = fmaxf(m, __shfl_xor(m, d, 64));
      p0 = expf(v0 - m); p1 = expf(v1 - m);
      p2 = expf(v2 - m); p3 = expf(v3 - m);
      float ss = p0 + p1 + p2 + p3;
#pragma unroll
      for (int d = 1; d < 64; d <<= 1) ss += __shfl_xor(ss, d, 64);
      Sinv = 1.f / ss;
    }
    if (w == 0) {
      aw[lane] = p0 * Sinv; aw[64 + lane] = p1 * Sinv;
      aw[128 + lane] = p2 * Sinv; aw[192 + lane] = p3 * Sinv;
    }
    __syncthreads();
    // r[d] = sum_n aw[n] * x[n][d], coalesced over d
    {
      int d = t & 127, grp = t >> 7;
      const unsigned short* xp = xs + (size_t)grp * 64 * 128 + d;
      const float* ap = aw + grp * 64;
      float r = 0.f;
#pragma unroll 8
      for (int n = 0; n < 64; n++) r += ap[n] * bf2f(xp[n * 128]);
      gates[t] = r;
    }
    __syncthreads();
    if (t < 128) {
      float rd = gates[t] + gates[128 + t] + gates[256 + t] + gates[384 + t];
      qsf[128 + t] = rd;
      float rp = __shfl_xor(rd, 1, 64);
      if ((t & 1) == 0) qu[64 + (t >> 1)] = packbf(rd, rp);
    }
    __syncthreads();
  }
  // memory LSTM (zero init), fp32 weights for output accuracy
  {
    float acc = mbih[t] + mbhh[t];
    const float4* w4 = (const float4*)(mwih + (size_t)t * 256);
    const float4* q4 = (const float4*)qsf;
#pragma unroll 8
    for (int k = 0; k < 64; k++) {
      float4 a = w4[k], b = q4[k];
      acc += a.x * b.x + a.y * b.y + a.z * b.z + a.w * b.w;
    }
    gates[t] = acc;
  }
  __syncthreads();
  if (t < 128) {
    float ig = sigf(gates[t]);
    float gg = tanhf(gates[256 + t]);
    float og = sigf(gates[384 + t]);
    float cx = ig * gg;
    float hx = og * tanhf(cx);
    cst[t] = hx;
    out[64 + s * 128 + t] = hx;
    out[64 + 8192 + s * 128 + t] = cx;
  }
  __syncthreads();
  if (t < 128) {
    float acc = l1b[t];
    const float4* w4 = (const float4*)(l1w + (size_t)t * 128);
    const float4* h4 = (const float4*)cst;
#pragma unroll 8
    for (int k = 0; k < 32; k++) {
      float4 a = w4[k], b = h4[k];
      acc += a.x * b.x + a.y * b.y + a.z * b.z + a.w * b.w;
    }
    red[t] = fmaxf(acc, 0.f) * l3w[t];
  } else if (t < 256) {
    red[t] = 0.f;
  }
  __syncthreads();
  for (int off = 128; off; off >>= 1) {
    if (t < off) red[t] += red[t + off];
    __syncthreads();
  }
  if (t == 0) out[s] = red[0] + l3b[0];
}

// ---------------------------------------------------------------------------
extern "C" void kernel_launch(void* const* d_in, const int* in_sizes, int n_in,
                              void* d_out, int out_size, void* d_ws,
                              size_t ws_size, hipStream_t stream) {
  const float* data       = (const float*)d_in[0];
  const float* lin0_w     = (const float*)d_in[1];
  const float* lin0_b     = (const float*)d_in[2];
  const float* attn_in_w  = (const float*)d_in[3];
  const float* attn_in_b  = (const float*)d_in[4];
  const float* attn_out_w = (const float*)d_in[5];
  const float* attn_out_b = (const float*)d_in[6];
  const float* ln1_g      = (const float*)d_in[7];
  const float* ln1_b      = (const float*)d_in[8];
  const float* ff_w1      = (const float*)d_in[9];
  const float* ff_b1      = (const float*)d_in[10];
  const float* ff_w2      = (const float*)d_in[11];
  const float* ff_b2      = (const float*)d_in[12];
  const float* ln2_g      = (const float*)d_in[13];
  const float* ln2_b      = (const float*)d_in[14];
  const float* s2s_wih    = (const float*)d_in[15];
  const float* s2s_whh    = (const float*)d_in[16];
  const float* s2s_bih    = (const float*)d_in[17];
  const float* s2s_bhh    = (const float*)d_in[18];
  const float* mem_wih    = (const float*)d_in[19];
  const float* mem_bih    = (const float*)d_in[21];
  const float* mem_bhh    = (const float*)d_in[22];
  const float* lin1_w     = (const float*)d_in[23];
  const float* lin1_b     = (const float*)d_in[24];
  const float* lin3_w     = (const float*)d_in[25];
  const float* lin3_b     = (const float*)d_in[26];
  float* out = (float*)d_out;

  char* p = (char*)d_ws;
  float* x = (float*)p;                      p += (size_t)16384 * 128 * 4;
  unsigned short* xb = (unsigned short*)p;   p += (size_t)16384 * 128 * 2;
  unsigned short* qkvb = (unsigned short*)p; p += (size_t)16384 * 384 * 2;
  unsigned short* aob = (unsigned short*)p;  p += (size_t)16384 * 128 * 2;
  unsigned short* wqkv = (unsigned short*)p; p += (size_t)294912 * 2;
  unsigned short* wout = (unsigned short*)p; p += (size_t)98304 * 2;
  unsigned short* w1b = (unsigned short*)p;  p += (size_t)1572864 * 2;
  unsigned short* w2b = (unsigned short*)p;  p += (size_t)1572864 * 2;
  unsigned short* wihb = (unsigned short*)p; p += (size_t)131072 * 2;
  unsigned short* whhb = (unsigned short*)p; p += (size_t)65536 * 2;
  unsigned short* ffbuf = (unsigned short*)p;
  size_t used = (size_t)(p - (char*)d_ws);
  bool full_ff = ws_size >= used + (size_t)16384 * 2048 * 2;
  int crow = full_ff ? 16384 : 4096;
  int nchunk = 16384 / crow;

  convw_kernel<<<14592, 256, 0, stream>>>(attn_in_w, attn_out_w, ff_w1, ff_w2,
                                          s2s_wih, s2s_whh,
                                          wqkv, wout, w1b, w2b, wihb, whhb);
  lin0_kernel<<<8192, 256, 0, stream>>>(data, lin0_w, lin0_b, x, xb);

  for (int l = 0; l < 6; l++) {
    gemm_k128<false><<<dim3(128, 3), 256, 0, stream>>>(
        xb, wqkv + (size_t)l * 49152, attn_in_b + l * 384, qkvb, 384);
    attn_kernel<<<2048, 256, 0, stream>>>(qkvb, aob);
    gemm_ln<<<256, 256, 0, stream>>>(
        aob, wout + (size_t)l * 16384, attn_out_b + l * 128, x, xb,
        ln1_g + l * 128, ln1_b + l * 128, 128);
    for (int ck = 0; ck < nchunk; ck++) {
      float* xc = x + (size_t)ck * crow * 128;
      unsigned short* xbc = xb + (size_t)ck * crow * 128;
      gemm_k128<true><<<dim3(crow / 128, 16), 256, 0, stream>>>(
          xbc, w1b + (size_t)l * 262144, ff_b1 + l * 2048, ffbuf, 2048);
      gemm_ln<<<crow / 64, 256, 0, stream>>>(
          ffbuf, w2b + (size_t)l * 262144, ff_b2 + l * 128, xc, xbc,
          ln2_g + l * 128, ln2_b + l * 128, 2048);
    }
  }

  s2s_kernel<<<64, 512, 0, stream>>>(
      xb, wihb, whhb, s2s_bih, s2s_bhh,
      mem_wih, mem_bih, mem_bhh, lin1_w, lin1_b, lin3_w, lin3_b, out);
}

// Round 4
// 713.162 us; speedup vs baseline: 3.4967x; 1.2846x over previous
//
#include <hip/hip_runtime.h>
#include <math.h>

// S=64 segments(seq), B=256 atoms(batch), N=16384 rows, D=128, H=8, HD=16,
// DFF=2048, NL=6.  Heavy GEMMs: bf16 MFMA 16x16x32, fp32 accum.

typedef __attribute__((ext_vector_type(8))) short bf16x8;
typedef __attribute__((ext_vector_type(4))) float f32x4;

__device__ __forceinline__ unsigned short f2bf(float f) {
  union { float f; unsigned u; } x; x.f = f;
  unsigned r = x.u + 0x7fff + ((x.u >> 16) & 1);
  return (unsigned short)(r >> 16);
}
__device__ __forceinline__ float bf2f(unsigned short u) {
  union { unsigned u; float f; } x; x.u = ((unsigned)u) << 16;
  return x.f;
}
__device__ __forceinline__ float uplo(unsigned u) {
  union { unsigned u; float f; } x; x.u = u << 16; return x.f;
}
__device__ __forceinline__ float uphi(unsigned u) {
  union { unsigned u; float f; } x; x.u = u & 0xffff0000u; return x.f;
}
__device__ __forceinline__ unsigned packbf(float a, float b) {
  return (unsigned)f2bf(a) | ((unsigned)f2bf(b) << 16);
}
__device__ __forceinline__ float sigf(float x) { return 1.f / (1.f + expf(-x)); }

// async 16B global->LDS; LDS base wave-uniform (+ lane*16 implicit).
__device__ __forceinline__ void gl2lds16(const void* g, void* l) {
  __builtin_amdgcn_global_load_lds(
      (const __attribute__((address_space(1))) unsigned int*)g,
      (__attribute__((address_space(3))) unsigned int*)l, 16, 0, 0);
}

// ---------------------------------------------------------------------------
// fp32 -> bf16 weight conversion.
// aiw 294912 | aow 98304 | w1 1572864 | w2 1572864 | wih 131072 | whh 65536
// ---------------------------------------------------------------------------
__global__ __launch_bounds__(256) void convw_kernel(
    const float* __restrict__ aiw, const float* __restrict__ aow,
    const float* __restrict__ w1, const float* __restrict__ w2,
    const float* __restrict__ wih, const float* __restrict__ whh,
    unsigned short* __restrict__ o0, unsigned short* __restrict__ o1,
    unsigned short* __restrict__ o2, unsigned short* __restrict__ o3,
    unsigned short* __restrict__ o4, unsigned short* __restrict__ o5) {
  int i = blockIdx.x * 256 + threadIdx.x;
  if (i < 294912) {
    o0[i] = f2bf(aiw[i]);
  } else if (i < 393216) {
    int j = i - 294912; o1[j] = f2bf(aow[j]);
  } else if (i < 1966080) {
    int j = i - 393216; o2[j] = f2bf(w1[j]);
  } else if (i < 3538944) {
    int j = i - 1966080; o3[j] = f2bf(w2[j]);
  } else if (i < 3670016) {
    int j = i - 3538944; o4[j] = f2bf(wih[j]);
  } else {
    int j = i - 3670016; o5[j] = f2bf(whh[j]);
  }
}

// ---------------------------------------------------------------------------
// lin0: x = relu(data @ w^T + b), writes fp32 x and bf16 xb
// ---------------------------------------------------------------------------
__global__ __launch_bounds__(256) void lin0_kernel(
    const float* __restrict__ data, const float* __restrict__ w,
    const float* __restrict__ b, float* __restrict__ x,
    unsigned short* __restrict__ xb) {
  int i = blockIdx.x * 256 + threadIdx.x;
  int n = i >> 7, d = i & 127;
  float v = b[d] + data[n * 3 + 0] * w[d * 3 + 0]
                 + data[n * 3 + 1] * w[d * 3 + 1]
                 + data[n * 3 + 2] * w[d * 3 + 2];
  v = fmaxf(v, 0.0f);
  x[i] = v;
  xb[i] = f2bf(v);
}

// ---------------------------------------------------------------------------
// Single-shot GEMM, K=128: out[N,M] = A[N,128] @ W[M,128]^T + b. 128x128 tile,
// 4 waves 2x2, whole K staged once, ONE barrier. XOR chunk swizzle.
// ---------------------------------------------------------------------------
__global__ __launch_bounds__(256) void gemm_k128(
    const unsigned short* __restrict__ A, const unsigned short* __restrict__ W,
    const float* __restrict__ bias, unsigned short* __restrict__ out, int M) {
  __shared__ __align__(16) unsigned short As[128 * 128];
  __shared__ __align__(16) unsigned short Bs[128 * 128];
  int tid = threadIdx.x;
  int w = tid >> 6, lane = tid & 63;
  int wr = w >> 1, wc = w & 1;
  int rowBase = blockIdx.x * 128, colBase = blockIdx.y * 128;
  f32x4 acc[4][4];
#pragma unroll
  for (int i = 0; i < 4; i++)
#pragma unroll
    for (int j = 0; j < 4; j++) acc[i][j] = (f32x4){0.f, 0.f, 0.f, 0.f};

  int r4 = lane >> 4, cs = lane & 15;
#pragma unroll
  for (int i = 0; i < 8; i++) {
    int issue = w * 8 + i;
    int row = issue * 4 + r4;
    int g = cs ^ (row & 7);
    gl2lds16(A + (size_t)(rowBase + row) * 128 + g * 8, As + issue * 512);
    gl2lds16(W + (size_t)(colBase + row) * 128 + g * 8, Bs + issue * 512);
  }
  __syncthreads();

  int fr = lane & 15, fq = lane >> 4;
#pragma unroll
  for (int ks = 0; ks < 4; ks++) {
    bf16x8 af[4], bf[4];
#pragma unroll
    for (int mi = 0; mi < 4; mi++) {
      int row = wr * 64 + mi * 16 + fr;
      int kq = (ks * 4 + fq) ^ (row & 7);
      af[mi] = *(const bf16x8*)(As + row * 128 + kq * 8);
    }
#pragma unroll
    for (int ni = 0; ni < 4; ni++) {
      int row = wc * 64 + ni * 16 + fr;
      int kq = (ks * 4 + fq) ^ (row & 7);
      bf[ni] = *(const bf16x8*)(Bs + row * 128 + kq * 8);
    }
#pragma unroll
    for (int mi = 0; mi < 4; mi++)
#pragma unroll
      for (int ni = 0; ni < 4; ni++)
        acc[mi][ni] = __builtin_amdgcn_mfma_f32_16x16x32_bf16(
            af[mi], bf[ni], acc[mi][ni], 0, 0, 0);
  }

  int cl = lane & 15, quad = lane >> 4;
#pragma unroll
  for (int ni = 0; ni < 4; ni++) {
    int col = colBase + wc * 64 + ni * 16 + cl;
    float bv = bias[col];
#pragma unroll
    for (int mi = 0; mi < 4; mi++) {
      int row0 = rowBase + wr * 64 + mi * 16 + quad * 4;
#pragma unroll
      for (int r = 0; r < 4; r++) {
        float v = acc[mi][ni][r] + bv;
        out[(size_t)(row0 + r) * M + col] = f2bf(v);
      }
    }
  }
}

// ---------------------------------------------------------------------------
// GEMM (64-row tile, M=128, K=128) + residual + LayerNorm, register epilogue.
// ---------------------------------------------------------------------------
__global__ __launch_bounds__(256) void gemm_ln(
    const unsigned short* __restrict__ A, const unsigned short* __restrict__ W,
    const float* __restrict__ bias, float* __restrict__ xio,
    unsigned short* __restrict__ xbo, const float* __restrict__ lng,
    const float* __restrict__ lnb, int K) {
  __shared__ __align__(16) unsigned short As[64 * 64];
  __shared__ __align__(16) unsigned short Bs[128 * 64];
  __shared__ float psum[4][64], psq[4][64];
  __shared__ float2 stats[64];
  int tid = threadIdx.x;
  int w = tid >> 6, lane = tid & 63;
  int rowBase = blockIdx.x * 64;
  f32x4 acc[4][2];
#pragma unroll
  for (int i = 0; i < 4; i++)
#pragma unroll
    for (int j = 0; j < 2; j++) acc[i][j] = (f32x4){0.f, 0.f, 0.f, 0.f};

  int r8 = lane >> 3;
  int gq = (lane & 7) ^ r8;
  int fr = lane & 15, fq = lane >> 4;

  for (int k0 = 0; k0 < K; k0 += 64) {
#pragma unroll
    for (int i = 0; i < 2; i++) {
      int issue = w * 2 + i;
      int row = issue * 8 + r8;
      gl2lds16(A + (size_t)(rowBase + row) * K + k0 + gq * 8, As + issue * 512);
    }
#pragma unroll
    for (int i = 0; i < 4; i++) {
      int issue = w * 4 + i;
      int row = issue * 8 + r8;
      gl2lds16(W + (size_t)row * K + k0 + gq * 8, Bs + issue * 512);
    }
    __syncthreads();
#pragma unroll
    for (int ks = 0; ks < 2; ks++) {
      bf16x8 af[4], bf[2];
#pragma unroll
      for (int mi = 0; mi < 4; mi++) {
        int row = mi * 16 + fr;
        int kq = (ks * 4 + fq) ^ (row & 7);
        af[mi] = *(const bf16x8*)(As + row * 64 + kq * 8);
      }
#pragma unroll
      for (int ni = 0; ni < 2; ni++) {
        int row = w * 32 + ni * 16 + fr;
        int kq = (ks * 4 + fq) ^ (row & 7);
        bf[ni] = *(const bf16x8*)(Bs + row * 64 + kq * 8);
      }
#pragma unroll
      for (int mi = 0; mi < 4; mi++)
#pragma unroll
        for (int ni = 0; ni < 2; ni++)
          acc[mi][ni] = __builtin_amdgcn_mfma_f32_16x16x32_bf16(
              af[mi], bf[ni], acc[mi][ni], 0, 0, 0);
    }
    __syncthreads();
  }

  int cl = lane & 15, quad = lane >> 4;
  float vv[4][2][4];
#pragma unroll
  for (int ni = 0; ni < 2; ni++) {
    int col = w * 32 + ni * 16 + cl;
    float bv = bias[col];
#pragma unroll
    for (int mi = 0; mi < 4; mi++) {
#pragma unroll
      for (int r = 0; r < 4; r++) {
        int row = mi * 16 + quad * 4 + r;
        vv[mi][ni][r] =
            acc[mi][ni][r] + bv + xio[(size_t)(rowBase + row) * 128 + col];
      }
    }
  }
  float sums[4][4], sqs[4][4];
#pragma unroll
  for (int mi = 0; mi < 4; mi++)
#pragma unroll
    for (int r = 0; r < 4; r++) {
      float a = vv[mi][0][r], b = vv[mi][1][r];
      sums[mi][r] = a + b;
      sqs[mi][r] = a * a + b * b;
    }
#pragma unroll
  for (int d = 1; d < 16; d <<= 1) {
#pragma unroll
    for (int mi = 0; mi < 4; mi++)
#pragma unroll
      for (int r = 0; r < 4; r++) {
        sums[mi][r] += __shfl_xor(sums[mi][r], d, 64);
        sqs[mi][r] += __shfl_xor(sqs[mi][r], d, 64);
      }
  }
  if (cl == 0) {
#pragma unroll
    for (int mi = 0; mi < 4; mi++)
#pragma unroll
      for (int r = 0; r < 4; r++) {
        int row = mi * 16 + quad * 4 + r;
        psum[w][row] = sums[mi][r];
        psq[w][row] = sqs[mi][r];
      }
  }
  __syncthreads();
  if (tid < 64) {
    float S = psum[0][tid] + psum[1][tid] + psum[2][tid] + psum[3][tid];
    float Q = psq[0][tid] + psq[1][tid] + psq[2][tid] + psq[3][tid];
    float m = S * (1.f / 128.f);
    float var = Q * (1.f / 128.f) - m * m;
    stats[tid] = make_float2(m, rsqrtf(var + 1e-5f));
  }
  __syncthreads();
#pragma unroll
  for (int ni = 0; ni < 2; ni++) {
    int col = w * 32 + ni * 16 + cl;
    float gl = lng[col], bl = lnb[col];
#pragma unroll
    for (int mi = 0; mi < 4; mi++) {
#pragma unroll
      for (int r = 0; r < 4; r++) {
        int row = mi * 16 + quad * 4 + r;
        float2 st = stats[row];
        float y = (vv[mi][ni][r] - st.x) * st.y * gl + bl;
        size_t o = (size_t)(rowBase + row) * 128 + col;
        xio[o] = y;
        xbo[o] = f2bf(y);
      }
    }
  }
}

// ---------------------------------------------------------------------------
// Fused FFN + residual + LN: x = LN(x + relu(x@w1^T+b1)@w2^T + b2).
// 64-row tile per block, 16 hidden chunks of 128. h re-fragmented via LDS.
// ---------------------------------------------------------------------------
__global__ __launch_bounds__(256) void ffn_ln(
    const unsigned short* __restrict__ xbi,
    const unsigned short* __restrict__ w1, const float* __restrict__ b1,
    const unsigned short* __restrict__ w2, const float* __restrict__ b2,
    float* __restrict__ xio, unsigned short* __restrict__ xbo,
    const float* __restrict__ lng, const float* __restrict__ lnb) {
  __shared__ __align__(16) unsigned short Xs[64 * 128];    // 16 KB
  __shared__ __align__(16) unsigned short W1s[128 * 128];  // 32 KB
  __shared__ __align__(16) unsigned short W2s[128 * 128];  // 32 KB
  __shared__ __align__(16) unsigned short Hs[64 * 136];    // 17 KB, 272B rows
  __shared__ float psum[4][64], psq[4][64];
  __shared__ float2 stats[64];
  int tid = threadIdx.x, w = tid >> 6, lane = tid & 63;
  int rowBase = blockIdx.x * 64;
  int r4 = lane >> 4, cs = lane & 15;
  int fr = lane & 15, fq = lane >> 4;
  int cl = fr, quad = fq;

  // stage X once: 64 rows x 256B
#pragma unroll
  for (int i = 0; i < 4; i++) {
    int issue = w * 4 + i;
    int row = issue * 4 + r4;
    int g = cs ^ (row & 7);
    gl2lds16(xbi + (size_t)(rowBase + row) * 128 + g * 8, Xs + issue * 512);
  }

  f32x4 acc2[4][2];
#pragma unroll
  for (int i = 0; i < 4; i++)
#pragma unroll
    for (int j = 0; j < 2; j++) acc2[i][j] = (f32x4){0.f, 0.f, 0.f, 0.f};

  for (int c = 0; c < 16; c++) {
    // stage w1 chunk [c*128..+128][128], w2 chunk [0..128][c*128..+128]
#pragma unroll
    for (int i = 0; i < 8; i++) {
      int issue = w * 8 + i;
      int row = issue * 4 + r4;
      int g = cs ^ (row & 7);
      gl2lds16(w1 + (size_t)(c * 128 + row) * 128 + g * 8, W1s + issue * 512);
      gl2lds16(w2 + (size_t)row * 2048 + c * 128 + g * 8, W2s + issue * 512);
    }
    __syncthreads();

    // ff1: wave w computes h cols [32w, 32w+32) for all 64 rows
    f32x4 acc1[4][2];
#pragma unroll
    for (int i = 0; i < 4; i++)
#pragma unroll
      for (int j = 0; j < 2; j++) acc1[i][j] = (f32x4){0.f, 0.f, 0.f, 0.f};
#pragma unroll
    for (int ks = 0; ks < 4; ks++) {
      bf16x8 af[4], bf[2];
#pragma unroll
      for (int mi = 0; mi < 4; mi++) {
        int row = mi * 16 + fr;
        int kq = (ks * 4 + fq) ^ (row & 7);
        af[mi] = *(const bf16x8*)(Xs + row * 128 + kq * 8);
      }
#pragma unroll
      for (int ni = 0; ni < 2; ni++) {
        int row = w * 32 + ni * 16 + fr;
        int kq = (ks * 4 + fq) ^ (row & 7);
        bf[ni] = *(const bf16x8*)(W1s + row * 128 + kq * 8);
      }
#pragma unroll
      for (int mi = 0; mi < 4; mi++)
#pragma unroll
        for (int ni = 0; ni < 2; ni++)
          acc1[mi][ni] = __builtin_amdgcn_mfma_f32_16x16x32_bf16(
              af[mi], bf[ni], acc1[mi][ni], 0, 0, 0);
    }
    // bias + relu -> Hs (bf16, stride 136)
#pragma unroll
    for (int ni = 0; ni < 2; ni++) {
      int col = w * 32 + ni * 16 + cl;
      float bv = b1[c * 128 + col];
#pragma unroll
      for (int mi = 0; mi < 4; mi++)
#pragma unroll
        for (int r = 0; r < 4; r++) {
          int row = mi * 16 + quad * 4 + r;
          Hs[row * 136 + col] = f2bf(fmaxf(acc1[mi][ni][r] + bv, 0.f));
        }
    }
    __syncthreads();

    // ff2: acc2 += H[64x128] @ W2s[128x128]^T, wave w -> out cols [32w..+32)
#pragma unroll
    for (int ks = 0; ks < 4; ks++) {
      bf16x8 af[4], bf[2];
#pragma unroll
      for (int mi = 0; mi < 4; mi++) {
        int row = mi * 16 + fr;
        af[mi] = *(const bf16x8*)(Hs + row * 136 + ks * 32 + fq * 8);
      }
#pragma unroll
      for (int ni = 0; ni < 2; ni++) {
        int row = w * 32 + ni * 16 + fr;
        int kq = (ks * 4 + fq) ^ (row & 7);
        bf[ni] = *(const bf16x8*)(W2s + row * 128 + kq * 8);
      }
#pragma unroll
      for (int mi = 0; mi < 4; mi++)
#pragma unroll
        for (int ni = 0; ni < 2; ni++)
          acc2[mi][ni] = __builtin_amdgcn_mfma_f32_16x16x32_bf16(
              af[mi], bf[ni], acc2[mi][ni], 0, 0, 0);
    }
    __syncthreads();
  }

  // epilogue: + b2 + residual, LayerNorm, write fp32 + bf16
  float vv[4][2][4];
#pragma unroll
  for (int ni = 0; ni < 2; ni++) {
    int col = w * 32 + ni * 16 + cl;
    float bv = b2[col];
#pragma unroll
    for (int mi = 0; mi < 4; mi++)
#pragma unroll
      for (int r = 0; r < 4; r++) {
        int row = mi * 16 + quad * 4 + r;
        vv[mi][ni][r] =
            acc2[mi][ni][r] + bv + xio[(size_t)(rowBase + row) * 128 + col];
      }
  }
  float sums[4][4], sqs[4][4];
#pragma unroll
  for (int mi = 0; mi < 4; mi++)
#pragma unroll
    for (int r = 0; r < 4; r++) {
      float a = vv[mi][0][r], b = vv[mi][1][r];
      sums[mi][r] = a + b;
      sqs[mi][r] = a * a + b * b;
    }
#pragma unroll
  for (int d = 1; d < 16; d <<= 1) {
#pragma unroll
    for (int mi = 0; mi < 4; mi++)
#pragma unroll
      for (int r = 0; r < 4; r++) {
        sums[mi][r] += __shfl_xor(sums[mi][r], d, 64);
        sqs[mi][r] += __shfl_xor(sqs[mi][r], d, 64);
      }
  }
  if (cl == 0) {
#pragma unroll
    for (int mi = 0; mi < 4; mi++)
#pragma unroll
      for (int r = 0; r < 4; r++) {
        int row = mi * 16 + quad * 4 + r;
        psum[w][row] = sums[mi][r];
        psq[w][row] = sqs[mi][r];
      }
  }
  __syncthreads();
  if (tid < 64) {
    float S = psum[0][tid] + psum[1][tid] + psum[2][tid] + psum[3][tid];
    float Q = psq[0][tid] + psq[1][tid] + psq[2][tid] + psq[3][tid];
    float m = S * (1.f / 128.f);
    float var = Q * (1.f / 128.f) - m * m;
    stats[tid] = make_float2(m, rsqrtf(var + 1e-5f));
  }
  __syncthreads();
#pragma unroll
  for (int ni = 0; ni < 2; ni++) {
    int col = w * 32 + ni * 16 + cl;
    float gl = lng[col], bl = lnb[col];
#pragma unroll
    for (int mi = 0; mi < 4; mi++)
#pragma unroll
      for (int r = 0; r < 4; r++) {
        int row = mi * 16 + quad * 4 + r;
        float2 st = stats[row];
        float y = (vv[mi][ni][r] - st.x) * st.y * gl + bl;
        size_t o = (size_t)(rowBase + row) * 128 + col;
        xio[o] = y;
        xbo[o] = f2bf(y);
      }
  }
}

// ---------------------------------------------------------------------------
// Attention per (b,h), register-tiled: thread (w,lane) owns row s=lane.
// Q row in 4xfloat4 regs; K/V rows read as wave-uniform b128 broadcasts.
// ---------------------------------------------------------------------------
__global__ __launch_bounds__(256) void attn_kernel(
    const unsigned short* __restrict__ qkv, unsigned short* __restrict__ ao) {
  __shared__ float Qs[64 * 20], Ks[64 * 20], Vs[64 * 20];
  __shared__ float SC[64 * 65];
  int tid = threadIdx.x, w = tid >> 6, lane = tid & 63;
  int b = blockIdx.x & 255, h = blockIdx.x >> 8;
  const unsigned short* base = qkv + b * 384 + h * 16;
#pragma unroll
  for (int i = 0; i < 4; i++) {
    int idx = tid + i * 256;
    int s = idx >> 4, d = idx & 15;
    const unsigned short* p = base + (size_t)s * (256 * 384);
    Qs[s * 20 + d] = bf2f(p[d]);
    Ks[s * 20 + d] = bf2f(p[128 + d]);
    Vs[s * 20 + d] = bf2f(p[256 + d]);
  }
  __syncthreads();
  {
    const float4* qp = (const float4*)(Qs + lane * 20);
    float4 q0 = qp[0], q1 = qp[1], q2 = qp[2], q3 = qp[3];
#pragma unroll
    for (int j = 0; j < 16; j++) {
      int t2 = w * 16 + j;
      const float4* kp = (const float4*)(Ks + t2 * 20);
      float4 k0 = kp[0], k1 = kp[1], k2 = kp[2], k3 = kp[3];
      float a0 = q0.x * k0.x + q0.y * k0.y + q0.z * k0.z + q0.w * k0.w;
      float a1 = q1.x * k1.x + q1.y * k1.y + q1.z * k1.z + q1.w * k1.w;
      float a2 = q2.x * k2.x + q2.y * k2.y + q2.z * k2.z + q2.w * k2.w;
      float a3 = q3.x * k3.x + q3.y * k3.y + q3.z * k3.z + q3.w * k3.w;
      SC[lane * 65 + t2] = (a0 + a1 + a2 + a3) * 0.25f;
    }
  }
  __syncthreads();
  {
    int s = tid >> 2, seg = tid & 3;
    float* rowp = SC + s * 65 + seg * 16;
    float m = -1e30f;
#pragma unroll
    for (int j = 0; j < 16; j++) m = fmaxf(m, rowp[j]);
    m = fmaxf(m, __shfl_xor(m, 1));
    m = fmaxf(m, __shfl_xor(m, 2));
    float pv[16], sum = 0.f;
#pragma unroll
    for (int j = 0; j < 16; j++) { pv[j] = expf(rowp[j] - m); sum += pv[j]; }
    sum += __shfl_xor(sum, 1);
    sum += __shfl_xor(sum, 2);
    float rinv = 1.f / sum;
#pragma unroll
    for (int j = 0; j < 16; j++) rowp[j] = pv[j] * rinv;
  }
  __syncthreads();
  {
    float a0 = 0.f, a1 = 0.f, a2 = 0.f, a3 = 0.f;
    const float* scr = SC + lane * 65;
#pragma unroll 8
    for (int t2 = 0; t2 < 64; t2++) {
      float p = scr[t2];
      float4 v = *(const float4*)(Vs + t2 * 20 + w * 4);
      a0 += p * v.x; a1 += p * v.y; a2 += p * v.z; a3 += p * v.w;
    }
    ushort4 o;
    o.x = f2bf(a0); o.y = f2bf(a1); o.z = f2bf(a2); o.w = f2bf(a3);
    *(ushort4*)(ao + (size_t)(lane * 256 + b) * 128 + h * 16 + w * 4) = o;
  }
}

// ---------------------------------------------------------------------------
// Set2Set (6 steps) + memory LSTM + lin1 + lin3. One 512-thread block per
// segment. x staged in LDS (stride 65 dwords: all reads <=2-way conflicts).
// ---------------------------------------------------------------------------
__global__ __launch_bounds__(512) void s2s_kernel(
    const unsigned short* __restrict__ xb,
    const unsigned short* __restrict__ wihb,
    const unsigned short* __restrict__ whhb,
    const float* __restrict__ bih, const float* __restrict__ bhh,
    const float* __restrict__ mwih, const float* __restrict__ mbih,
    const float* __restrict__ mbhh,
    const float* __restrict__ l1w, const float* __restrict__ l1b,
    const float* __restrict__ l3w, const float* __restrict__ l3b,
    float* __restrict__ out) {
  __shared__ __align__(16) unsigned xl[256 * 65];  // 65 KB
  __shared__ __align__(16) unsigned qu[128];       // q_star bf16 pairs
  __shared__ __align__(16) float qsf[256];         // q_star fp32
  __shared__ __align__(16) float cst[128];
  __shared__ __align__(16) float gates[512];
  __shared__ __align__(16) float red[256];
  __shared__ __align__(16) float aw[256];
  int s = blockIdx.x, t = threadIdx.x, lane = t & 63, w = t >> 6;
  const uint4* xs4 = (const uint4*)(xb + (size_t)s * 32768);
  // stage x into LDS, stride 65 dwords per row
#pragma unroll
  for (int it = 0; it < 8; it++) {
    int f = it * 512 + t;  // 16B-chunk index
    uint4 v = xs4[f];
    int n = f >> 4, jc = (f & 15) * 4;
    unsigned* dst = xl + n * 65 + jc;
    dst[0] = v.x; dst[1] = v.y; dst[2] = v.z; dst[3] = v.w;
  }
  if (t < 128) cst[t] = 0.f;
  __syncthreads();

  const uint4* w1v = (const uint4*)(wihb + (size_t)t * 256);  // 32 x 16B
  const uint4* w2v = (const uint4*)(whhb + (size_t)t * 128);  // 16 x 16B
  const uint4* q4 = (const uint4*)qu;
  float bsum = bih[t] + bhh[t];

  for (int step = 0; step < 6; step++) {
    // gates
    if (step > 0) {
      float a0 = 0.f, a1 = 0.f, a2 = 0.f, a3 = 0.f;
#pragma unroll 8
      for (int i = 0; i < 32; i++) {
        uint4 wv = w1v[i], qv = q4[i];
        a0 += uplo(wv.x) * uplo(qv.x) + uphi(wv.x) * uphi(qv.x);
        a1 += uplo(wv.y) * uplo(qv.y) + uphi(wv.y) * uphi(qv.y);
        a2 += uplo(wv.z) * uplo(qv.z) + uphi(wv.z) * uphi(qv.z);
        a3 += uplo(wv.w) * uplo(qv.w) + uphi(wv.w) * uphi(qv.w);
      }
#pragma unroll 8
      for (int i = 0; i < 16; i++) {
        uint4 wv = w2v[i], qv = q4[i];
        a0 += uplo(wv.x) * uplo(qv.x) + uphi(wv.x) * uphi(qv.x);
        a1 += uplo(wv.y) * uplo(qv.y) + uphi(wv.y) * uphi(qv.y);
        a2 += uplo(wv.z) * uplo(qv.z) + uphi(wv.z) * uphi(qv.z);
        a3 += uplo(wv.w) * uplo(qv.w) + uphi(wv.w) * uphi(qv.w);
      }
      gates[t] = bsum + ((a0 + a1) + (a2 + a3));
    } else {
      gates[t] = bsum;
    }
    __syncthreads();
    if (t < 128) {
      float ig = sigf(gates[t]), fg = sigf(gates[128 + t]);
      float gg = tanhf(gates[256 + t]), og = sigf(gates[384 + t]);
      float cn = fg * cst[t] + ig * gg;
      cst[t] = cn;
      float hn = og * tanhf(cn);
      qsf[t] = hn;
      float hp = __shfl_xor(hn, 1, 64);
      if ((t & 1) == 0) qu[t >> 1] = packbf(hn, hp);
    }
    __syncthreads();
    if (step > 0) {
      // e[n] = x[n].h : 2 threads per row, one shuffle
      int n = t >> 1, p = t & 1;
      const unsigned* xr = xl + n * 65 + p * 32;
      float e0 = 0.f, e1 = 0.f;
#pragma unroll 8
      for (int i = 0; i < 32; i++) {
        unsigned xv = xr[i];
        unsigned hv = qu[p * 32 + i];
        e0 += uplo(xv) * uplo(hv);
        e1 += uphi(xv) * uphi(hv);
      }
      float e = e0 + e1;
      e += __shfl_xor(e, 1, 64);
      if (p == 0) red[n] = e;
      __syncthreads();
      // softmax over 256 — redundant per-wave reduce
      float v0 = red[lane], v1 = red[64 + lane];
      float v2 = red[128 + lane], v3 = red[192 + lane];
      float m = fmaxf(fmaxf(v0, v1), fmaxf(v2, v3));
#pragma unroll
      for (int d = 1; d < 64; d <<= 1) m = fmaxf(m, __shfl_xor(m, d, 64));
      float p0 = expf(v0 - m), p1 = expf(v1 - m);
      float p2 = expf(v2 - m), p3 = expf(v3 - m);
      float ss = p0 + p1 + p2 + p3;
#pragma unroll
      for (int d = 1; d < 64; d <<= 1) ss += __shfl_xor(ss, d, 64);
      float Sinv = 1.f / ss;
      if (w == 0) {
        aw[lane] = p0 * Sinv; aw[64 + lane] = p1 * Sinv;
        aw[128 + lane] = p2 * Sinv; aw[192 + lane] = p3 * Sinv;
      }
    } else {
      if (t < 256) aw[t] = 1.f / 256.f;
    }
    __syncthreads();
    // r[d] = sum_n aw[n]*x[n][d]
    {
      int d = t & 127, grp = t >> 7;
      const unsigned* xc = xl + grp * 64 * 65 + (d >> 1);
      int hi = d & 1;
      const float* ap = aw + grp * 64;
      float r = 0.f;
#pragma unroll 8
      for (int n2 = 0; n2 < 64; n2++) {
        unsigned u = xc[n2 * 65];
        r += ap[n2] * (hi ? uphi(u) : uplo(u));
      }
      gates[t] = r;
    }
    __syncthreads();
    if (t < 128) {
      float rd = gates[t] + gates[128 + t] + gates[256 + t] + gates[384 + t];
      qsf[128 + t] = rd;
      float rp = __shfl_xor(rd, 1, 64);
      if ((t & 1) == 0) qu[64 + (t >> 1)] = packbf(rd, rp);
    }
    __syncthreads();
  }
  // memory LSTM (zero init state), fp32 weights
  {
    float acc = mbih[t] + mbhh[t];
    const float4* w4 = (const float4*)(mwih + (size_t)t * 256);
    const float4* qq = (const float4*)qsf;
#pragma unroll 8
    for (int k = 0; k < 64; k++) {
      float4 a = w4[k], b = qq[k];
      acc += a.x * b.x + a.y * b.y + a.z * b.z + a.w * b.w;
    }
    gates[t] = acc;
  }
  __syncthreads();
  if (t < 128) {
    float ig = sigf(gates[t]);
    float gg = tanhf(gates[256 + t]);
    float og = sigf(gates[384 + t]);
    float cx = ig * gg;
    float hx = og * tanhf(cx);
    cst[t] = hx;
    out[64 + s * 128 + t] = hx;
    out[64 + 8192 + s * 128 + t] = cx;
  }
  __syncthreads();
  if (t < 128) {
    float acc = l1b[t];
    const float4* w4 = (const float4*)(l1w + (size_t)t * 128);
    const float4* h4 = (const float4*)cst;
#pragma unroll 8
    for (int k = 0; k < 32; k++) {
      float4 a = w4[k], b = h4[k];
      acc += a.x * b.x + a.y * b.y + a.z * b.z + a.w * b.w;
    }
    red[t] = fmaxf(acc, 0.f) * l3w[t];
  } else if (t < 256) {
    red[t] = 0.f;
  }
  __syncthreads();
  for (int off = 128; off; off >>= 1) {
    if (t < off) red[t] += red[t + off];
    __syncthreads();
  }
  if (t == 0) out[s] = red[0] + l3b[0];
}

// ---------------------------------------------------------------------------
extern "C" void kernel_launch(void* const* d_in, const int* in_sizes, int n_in,
                              void* d_out, int out_size, void* d_ws,
                              size_t ws_size, hipStream_t stream) {
  const float* data       = (const float*)d_in[0];
  const float* lin0_w     = (const float*)d_in[1];
  const float* lin0_b     = (const float*)d_in[2];
  const float* attn_in_w  = (const float*)d_in[3];
  const float* attn_in_b  = (const float*)d_in[4];
  const float* attn_out_w = (const float*)d_in[5];
  const float* attn_out_b = (const float*)d_in[6];
  const float* ln1_g      = (const float*)d_in[7];
  const float* ln1_b      = (const float*)d_in[8];
  const float* ff_w1      = (const float*)d_in[9];
  const float* ff_b1      = (const float*)d_in[10];
  const float* ff_w2      = (const float*)d_in[11];
  const float* ff_b2      = (const float*)d_in[12];
  const float* ln2_g      = (const float*)d_in[13];
  const float* ln2_b      = (const float*)d_in[14];
  const float* s2s_wih    = (const float*)d_in[15];
  const float* s2s_whh    = (const float*)d_in[16];
  const float* s2s_bih    = (const float*)d_in[17];
  const float* s2s_bhh    = (const float*)d_in[18];
  const float* mem_wih    = (const float*)d_in[19];
  const float* mem_bih    = (const float*)d_in[21];
  const float* mem_bhh    = (const float*)d_in[22];
  const float* lin1_w     = (const float*)d_in[23];
  const float* lin1_b     = (const float*)d_in[24];
  const float* lin3_w     = (const float*)d_in[25];
  const float* lin3_b     = (const float*)d_in[26];
  float* out = (float*)d_out;

  char* p = (char*)d_ws;
  float* x = (float*)p;                      p += (size_t)16384 * 128 * 4;
  unsigned short* xb = (unsigned short*)p;   p += (size_t)16384 * 128 * 2;
  unsigned short* qkvb = (unsigned short*)p; p += (size_t)16384 * 384 * 2;
  unsigned short* aob = (unsigned short*)p;  p += (size_t)16384 * 128 * 2;
  unsigned short* wqkv = (unsigned short*)p; p += (size_t)294912 * 2;
  unsigned short* wout = (unsigned short*)p; p += (size_t)98304 * 2;
  unsigned short* w1b = (unsigned short*)p;  p += (size_t)1572864 * 2;
  unsigned short* w2b = (unsigned short*)p;  p += (size_t)1572864 * 2;
  unsigned short* wihb = (unsigned short*)p; p += (size_t)131072 * 2;
  unsigned short* whhb = (unsigned short*)p; p += (size_t)65536 * 2;

  convw_kernel<<<14592, 256, 0, stream>>>(attn_in_w, attn_out_w, ff_w1, ff_w2,
                                          s2s_wih, s2s_whh,
                                          wqkv, wout, w1b, w2b, wihb, whhb);
  lin0_kernel<<<8192, 256, 0, stream>>>(data, lin0_w, lin0_b, x, xb);

  for (int l = 0; l < 6; l++) {
    gemm_k128<<<dim3(128, 3), 256, 0, stream>>>(
        xb, wqkv + (size_t)l * 49152, attn_in_b + l * 384, qkvb, 384);
    attn_kernel<<<2048, 256, 0, stream>>>(qkvb, aob);
    gemm_ln<<<256, 256, 0, stream>>>(
        aob, wout + (size_t)l * 16384, attn_out_b + l * 128, x, xb,
        ln1_g + l * 128, ln1_b + l * 128, 128);
    ffn_ln<<<256, 256, 0, stream>>>(
        xb, w1b + (size_t)l * 262144, ff_b1 + l * 2048,
        w2b + (size_t)l * 262144, ff_b2 + l * 128, x, xb,
        ln2_g + l * 128, ln2_b + l * 128);
  }

  s2s_kernel<<<64, 512, 0, stream>>>(
      xb, wihb, whhb, s2s_bih, s2s_bhh,
      mem_wih, mem_bih, mem_bhh, lin1_w, lin1_b, lin3_w, lin3_b, out);
}

// Round 5
// 625.570 us; speedup vs baseline: 3.9863x; 1.1400x over previous
//
#include <hip/hip_runtime.h>
#include <math.h>

// S=64 segments(seq), B=256 atoms(batch), N=16384 rows, D=128, H=8, HD=16,
// DFF=2048, NL=6.  Heavy GEMMs: bf16 MFMA 16x16x32, fp32 accum.
// s2s path: f16 weights/activations + v_dot2_f32_f16, fp32 accum.

typedef __attribute__((ext_vector_type(8))) short bf16x8;
typedef __attribute__((ext_vector_type(4))) float f32x4;
typedef _Float16 __attribute__((ext_vector_type(2))) h16x2;

__device__ __forceinline__ unsigned short f2bf(float f) {
  union { float f; unsigned u; } x; x.f = f;
  unsigned r = x.u + 0x7fff + ((x.u >> 16) & 1);
  return (unsigned short)(r >> 16);
}
__device__ __forceinline__ float bf2f(unsigned short u) {
  union { unsigned u; float f; } x; x.u = ((unsigned)u) << 16;
  return x.f;
}
__device__ __forceinline__ float uplo(unsigned u) {
  union { unsigned u; float f; } x; x.u = u << 16; return x.f;
}
__device__ __forceinline__ float uphi(unsigned u) {
  union { unsigned u; float f; } x; x.u = u & 0xffff0000u; return x.f;
}
__device__ __forceinline__ unsigned short f2h(float f) {
  union { _Float16 h; unsigned short s; } x; x.h = (_Float16)f; return x.s;
}
__device__ __forceinline__ unsigned packh(float a, float b) {
  return (unsigned)f2h(a) | ((unsigned)f2h(b) << 16);
}
__device__ __forceinline__ float hlo(unsigned u) {
  union { unsigned short s; _Float16 h; } x; x.s = (unsigned short)(u & 0xffff);
  return (float)x.h;
}
__device__ __forceinline__ float hhi(unsigned u) {
  union { unsigned short s; _Float16 h; } x; x.s = (unsigned short)(u >> 16);
  return (float)x.h;
}
__device__ __forceinline__ float fdot2u(unsigned a, unsigned b, float c) {
#if __has_builtin(__builtin_amdgcn_fdot2)
  union U { unsigned u; h16x2 h; };
  U x, y; x.u = a; y.u = b;
  return __builtin_amdgcn_fdot2(x.h, y.h, c, false);
#else
  return c + hlo(a) * hlo(b) + hhi(a) * hhi(b);
#endif
}
__device__ __forceinline__ float sigf(float x) { return 1.f / (1.f + expf(-x)); }

// async 16B global->LDS; LDS base wave-uniform (+ lane*16 implicit).
__device__ __forceinline__ void gl2lds16(const void* g, void* l) {
  __builtin_amdgcn_global_load_lds(
      (const __attribute__((address_space(1))) unsigned int*)g,
      (__attribute__((address_space(3))) unsigned int*)l, 16, 0, 0);
}

// ---------------------------------------------------------------------------
// weight conversion: bf16 for MFMA GEMMs, f16 for the s2s tail.
// aiw 294912 | aow 98304 | w1 1572864 | w2 1572864 (bf16)
// | wih 131072 | whh 65536 | mwih 131072 (f16)   -> total 3866624
// ---------------------------------------------------------------------------
__global__ __launch_bounds__(256) void convw_kernel(
    const float* __restrict__ aiw, const float* __restrict__ aow,
    const float* __restrict__ w1, const float* __restrict__ w2,
    const float* __restrict__ wih, const float* __restrict__ whh,
    const float* __restrict__ mwih,
    unsigned short* __restrict__ o0, unsigned short* __restrict__ o1,
    unsigned short* __restrict__ o2, unsigned short* __restrict__ o3,
    unsigned short* __restrict__ o4, unsigned short* __restrict__ o5,
    unsigned short* __restrict__ o6) {
  int i = blockIdx.x * 256 + threadIdx.x;
  if (i < 294912) {
    o0[i] = f2bf(aiw[i]);
  } else if (i < 393216) {
    int j = i - 294912; o1[j] = f2bf(aow[j]);
  } else if (i < 1966080) {
    int j = i - 393216; o2[j] = f2bf(w1[j]);
  } else if (i < 3538944) {
    int j = i - 1966080; o3[j] = f2bf(w2[j]);
  } else if (i < 3670016) {
    int j = i - 3538944; o4[j] = f2h(wih[j]);
  } else if (i < 3735552) {
    int j = i - 3670016; o5[j] = f2h(whh[j]);
  } else {
    int j = i - 3735552; o6[j] = f2h(mwih[j]);
  }
}

// ---------------------------------------------------------------------------
// lin0: x = relu(data @ w^T + b), writes fp32 x and bf16 xb
// ---------------------------------------------------------------------------
__global__ __launch_bounds__(256) void lin0_kernel(
    const float* __restrict__ data, const float* __restrict__ w,
    const float* __restrict__ b, float* __restrict__ x,
    unsigned short* __restrict__ xb) {
  int i = blockIdx.x * 256 + threadIdx.x;
  int n = i >> 7, d = i & 127;
  float v = b[d] + data[n * 3 + 0] * w[d * 3 + 0]
                 + data[n * 3 + 1] * w[d * 3 + 1]
                 + data[n * 3 + 2] * w[d * 3 + 2];
  v = fmaxf(v, 0.0f);
  x[i] = v;
  xb[i] = f2bf(v);
}

// ---------------------------------------------------------------------------
// Single-shot GEMM, K=128: out[N,M] = A[N,128] @ W[M,128]^T + b. 128x128 tile,
// 4 waves 2x2, whole K staged once, ONE barrier. XOR chunk swizzle.
// ---------------------------------------------------------------------------
__global__ __launch_bounds__(256) void gemm_k128(
    const unsigned short* __restrict__ A, const unsigned short* __restrict__ W,
    const float* __restrict__ bias, unsigned short* __restrict__ out, int M) {
  __shared__ __align__(16) unsigned short As[128 * 128];
  __shared__ __align__(16) unsigned short Bs[128 * 128];
  int tid = threadIdx.x;
  int w = tid >> 6, lane = tid & 63;
  int wr = w >> 1, wc = w & 1;
  int rowBase = blockIdx.x * 128, colBase = blockIdx.y * 128;
  f32x4 acc[4][4];
#pragma unroll
  for (int i = 0; i < 4; i++)
#pragma unroll
    for (int j = 0; j < 4; j++) acc[i][j] = (f32x4){0.f, 0.f, 0.f, 0.f};

  int r4 = lane >> 4, cs = lane & 15;
#pragma unroll
  for (int i = 0; i < 8; i++) {
    int issue = w * 8 + i;
    int row = issue * 4 + r4;
    int g = cs ^ (row & 7);
    gl2lds16(A + (size_t)(rowBase + row) * 128 + g * 8, As + issue * 512);
    gl2lds16(W + (size_t)(colBase + row) * 128 + g * 8, Bs + issue * 512);
  }
  __syncthreads();

  int fr = lane & 15, fq = lane >> 4;
#pragma unroll
  for (int ks = 0; ks < 4; ks++) {
    bf16x8 af[4], bf[4];
#pragma unroll
    for (int mi = 0; mi < 4; mi++) {
      int row = wr * 64 + mi * 16 + fr;
      int kq = (ks * 4 + fq) ^ (row & 7);
      af[mi] = *(const bf16x8*)(As + row * 128 + kq * 8);
    }
#pragma unroll
    for (int ni = 0; ni < 4; ni++) {
      int row = wc * 64 + ni * 16 + fr;
      int kq = (ks * 4 + fq) ^ (row & 7);
      bf[ni] = *(const bf16x8*)(Bs + row * 128 + kq * 8);
    }
#pragma unroll
    for (int mi = 0; mi < 4; mi++)
#pragma unroll
      for (int ni = 0; ni < 4; ni++)
        acc[mi][ni] = __builtin_amdgcn_mfma_f32_16x16x32_bf16(
            af[mi], bf[ni], acc[mi][ni], 0, 0, 0);
  }

  int cl = lane & 15, quad = lane >> 4;
#pragma unroll
  for (int ni = 0; ni < 4; ni++) {
    int col = colBase + wc * 64 + ni * 16 + cl;
    float bv = bias[col];
#pragma unroll
    for (int mi = 0; mi < 4; mi++) {
      int row0 = rowBase + wr * 64 + mi * 16 + quad * 4;
#pragma unroll
      for (int r = 0; r < 4; r++) {
        float v = acc[mi][ni][r] + bv;
        out[(size_t)(row0 + r) * M + col] = f2bf(v);
      }
    }
  }
}

// ---------------------------------------------------------------------------
// GEMM (64-row tile, M=128, K=128) + residual + LayerNorm, register epilogue.
// ---------------------------------------------------------------------------
__global__ __launch_bounds__(256) void gemm_ln(
    const unsigned short* __restrict__ A, const unsigned short* __restrict__ W,
    const float* __restrict__ bias, float* __restrict__ xio,
    unsigned short* __restrict__ xbo, const float* __restrict__ lng,
    const float* __restrict__ lnb, int K) {
  __shared__ __align__(16) unsigned short As[64 * 64];
  __shared__ __align__(16) unsigned short Bs[128 * 64];
  __shared__ float psum[4][64], psq[4][64];
  __shared__ float2 stats[64];
  int tid = threadIdx.x;
  int w = tid >> 6, lane = tid & 63;
  int rowBase = blockIdx.x * 64;
  f32x4 acc[4][2];
#pragma unroll
  for (int i = 0; i < 4; i++)
#pragma unroll
    for (int j = 0; j < 2; j++) acc[i][j] = (f32x4){0.f, 0.f, 0.f, 0.f};

  int r8 = lane >> 3;
  int gq = (lane & 7) ^ r8;
  int fr = lane & 15, fq = lane >> 4;

  for (int k0 = 0; k0 < K; k0 += 64) {
#pragma unroll
    for (int i = 0; i < 2; i++) {
      int issue = w * 2 + i;
      int row = issue * 8 + r8;
      gl2lds16(A + (size_t)(rowBase + row) * K + k0 + gq * 8, As + issue * 512);
    }
#pragma unroll
    for (int i = 0; i < 4; i++) {
      int issue = w * 4 + i;
      int row = issue * 8 + r8;
      gl2lds16(W + (size_t)row * K + k0 + gq * 8, Bs + issue * 512);
    }
    __syncthreads();
#pragma unroll
    for (int ks = 0; ks < 2; ks++) {
      bf16x8 af[4], bf[2];
#pragma unroll
      for (int mi = 0; mi < 4; mi++) {
        int row = mi * 16 + fr;
        int kq = (ks * 4 + fq) ^ (row & 7);
        af[mi] = *(const bf16x8*)(As + row * 64 + kq * 8);
      }
#pragma unroll
      for (int ni = 0; ni < 2; ni++) {
        int row = w * 32 + ni * 16 + fr;
        int kq = (ks * 4 + fq) ^ (row & 7);
        bf[ni] = *(const bf16x8*)(Bs + row * 64 + kq * 8);
      }
#pragma unroll
      for (int mi = 0; mi < 4; mi++)
#pragma unroll
        for (int ni = 0; ni < 2; ni++)
          acc[mi][ni] = __builtin_amdgcn_mfma_f32_16x16x32_bf16(
              af[mi], bf[ni], acc[mi][ni], 0, 0, 0);
    }
    __syncthreads();
  }

  int cl = lane & 15, quad = lane >> 4;
  float vv[4][2][4];
#pragma unroll
  for (int ni = 0; ni < 2; ni++) {
    int col = w * 32 + ni * 16 + cl;
    float bv = bias[col];
#pragma unroll
    for (int mi = 0; mi < 4; mi++) {
#pragma unroll
      for (int r = 0; r < 4; r++) {
        int row = mi * 16 + quad * 4 + r;
        vv[mi][ni][r] =
            acc[mi][ni][r] + bv + xio[(size_t)(rowBase + row) * 128 + col];
      }
    }
  }
  float sums[4][4], sqs[4][4];
#pragma unroll
  for (int mi = 0; mi < 4; mi++)
#pragma unroll
    for (int r = 0; r < 4; r++) {
      float a = vv[mi][0][r], b = vv[mi][1][r];
      sums[mi][r] = a + b;
      sqs[mi][r] = a * a + b * b;
    }
#pragma unroll
  for (int d = 1; d < 16; d <<= 1) {
#pragma unroll
    for (int mi = 0; mi < 4; mi++)
#pragma unroll
      for (int r = 0; r < 4; r++) {
        sums[mi][r] += __shfl_xor(sums[mi][r], d, 64);
        sqs[mi][r] += __shfl_xor(sqs[mi][r], d, 64);
      }
  }
  if (cl == 0) {
#pragma unroll
    for (int mi = 0; mi < 4; mi++)
#pragma unroll
      for (int r = 0; r < 4; r++) {
        int row = mi * 16 + quad * 4 + r;
        psum[w][row] = sums[mi][r];
        psq[w][row] = sqs[mi][r];
      }
  }
  __syncthreads();
  if (tid < 64) {
    float S = psum[0][tid] + psum[1][tid] + psum[2][tid] + psum[3][tid];
    float Q = psq[0][tid] + psq[1][tid] + psq[2][tid] + psq[3][tid];
    float m = S * (1.f / 128.f);
    float var = Q * (1.f / 128.f) - m * m;
    stats[tid] = make_float2(m, rsqrtf(var + 1e-5f));
  }
  __syncthreads();
#pragma unroll
  for (int ni = 0; ni < 2; ni++) {
    int col = w * 32 + ni * 16 + cl;
    float gl = lng[col], bl = lnb[col];
#pragma unroll
    for (int mi = 0; mi < 4; mi++) {
#pragma unroll
      for (int r = 0; r < 4; r++) {
        int row = mi * 16 + quad * 4 + r;
        float2 st = stats[row];
        float y = (vv[mi][ni][r] - st.x) * st.y * gl + bl;
        size_t o = (size_t)(rowBase + row) * 128 + col;
        xio[o] = y;
        xbo[o] = f2bf(y);
      }
    }
  }
}

// ---------------------------------------------------------------------------
// Fused FFN + residual + LN, software-pipelined: W1 double-buffered, W2
// staged during ff1 compute. 64-row tile, 16 hidden chunks of 128.
// ---------------------------------------------------------------------------
__global__ __launch_bounds__(256) void ffn_ln(
    const unsigned short* __restrict__ xbi,
    const unsigned short* __restrict__ w1, const float* __restrict__ b1,
    const unsigned short* __restrict__ w2, const float* __restrict__ b2,
    float* __restrict__ xio, unsigned short* __restrict__ xbo,
    const float* __restrict__ lng, const float* __restrict__ lnb) {
  __shared__ __align__(16) unsigned short Xs[64 * 128];       // 16 KB
  __shared__ __align__(16) unsigned short W1s[2][128 * 128];  // 64 KB
  __shared__ __align__(16) unsigned short W2s[128 * 128];     // 32 KB
  __shared__ __align__(16) unsigned short Hs[64 * 136];       // 17 KB
  __shared__ float psum[4][64], psq[4][64];
  __shared__ float2 stats[64];
  int tid = threadIdx.x, w = tid >> 6, lane = tid & 63;
  int rowBase = blockIdx.x * 64;
  int r4 = lane >> 4, cs = lane & 15;
  int fr = lane & 15, fq = lane >> 4;
  int cl = fr, quad = fq;

  // prologue: stage X + W1(0)
#pragma unroll
  for (int i = 0; i < 4; i++) {
    int issue = w * 4 + i;
    int row = issue * 4 + r4;
    int g = cs ^ (row & 7);
    gl2lds16(xbi + (size_t)(rowBase + row) * 128 + g * 8, Xs + issue * 512);
  }
#pragma unroll
  for (int i = 0; i < 8; i++) {
    int issue = w * 8 + i;
    int row = issue * 4 + r4;
    int g = cs ^ (row & 7);
    gl2lds16(w1 + (size_t)row * 128 + g * 8, W1s[0] + issue * 512);
  }
  __syncthreads();

  f32x4 acc2[4][2];
#pragma unroll
  for (int i = 0; i < 4; i++)
#pragma unroll
    for (int j = 0; j < 2; j++) acc2[i][j] = (f32x4){0.f, 0.f, 0.f, 0.f};

  for (int c = 0; c < 16; c++) {
    const unsigned short* W1cur = W1s[c & 1];
    // stage W2(c) now — flies during ff1 compute
#pragma unroll
    for (int i = 0; i < 8; i++) {
      int issue = w * 8 + i;
      int row = issue * 4 + r4;
      int g = cs ^ (row & 7);
      gl2lds16(w2 + (size_t)row * 2048 + c * 128 + g * 8, W2s + issue * 512);
    }

    // ff1: wave w computes h cols [32w, 32w+32) for all 64 rows
    f32x4 acc1[4][2];
#pragma unroll
    for (int i = 0; i < 4; i++)
#pragma unroll
      for (int j = 0; j < 2; j++) acc1[i][j] = (f32x4){0.f, 0.f, 0.f, 0.f};
#pragma unroll
    for (int ks = 0; ks < 4; ks++) {
      bf16x8 af[4], bf[2];
#pragma unroll
      for (int mi = 0; mi < 4; mi++) {
        int row = mi * 16 + fr;
        int kq = (ks * 4 + fq) ^ (row & 7);
        af[mi] = *(const bf16x8*)(Xs + row * 128 + kq * 8);
      }
#pragma unroll
      for (int ni = 0; ni < 2; ni++) {
        int row = w * 32 + ni * 16 + fr;
        int kq = (ks * 4 + fq) ^ (row & 7);
        bf[ni] = *(const bf16x8*)(W1cur + row * 128 + kq * 8);
      }
#pragma unroll
      for (int mi = 0; mi < 4; mi++)
#pragma unroll
        for (int ni = 0; ni < 2; ni++)
          acc1[mi][ni] = __builtin_amdgcn_mfma_f32_16x16x32_bf16(
              af[mi], bf[ni], acc1[mi][ni], 0, 0, 0);
    }

    // prefetch W1(c+1) — flies during Hs write
    if (c < 15) {
#pragma unroll
      for (int i = 0; i < 8; i++) {
        int issue = w * 8 + i;
        int row = issue * 4 + r4;
        int g = cs ^ (row & 7);
        gl2lds16(w1 + (size_t)(c * 128 + 128 + row) * 128 + g * 8,
                 W1s[(c + 1) & 1] + issue * 512);
      }
    }

    // bias + relu -> Hs (bf16, stride 136)
#pragma unroll
    for (int ni = 0; ni < 2; ni++) {
      int col = w * 32 + ni * 16 + cl;
      float bv = b1[c * 128 + col];
#pragma unroll
      for (int mi = 0; mi < 4; mi++)
#pragma unroll
        for (int r = 0; r < 4; r++) {
          int row = mi * 16 + quad * 4 + r;
          Hs[row * 136 + col] = f2bf(fmaxf(acc1[mi][ni][r] + bv, 0.f));
        }
    }
    __syncthreads();  // drains W2(c), W1(c+1); Hs visible

    // ff2: acc2 += H[64x128] @ W2s[128x128]^T
#pragma unroll
    for (int ks = 0; ks < 4; ks++) {
      bf16x8 af[4], bf[2];
#pragma unroll
      for (int mi = 0; mi < 4; mi++) {
        int row = mi * 16 + fr;
        af[mi] = *(const bf16x8*)(Hs + row * 136 + ks * 32 + fq * 8);
      }
#pragma unroll
      for (int ni = 0; ni < 2; ni++) {
        int row = w * 32 + ni * 16 + fr;
        int kq = (ks * 4 + fq) ^ (row & 7);
        bf[ni] = *(const bf16x8*)(W2s + row * 128 + kq * 8);
      }
#pragma unroll
      for (int mi = 0; mi < 4; mi++)
#pragma unroll
        for (int ni = 0; ni < 2; ni++)
          acc2[mi][ni] = __builtin_amdgcn_mfma_f32_16x16x32_bf16(
              af[mi], bf[ni], acc2[mi][ni], 0, 0, 0);
    }
    __syncthreads();  // Hs / W2s reusable
  }

  // epilogue: + b2 + residual, LayerNorm, write fp32 + bf16
  float vv[4][2][4];
#pragma unroll
  for (int ni = 0; ni < 2; ni++) {
    int col = w * 32 + ni * 16 + cl;
    float bv = b2[col];
#pragma unroll
    for (int mi = 0; mi < 4; mi++)
#pragma unroll
      for (int r = 0; r < 4; r++) {
        int row = mi * 16 + quad * 4 + r;
        vv[mi][ni][r] =
            acc2[mi][ni][r] + bv + xio[(size_t)(rowBase + row) * 128 + col];
      }
  }
  float sums[4][4], sqs[4][4];
#pragma unroll
  for (int mi = 0; mi < 4; mi++)
#pragma unroll
    for (int r = 0; r < 4; r++) {
      float a = vv[mi][0][r], b = vv[mi][1][r];
      sums[mi][r] = a + b;
      sqs[mi][r] = a * a + b * b;
    }
#pragma unroll
  for (int d = 1; d < 16; d <<= 1) {
#pragma unroll
    for (int mi = 0; mi < 4; mi++)
#pragma unroll
      for (int r = 0; r < 4; r++) {
        sums[mi][r] += __shfl_xor(sums[mi][r], d, 64);
        sqs[mi][r] += __shfl_xor(sqs[mi][r], d, 64);
      }
  }
  if (cl == 0) {
#pragma unroll
    for (int mi = 0; mi < 4; mi++)
#pragma unroll
      for (int r = 0; r < 4; r++) {
        int row = mi * 16 + quad * 4 + r;
        psum[w][row] = sums[mi][r];
        psq[w][row] = sqs[mi][r];
      }
  }
  __syncthreads();
  if (tid < 64) {
    float S = psum[0][tid] + psum[1][tid] + psum[2][tid] + psum[3][tid];
    float Q = psq[0][tid] + psq[1][tid] + psq[2][tid] + psq[3][tid];
    float m = S * (1.f / 128.f);
    float var = Q * (1.f / 128.f) - m * m;
    stats[tid] = make_float2(m, rsqrtf(var + 1e-5f));
  }
  __syncthreads();
#pragma unroll
  for (int ni = 0; ni < 2; ni++) {
    int col = w * 32 + ni * 16 + cl;
    float gl = lng[col], bl = lnb[col];
#pragma unroll
    for (int mi = 0; mi < 4; mi++)
#pragma unroll
      for (int r = 0; r < 4; r++) {
        int row = mi * 16 + quad * 4 + r;
        float2 st = stats[row];
        float y = (vv[mi][ni][r] - st.x) * st.y * gl + bl;
        size_t o = (size_t)(rowBase + row) * 128 + col;
        xio[o] = y;
        xbo[o] = f2bf(y);
      }
  }
}

// ---------------------------------------------------------------------------
// Attention per (b,h), register-tiled rows; vectorized uint4 staging.
// ---------------------------------------------------------------------------
__global__ __launch_bounds__(256) void attn_kernel(
    const unsigned short* __restrict__ qkv, unsigned short* __restrict__ ao) {
  __shared__ float Qs[64 * 20], Ks[64 * 20], Vs[64 * 20];
  __shared__ float SC[64 * 65];
  int tid = threadIdx.x, w = tid >> 6, lane = tid & 63;
  int b = blockIdx.x & 255, h = blockIdx.x >> 8;
  // stage: 384 slots of 8 elems; slot j -> (s=j/6, which=(j%6)>>1, half=j&1)
  for (int j = tid; j < 384; j += 256) {
    int s = j / 6, r = j % 6;
    int which = r >> 1, half = r & 1;
    uint4 v = *(const uint4*)(qkv + (size_t)(s * 256 + b) * 384 +
                              which * 128 + h * 16 + half * 8);
    float* dst = (which == 0 ? Qs : which == 1 ? Ks : Vs) + s * 20 + half * 8;
    *(float4*)dst = make_float4(uplo(v.x), uphi(v.x), uplo(v.y), uphi(v.y));
    *(float4*)(dst + 4) = make_float4(uplo(v.z), uphi(v.z), uplo(v.w), uphi(v.w));
  }
  __syncthreads();
  {
    const float4* qp = (const float4*)(Qs + lane * 20);
    float4 q0 = qp[0], q1 = qp[1], q2 = qp[2], q3 = qp[3];
#pragma unroll
    for (int j = 0; j < 16; j++) {
      int t2 = w * 16 + j;
      const float4* kp = (const float4*)(Ks + t2 * 20);
      float4 k0 = kp[0], k1 = kp[1], k2 = kp[2], k3 = kp[3];
      float a0 = q0.x * k0.x + q0.y * k0.y + q0.z * k0.z + q0.w * k0.w;
      float a1 = q1.x * k1.x + q1.y * k1.y + q1.z * k1.z + q1.w * k1.w;
      float a2 = q2.x * k2.x + q2.y * k2.y + q2.z * k2.z + q2.w * k2.w;
      float a3 = q3.x * k3.x + q3.y * k3.y + q3.z * k3.z + q3.w * k3.w;
      SC[lane * 65 + t2] = (a0 + a1 + a2 + a3) * 0.25f;
    }
  }
  __syncthreads();
  {
    int s = tid >> 2, seg = tid & 3;
    float* rowp = SC + s * 65 + seg * 16;
    float m = -1e30f;
#pragma unroll
    for (int j = 0; j < 16; j++) m = fmaxf(m, rowp[j]);
    m = fmaxf(m, __shfl_xor(m, 1));
    m = fmaxf(m, __shfl_xor(m, 2));
    float pv[16], sum = 0.f;
#pragma unroll
    for (int j = 0; j < 16; j++) { pv[j] = expf(rowp[j] - m); sum += pv[j]; }
    sum += __shfl_xor(sum, 1);
    sum += __shfl_xor(sum, 2);
    float rinv = 1.f / sum;
#pragma unroll
    for (int j = 0; j < 16; j++) rowp[j] = pv[j] * rinv;
  }
  __syncthreads();
  {
    float a0 = 0.f, a1 = 0.f, a2 = 0.f, a3 = 0.f;
    const float* scr = SC + lane * 65;
#pragma unroll 8
    for (int t2 = 0; t2 < 64; t2++) {
      float p = scr[t2];
      float4 v = *(const float4*)(Vs + t2 * 20 + w * 4);
      a0 += p * v.x; a1 += p * v.y; a2 += p * v.z; a3 += p * v.w;
    }
    ushort4 o;
    o.x = f2bf(a0); o.y = f2bf(a1); o.z = f2bf(a2); o.w = f2bf(a3);
    *(ushort4*)(ao + (size_t)(lane * 256 + b) * 128 + h * 16 + w * 4) = o;
  }
}

// ---------------------------------------------------------------------------
// Set2Set (6 steps) + memory LSTM + lin1 + lin3. One 512-thread block per
// segment. f16 path: wih/whh rows live in per-thread REGISTERS (48 uint4),
// q_star packed f16 in LDS (broadcast reads), fdot2 fp32 accumulation.
// ---------------------------------------------------------------------------
__global__ __launch_bounds__(512, 2) void s2s_kernel(
    const unsigned short* __restrict__ xb,
    const unsigned short* __restrict__ wihh,
    const unsigned short* __restrict__ whhh,
    const float* __restrict__ bih, const float* __restrict__ bhh,
    const unsigned short* __restrict__ mwihh,
    const float* __restrict__ mbih, const float* __restrict__ mbhh,
    const float* __restrict__ l1w, const float* __restrict__ l1b,
    const float* __restrict__ l3w, const float* __restrict__ l3b,
    float* __restrict__ out) {
  __shared__ __align__(16) unsigned xl[256 * 65];  // x as f16 pairs, 65-dw rows
  __shared__ __align__(16) unsigned qu[128];       // q_star f16 pairs
  __shared__ __align__(16) float cst[128];
  __shared__ __align__(16) float gates[512];
  __shared__ __align__(16) float red[256];
  __shared__ __align__(16) float aw[256];
  int s = blockIdx.x, t = threadIdx.x, lane = t & 63, w = t >> 6;

  // per-thread gate weights -> registers (persist whole kernel)
  uint4 wreg[32], ureg[16];
  {
    const uint4* wp = (const uint4*)(wihh + (size_t)t * 256);
#pragma unroll
    for (int i = 0; i < 32; i++) wreg[i] = wp[i];
    const uint4* up = (const uint4*)(whhh + (size_t)t * 128);
#pragma unroll
    for (int i = 0; i < 16; i++) ureg[i] = up[i];
  }

  // stage x (bf16 global) -> LDS f16, 65-dword row stride
  const uint4* xs4 = (const uint4*)(xb + (size_t)s * 32768);
#pragma unroll
  for (int it = 0; it < 8; it++) {
    int f = it * 512 + t;  // 16B-chunk index
    uint4 v = xs4[f];
    int n = f >> 4, jc = (f & 15) * 4;
    unsigned* dst = xl + n * 65 + jc;
    dst[0] = packh(uplo(v.x), uphi(v.x));
    dst[1] = packh(uplo(v.y), uphi(v.y));
    dst[2] = packh(uplo(v.z), uphi(v.z));
    dst[3] = packh(uplo(v.w), uphi(v.w));
  }
  if (t < 128) cst[t] = 0.f;
  __syncthreads();

  const uint4* q4 = (const uint4*)qu;
  float bsum = bih[t] + bhh[t];

  for (int step = 0; step < 6; step++) {
    // gates = bias + wih.q_star + whh.h (registers x LDS-broadcast)
    if (step > 0) {
      float a0 = 0.f, a1 = 0.f, a2 = 0.f, a3 = 0.f;
#pragma unroll
      for (int i = 0; i < 16; i++) {
        uint4 qv = q4[i];
        a0 = fdot2u(wreg[i].x, qv.x, a0);
        a1 = fdot2u(wreg[i].y, qv.y, a1);
        a2 = fdot2u(wreg[i].z, qv.z, a2);
        a3 = fdot2u(wreg[i].w, qv.w, a3);
        a0 = fdot2u(ureg[i].x, qv.x, a0);
        a1 = fdot2u(ureg[i].y, qv.y, a1);
        a2 = fdot2u(ureg[i].z, qv.z, a2);
        a3 = fdot2u(ureg[i].w, qv.w, a3);
      }
#pragma unroll
      for (int i = 16; i < 32; i++) {
        uint4 qv = q4[i];
        a0 = fdot2u(wreg[i].x, qv.x, a0);
        a1 = fdot2u(wreg[i].y, qv.y, a1);
        a2 = fdot2u(wreg[i].z, qv.z, a2);
        a3 = fdot2u(wreg[i].w, qv.w, a3);
      }
      gates[t] = bsum + ((a0 + a1) + (a2 + a3));
    } else {
      gates[t] = bsum;
    }
    __syncthreads();
    if (t < 128) {
      float ig = sigf(gates[t]), fg = sigf(gates[128 + t]);
      float gg = tanhf(gates[256 + t]), og = sigf(gates[384 + t]);
      float cn = fg * cst[t] + ig * gg;
      cst[t] = cn;
      float hn = og * tanhf(cn);
      float hp = __shfl_xor(hn, 1, 64);
      if ((t & 1) == 0) qu[t >> 1] = packh(hn, hp);
    }
    __syncthreads();
    if (step > 0) {
      // e[n] = x[n].h : 2 threads per row, one shuffle
      int n = t >> 1, p = t & 1;
      const unsigned* xr = xl + n * 65 + p * 32;
      float e0 = 0.f, e1 = 0.f;
#pragma unroll 8
      for (int i = 0; i < 32; i += 2) {
        e0 = fdot2u(xr[i], qu[p * 32 + i], e0);
        e1 = fdot2u(xr[i + 1], qu[p * 32 + i + 1], e1);
      }
      float e = e0 + e1;
      e += __shfl_xor(e, 1, 64);
      if (p == 0) red[n] = e;
      __syncthreads();
      // softmax over 256 — redundant per-wave reduce
      float v0 = red[lane], v1 = red[64 + lane];
      float v2 = red[128 + lane], v3 = red[192 + lane];
      float m = fmaxf(fmaxf(v0, v1), fmaxf(v2, v3));
#pragma unroll
      for (int d = 1; d < 64; d <<= 1) m = fmaxf(m, __shfl_xor(m, d, 64));
      float p0 = expf(v0 - m), p1 = expf(v1 - m);
      float p2 = expf(v2 - m), p3 = expf(v3 - m);
      float ss = p0 + p1 + p2 + p3;
#pragma unroll
      for (int d = 1; d < 64; d <<= 1) ss += __shfl_xor(ss, d, 64);
      float Sinv = 1.f / ss;
      if (w == 0) {
        aw[lane] = p0 * Sinv; aw[64 + lane] = p1 * Sinv;
        aw[128 + lane] = p2 * Sinv; aw[192 + lane] = p3 * Sinv;
      }
    } else {
      if (t < 256) aw[t] = 1.f / 256.f;
    }
    __syncthreads();
    // r[d] = sum_n aw[n]*x[n][d]
    {
      int d = t & 127, grp = t >> 7;
      const unsigned* xc = xl + grp * 64 * 65 + (d >> 1);
      int hi = d & 1;
      const float* ap = aw + grp * 64;
      float r = 0.f;
#pragma unroll 8
      for (int n2 = 0; n2 < 64; n2++) {
        unsigned u = xc[n2 * 65];
        r += ap[n2] * (hi ? hhi(u) : hlo(u));
      }
      gates[t] = r;
    }
    __syncthreads();
    if (t < 128) {
      float rd = gates[t] + gates[128 + t] + gates[256 + t] + gates[384 + t];
      float rp = __shfl_xor(rd, 1, 64);
      if ((t & 1) == 0) qu[64 + (t >> 1)] = packh(rd, rp);
    }
    __syncthreads();
  }
  // memory LSTM (zero init state), f16 weights streamed, fdot2
  {
    float a0 = 0.f, a1 = 0.f, a2 = 0.f, a3 = 0.f;
    const uint4* mp = (const uint4*)(mwihh + (size_t)t * 256);
#pragma unroll 8
    for (int i = 0; i < 32; i++) {
      uint4 wv = mp[i], qv = q4[i];
      a0 = fdot2u(wv.x, qv.x, a0);
      a1 = fdot2u(wv.y, qv.y, a1);
      a2 = fdot2u(wv.z, qv.z, a2);
      a3 = fdot2u(wv.w, qv.w, a3);
    }
    gates[t] = mbih[t] + mbhh[t] + ((a0 + a1) + (a2 + a3));
  }
  __syncthreads();
  if (t < 128) {
    float ig = sigf(gates[t]);
    float gg = tanhf(gates[256 + t]);
    float og = sigf(gates[384 + t]);
    float cx = ig * gg;
    float hx = og * tanhf(cx);
    cst[t] = hx;
    out[64 + s * 128 + t] = hx;
    out[64 + 8192 + s * 128 + t] = cx;
  }
  __syncthreads();
  if (t < 128) {
    float acc = l1b[t];
    const float4* w4 = (const float4*)(l1w + (size_t)t * 128);
    const float4* h4 = (const float4*)cst;
#pragma unroll 8
    for (int k = 0; k < 32; k++) {
      float4 a = w4[k], b = h4[k];
      acc += a.x * b.x + a.y * b.y + a.z * b.z + a.w * b.w;
    }
    red[t] = fmaxf(acc, 0.f) * l3w[t];
  } else if (t < 256) {
    red[t] = 0.f;
  }
  __syncthreads();
  for (int off = 128; off; off >>= 1) {
    if (t < off) red[t] += red[t + off];
    __syncthreads();
  }
  if (t == 0) out[s] = red[0] + l3b[0];
}

// ---------------------------------------------------------------------------
extern "C" void kernel_launch(void* const* d_in, const int* in_sizes, int n_in,
                              void* d_out, int out_size, void* d_ws,
                              size_t ws_size, hipStream_t stream) {
  const float* data       = (const float*)d_in[0];
  const float* lin0_w     = (const float*)d_in[1];
  const float* lin0_b     = (const float*)d_in[2];
  const float* attn_in_w  = (const float*)d_in[3];
  const float* attn_in_b  = (const float*)d_in[4];
  const float* attn_out_w = (const float*)d_in[5];
  const float* attn_out_b = (const float*)d_in[6];
  const float* ln1_g      = (const float*)d_in[7];
  const float* ln1_b      = (const float*)d_in[8];
  const float* ff_w1      = (const float*)d_in[9];
  const float* ff_b1      = (const float*)d_in[10];
  const float* ff_w2      = (const float*)d_in[11];
  const float* ff_b2      = (const float*)d_in[12];
  const float* ln2_g      = (const float*)d_in[13];
  const float* ln2_b      = (const float*)d_in[14];
  const float* s2s_wih    = (const float*)d_in[15];
  const float* s2s_whh    = (const float*)d_in[16];
  const float* s2s_bih    = (const float*)d_in[17];
  const float* s2s_bhh    = (const float*)d_in[18];
  const float* mem_wih    = (const float*)d_in[19];
  const float* mem_bih    = (const float*)d_in[21];
  const float* mem_bhh    = (const float*)d_in[22];
  const float* lin1_w     = (const float*)d_in[23];
  const float* lin1_b     = (const float*)d_in[24];
  const float* lin3_w     = (const float*)d_in[25];
  const float* lin3_b     = (const float*)d_in[26];
  float* out = (float*)d_out;

  char* p = (char*)d_ws;
  float* x = (float*)p;                      p += (size_t)16384 * 128 * 4;
  unsigned short* xb = (unsigned short*)p;   p += (size_t)16384 * 128 * 2;
  unsigned short* qkvb = (unsigned short*)p; p += (size_t)16384 * 384 * 2;
  unsigned short* aob = (unsigned short*)p;  p += (size_t)16384 * 128 * 2;
  unsigned short* wqkv = (unsigned short*)p; p += (size_t)294912 * 2;
  unsigned short* wout = (unsigned short*)p; p += (size_t)98304 * 2;
  unsigned short* w1b = (unsigned short*)p;  p += (size_t)1572864 * 2;
  unsigned short* w2b = (unsigned short*)p;  p += (size_t)1572864 * 2;
  unsigned short* wihh = (unsigned short*)p; p += (size_t)131072 * 2;
  unsigned short* whhh = (unsigned short*)p; p += (size_t)65536 * 2;
  unsigned short* mwihh = (unsigned short*)p; p += (size_t)131072 * 2;

  convw_kernel<<<15104, 256, 0, stream>>>(
      attn_in_w, attn_out_w, ff_w1, ff_w2, s2s_wih, s2s_whh, mem_wih,
      wqkv, wout, w1b, w2b, wihh, whhh, mwihh);
  lin0_kernel<<<8192, 256, 0, stream>>>(data, lin0_w, lin0_b, x, xb);

  for (int l = 0; l < 6; l++) {
    gemm_k128<<<dim3(128, 3), 256, 0, stream>>>(
        xb, wqkv + (size_t)l * 49152, attn_in_b + l * 384, qkvb, 384);
    attn_kernel<<<2048, 256, 0, stream>>>(qkvb, aob);
    gemm_ln<<<256, 256, 0, stream>>>(
        aob, wout + (size_t)l * 16384, attn_out_b + l * 128, x, xb,
        ln1_g + l * 128, ln1_b + l * 128, 128);
    ffn_ln<<<256, 256, 0, stream>>>(
        xb, w1b + (size_t)l * 262144, ff_b1 + l * 2048,
        w2b + (size_t)l * 262144, ff_b2 + l * 128, x, xb,
        ln2_g + l * 128, ln2_b + l * 128);
  }

  s2s_kernel<<<64, 512, 0, stream>>>(
      xb, wihh, whhh, s2s_bih, s2s_bhh,
      mwihh, mem_bih, mem_bhh, lin1_w, lin1_b, lin3_w, lin3_b, out);
}

// Round 6
// 577.011 us; speedup vs baseline: 4.3218x; 1.0842x over previous
//
#include <hip/hip_runtime.h>
#include <math.h>

// S=64 segments(seq), B=256 atoms(batch), N=16384 rows, D=128, H=8, HD=16,
// DFF=2048, NL=6.  Heavy GEMMs: bf16 MFMA 16x16x32, fp32 accum.
// Layer = attn_fused (qkv+attention+attn_out+LN1, one block per atom b)
//       + ffn_ln (ff1+relu+ff2+residual+LN2).

typedef __attribute__((ext_vector_type(8))) short bf16x8;
typedef __attribute__((ext_vector_type(4))) float f32x4;
typedef _Float16 __attribute__((ext_vector_type(2))) h16x2;

__device__ __forceinline__ unsigned short f2bf(float f) {
  union { float f; unsigned u; } x; x.f = f;
  unsigned r = x.u + 0x7fff + ((x.u >> 16) & 1);
  return (unsigned short)(r >> 16);
}
__device__ __forceinline__ float uplo(unsigned u) {
  union { unsigned u; float f; } x; x.u = u << 16; return x.f;
}
__device__ __forceinline__ float uphi(unsigned u) {
  union { unsigned u; float f; } x; x.u = u & 0xffff0000u; return x.f;
}
__device__ __forceinline__ unsigned short f2h(float f) {
  union { _Float16 h; unsigned short s; } x; x.h = (_Float16)f; return x.s;
}
__device__ __forceinline__ unsigned packh(float a, float b) {
  return (unsigned)f2h(a) | ((unsigned)f2h(b) << 16);
}
__device__ __forceinline__ float hlo(unsigned u) {
  union { unsigned short s; _Float16 h; } x; x.s = (unsigned short)(u & 0xffff);
  return (float)x.h;
}
__device__ __forceinline__ float hhi(unsigned u) {
  union { unsigned short s; _Float16 h; } x; x.s = (unsigned short)(u >> 16);
  return (float)x.h;
}
__device__ __forceinline__ float fdot2u(unsigned a, unsigned b, float c) {
#if __has_builtin(__builtin_amdgcn_fdot2)
  union U { unsigned u; h16x2 h; };
  U x, y; x.u = a; y.u = b;
  return __builtin_amdgcn_fdot2(x.h, y.h, c, false);
#else
  return c + hlo(a) * hlo(b) + hhi(a) * hhi(b);
#endif
}
__device__ __forceinline__ float sigf(float x) { return 1.f / (1.f + expf(-x)); }

// async 16B global->LDS; LDS base wave-uniform (+ lane*16 implicit).
__device__ __forceinline__ void gl2lds16(const void* g, void* l) {
  __builtin_amdgcn_global_load_lds(
      (const __attribute__((address_space(1))) unsigned int*)g,
      (__attribute__((address_space(3))) unsigned int*)l, 16, 0, 0);
}

// ---------------------------------------------------------------------------
// weight conversion: bf16 for MFMA GEMMs, f16 for the s2s tail.
// aiw 294912 | aow 98304 | w1 1572864 | w2 1572864 (bf16)
// | wih 131072 | whh 65536 | mwih 131072 (f16)   -> total 3866624
// ---------------------------------------------------------------------------
__global__ __launch_bounds__(256) void convw_kernel(
    const float* __restrict__ aiw, const float* __restrict__ aow,
    const float* __restrict__ w1, const float* __restrict__ w2,
    const float* __restrict__ wih, const float* __restrict__ whh,
    const float* __restrict__ mwih,
    unsigned short* __restrict__ o0, unsigned short* __restrict__ o1,
    unsigned short* __restrict__ o2, unsigned short* __restrict__ o3,
    unsigned short* __restrict__ o4, unsigned short* __restrict__ o5,
    unsigned short* __restrict__ o6) {
  int i = blockIdx.x * 256 + threadIdx.x;
  if (i < 294912) {
    o0[i] = f2bf(aiw[i]);
  } else if (i < 393216) {
    int j = i - 294912; o1[j] = f2bf(aow[j]);
  } else if (i < 1966080) {
    int j = i - 393216; o2[j] = f2bf(w1[j]);
  } else if (i < 3538944) {
    int j = i - 1966080; o3[j] = f2bf(w2[j]);
  } else if (i < 3670016) {
    int j = i - 3538944; o4[j] = f2h(wih[j]);
  } else if (i < 3735552) {
    int j = i - 3670016; o5[j] = f2h(whh[j]);
  } else {
    int j = i - 3735552; o6[j] = f2h(mwih[j]);
  }
}

// ---------------------------------------------------------------------------
// lin0: x = relu(data @ w^T + b), writes fp32 x and bf16 xb
// ---------------------------------------------------------------------------
__global__ __launch_bounds__(256) void lin0_kernel(
    const float* __restrict__ data, const float* __restrict__ w,
    const float* __restrict__ b, float* __restrict__ x,
    unsigned short* __restrict__ xb) {
  int i = blockIdx.x * 256 + threadIdx.x;
  int n = i >> 7, d = i & 127;
  float v = b[d] + data[n * 3 + 0] * w[d * 3 + 0]
                 + data[n * 3 + 1] * w[d * 3 + 1]
                 + data[n * 3 + 2] * w[d * 3 + 2];
  v = fmaxf(v, 0.0f);
  x[i] = v;
  xb[i] = f2bf(v);
}

// ---------------------------------------------------------------------------
// Fused attention layer: block = atom b (256 blocks), 512 threads = 8 waves.
// Block b owns rows {s*256+b}: qkv GEMM -> per-head MFMA attention ->
// ao@Wout + residual + LN, all in LDS. Row&7 XOR chunk swizzle everywhere.
// ---------------------------------------------------------------------------
__global__ __launch_bounds__(512) void attn_fused(
    const unsigned short* __restrict__ xbg, const unsigned short* __restrict__ wqkv,
    const float* __restrict__ bqkv, const unsigned short* __restrict__ wout,
    const float* __restrict__ bout, const float* __restrict__ lng,
    const float* __restrict__ lnb, float* __restrict__ xio,
    unsigned short* __restrict__ xbo) {
  __shared__ __align__(16) unsigned short Xs[64 * 128];   // 16 KB  x tile bf16
  __shared__ __align__(16) unsigned short Ws[256 * 128];  // 64 KB  W stage / P
  __shared__ __align__(16) unsigned short Qs[64 * 128];   // 16 KB
  __shared__ __align__(16) unsigned short Ks2[64 * 128];  // 16 KB
  __shared__ __align__(16) unsigned short VT[128 * 64];   // 16 KB  V transposed
  __shared__ __align__(16) unsigned short AOs[64 * 128];  // 16 KB
  __shared__ __align__(16) uint4 zchunk;                  // 16B zeros
  __shared__ float psum[8][64], psq[8][64];
  __shared__ float2 stats[64];

  int tid = threadIdx.x, w = tid >> 6, lane = tid & 63;
  int b = blockIdx.x;
  int r4 = lane >> 4, cs = lane & 15;
  int fr = lane & 15, fq = lane >> 4;

  if (tid == 0) zchunk = make_uint4(0u, 0u, 0u, 0u);

  // ---- phase 0: stage x tile + Wq+Wk (wqkv rows 0..255) ----
#pragma unroll
  for (int i = 0; i < 2; i++) {
    int issue = w * 2 + i;
    int row = issue * 4 + r4;  // s index
    int g = cs ^ (row & 7);
    gl2lds16(xbg + (size_t)(row * 256 + b) * 128 + g * 8,
             (char*)Xs + issue * 1024);
  }
#pragma unroll
  for (int i = 0; i < 8; i++) {
    int issue = w * 8 + i;
    int row = issue * 4 + r4;  // wqkv row 0..255
    int g = cs ^ (row & 7);
    gl2lds16(wqkv + (size_t)row * 128 + g * 8, (char*)Ws + issue * 1024);
  }
  __syncthreads();

  // ---- phase 1: Q,K = x @ Wqk^T + bias -> Qs/Ks2 (bf16, swizzled) ----
  {
    f32x4 acc[4][2];
#pragma unroll
    for (int i = 0; i < 4; i++)
#pragma unroll
      for (int j = 0; j < 2; j++) acc[i][j] = (f32x4){0.f, 0.f, 0.f, 0.f};
#pragma unroll
    for (int ks = 0; ks < 4; ks++) {
      bf16x8 af[4], bf[2];
#pragma unroll
      for (int mi = 0; mi < 4; mi++) {
        int row = mi * 16 + fr;
        int kq = (ks * 4 + fq) ^ (row & 7);
        af[mi] = *(const bf16x8*)(Xs + row * 128 + kq * 8);
      }
#pragma unroll
      for (int ni = 0; ni < 2; ni++) {
        int wr = (w * 2 + ni) * 16 + fr;
        int kq = (ks * 4 + fq) ^ (wr & 7);
        bf[ni] = *(const bf16x8*)(Ws + wr * 128 + kq * 8);
      }
#pragma unroll
      for (int mi = 0; mi < 4; mi++)
#pragma unroll
        for (int ni = 0; ni < 2; ni++)
          acc[mi][ni] = __builtin_amdgcn_mfma_f32_16x16x32_bf16(
              af[mi], bf[ni], acc[mi][ni], 0, 0, 0);
    }
#pragma unroll
    for (int ni = 0; ni < 2; ni++) {
      int c = (w * 2 + ni) * 16 + fr;  // 0..255
      float bv = bqkv[c];
      unsigned short* dst = (c < 128) ? Qs : Ks2;
      int cc = c & 127;
#pragma unroll
      for (int mi = 0; mi < 4; mi++)
#pragma unroll
        for (int r = 0; r < 4; r++) {
          int row = mi * 16 + fq * 4 + r;
          dst[row * 128 + (((cc >> 3) ^ (row & 7)) << 3) + (cc & 7)] =
              f2bf(acc[mi][ni][r] + bv);
        }
    }
  }
  __syncthreads();

  // ---- stage Wv (wqkv rows 256..383) into Ws rows 0..127 ----
#pragma unroll
  for (int i = 0; i < 4; i++) {
    int issue = w * 4 + i;
    int row = issue * 4 + r4;  // 0..127
    int g = cs ^ (row & 7);
    gl2lds16(wqkv + (size_t)(256 + row) * 128 + g * 8, (char*)Ws + issue * 1024);
  }
  __syncthreads();

  // ---- phase 2: V = x @ Wv^T + bias -> VT[feature][s] (bf16, swizzled) ----
  {
    f32x4 acc[4];
#pragma unroll
    for (int i = 0; i < 4; i++) acc[i] = (f32x4){0.f, 0.f, 0.f, 0.f};
#pragma unroll
    for (int ks = 0; ks < 4; ks++) {
      bf16x8 af[4], bf;
#pragma unroll
      for (int mi = 0; mi < 4; mi++) {
        int row = mi * 16 + fr;
        int kq = (ks * 4 + fq) ^ (row & 7);
        af[mi] = *(const bf16x8*)(Xs + row * 128 + kq * 8);
      }
      {
        int wr = w * 16 + fr;
        int kq = (ks * 4 + fq) ^ (wr & 7);
        bf = *(const bf16x8*)(Ws + wr * 128 + kq * 8);
      }
#pragma unroll
      for (int mi = 0; mi < 4; mi++)
        acc[mi] = __builtin_amdgcn_mfma_f32_16x16x32_bf16(af[mi], bf, acc[mi],
                                                          0, 0, 0);
    }
    int f = w * 16 + fr;  // feature 0..127
    float bv = bqkv[256 + f];
#pragma unroll
    for (int mi = 0; mi < 4; mi++)
#pragma unroll
      for (int r = 0; r < 4; r++) {
        int srow = mi * 16 + fq * 4 + r;
        VT[f * 64 + (((srow >> 3) ^ (f & 7)) << 3) + (srow & 7)] =
            f2bf(acc[mi][r] + bv);
      }
  }
  __syncthreads();

  // ---- phase 3: per-wave head attention (head h = w), P private in Ws ----
  {
    int h = w;
    unsigned short* Pb = Ws + w * 4096;  // 8 KB per wave
    f32x4 sc[4][4];
#pragma unroll
    for (int i = 0; i < 4; i++)
#pragma unroll
      for (int j = 0; j < 4; j++) sc[i][j] = (f32x4){0.f, 0.f, 0.f, 0.f};
    // scores = Q K^T (K-dim 16, zero-padded to 32 via zchunk broadcast)
    {
      bf16x8 af[4], bf[4];
#pragma unroll
      for (int mi = 0; mi < 4; mi++) {
        int row = mi * 16 + fr;
        const unsigned short* pa =
            (fq < 2) ? (Qs + row * 128 + (((h * 2 + fq) ^ (row & 7)) << 3))
                     : (const unsigned short*)&zchunk;
        af[mi] = *(const bf16x8*)pa;
      }
#pragma unroll
      for (int ti = 0; ti < 4; ti++) {
        int trow = ti * 16 + fr;
        const unsigned short* pb =
            (fq < 2) ? (Ks2 + trow * 128 + (((h * 2 + fq) ^ (trow & 7)) << 3))
                     : (const unsigned short*)&zchunk;
        bf[ti] = *(const bf16x8*)pb;
      }
#pragma unroll
      for (int mi = 0; mi < 4; mi++)
#pragma unroll
        for (int ti = 0; ti < 4; ti++)
          sc[mi][ti] = __builtin_amdgcn_mfma_f32_16x16x32_bf16(
              af[mi], bf[ti], sc[mi][ti], 0, 0, 0);
    }
    // softmax over t (cols), rows held as (mi, fq*4+r), col fr per tile ti
#pragma unroll
    for (int mi = 0; mi < 4; mi++) {
#pragma unroll
      for (int r = 0; r < 4; r++) {
        float m = -1e30f;
#pragma unroll
        for (int ti = 0; ti < 4; ti++) m = fmaxf(m, sc[mi][ti][r]);
        m = fmaxf(m, __shfl_xor(m, 1, 64));
        m = fmaxf(m, __shfl_xor(m, 2, 64));
        m = fmaxf(m, __shfl_xor(m, 4, 64));
        m = fmaxf(m, __shfl_xor(m, 8, 64));
        m *= 0.25f;
        float ss = 0.f;
#pragma unroll
        for (int ti = 0; ti < 4; ti++) {
          float p = expf(sc[mi][ti][r] * 0.25f - m);
          sc[mi][ti][r] = p;
          ss += p;
        }
        ss += __shfl_xor(ss, 1, 64);
        ss += __shfl_xor(ss, 2, 64);
        ss += __shfl_xor(ss, 4, 64);
        ss += __shfl_xor(ss, 8, 64);
        float inv = 1.f / ss;
        int prow = mi * 16 + fq * 4 + r;
#pragma unroll
        for (int ti = 0; ti < 4; ti++) {
          int t = ti * 16 + fr;
          Pb[prow * 64 + (((t >> 3) ^ (prow & 7)) << 3) + (t & 7)] =
              f2bf(sc[mi][ti][r] * inv);
        }
      }
    }
    // PV: out[s, feat16] = P[64x64] @ V[64x16]  (A from Pb, B from VT rows)
    f32x4 po[4];
#pragma unroll
    for (int i = 0; i < 4; i++) po[i] = (f32x4){0.f, 0.f, 0.f, 0.f};
#pragma unroll
    for (int ks2 = 0; ks2 < 2; ks2++) {
      bf16x8 af[4], bf;
#pragma unroll
      for (int si = 0; si < 4; si++) {
        int prow = si * 16 + fr;
        int kq = (ks2 * 4 + fq) ^ (prow & 7);
        af[si] = *(const bf16x8*)(Pb + prow * 64 + kq * 8);
      }
      {
        int vrow = h * 16 + fr;
        int kq = (ks2 * 4 + fq) ^ (vrow & 7);
        bf = *(const bf16x8*)(VT + vrow * 64 + kq * 8);
      }
#pragma unroll
      for (int si = 0; si < 4; si++)
        po[si] = __builtin_amdgcn_mfma_f32_16x16x32_bf16(af[si], bf, po[si],
                                                         0, 0, 0);
    }
#pragma unroll
    for (int si = 0; si < 4; si++)
#pragma unroll
      for (int r = 0; r < 4; r++) {
        int arow = si * 16 + fq * 4 + r;
        int c = h * 16 + fr;
        AOs[arow * 128 + (((c >> 3) ^ (arow & 7)) << 3) + (c & 7)] =
            f2bf(po[si][r]);
      }
  }
  __syncthreads();

  // ---- stage Wout into Ws rows 0..127 ----
#pragma unroll
  for (int i = 0; i < 4; i++) {
    int issue = w * 4 + i;
    int row = issue * 4 + r4;
    int g = cs ^ (row & 7);
    gl2lds16(wout + (size_t)row * 128 + g * 8, (char*)Ws + issue * 1024);
  }
  __syncthreads();

  // ---- phase 4: x = LN(x + ao @ Wout^T + bias) ----
  f32x4 acc[4];
#pragma unroll
  for (int i = 0; i < 4; i++) acc[i] = (f32x4){0.f, 0.f, 0.f, 0.f};
#pragma unroll
  for (int ks = 0; ks < 4; ks++) {
    bf16x8 af[4], bf;
#pragma unroll
    for (int si = 0; si < 4; si++) {
      int row = si * 16 + fr;
      int kq = (ks * 4 + fq) ^ (row & 7);
      af[si] = *(const bf16x8*)(AOs + row * 128 + kq * 8);
    }
    {
      int wr = w * 16 + fr;
      int kq = (ks * 4 + fq) ^ (wr & 7);
      bf = *(const bf16x8*)(Ws + wr * 128 + kq * 8);
    }
#pragma unroll
    for (int si = 0; si < 4; si++)
      acc[si] = __builtin_amdgcn_mfma_f32_16x16x32_bf16(af[si], bf, acc[si],
                                                        0, 0, 0);
  }
  int c = w * 16 + fr;
  float bv = bout[c];
  float vv[4][4];
  float sums[4][4], sqs[4][4];
#pragma unroll
  for (int si = 0; si < 4; si++)
#pragma unroll
    for (int r = 0; r < 4; r++) {
      int row = si * 16 + fq * 4 + r;
      float v = acc[si][r] + bv + xio[(size_t)(row * 256 + b) * 128 + c];
      vv[si][r] = v;
      sums[si][r] = v;
      sqs[si][r] = v * v;
    }
#pragma unroll
  for (int d = 1; d < 16; d <<= 1) {
#pragma unroll
    for (int si = 0; si < 4; si++)
#pragma unroll
      for (int r = 0; r < 4; r++) {
        sums[si][r] += __shfl_xor(sums[si][r], d, 64);
        sqs[si][r] += __shfl_xor(sqs[si][r], d, 64);
      }
  }
  if (fr == 0) {
#pragma unroll
    for (int si = 0; si < 4; si++)
#pragma unroll
      for (int r = 0; r < 4; r++) {
        int row = si * 16 + fq * 4 + r;
        psum[w][row] = sums[si][r];
        psq[w][row] = sqs[si][r];
      }
  }
  __syncthreads();
  if (tid < 64) {
    float S = 0.f, Q = 0.f;
#pragma unroll
    for (int ww = 0; ww < 8; ww++) { S += psum[ww][tid]; Q += psq[ww][tid]; }
    float m = S * (1.f / 128.f);
    float var = Q * (1.f / 128.f) - m * m;
    stats[tid] = make_float2(m, rsqrtf(var + 1e-5f));
  }
  __syncthreads();
  float gl = lng[c], bl = lnb[c];
#pragma unroll
  for (int si = 0; si < 4; si++)
#pragma unroll
    for (int r = 0; r < 4; r++) {
      int row = si * 16 + fq * 4 + r;
      float2 st = stats[row];
      float y = (vv[si][r] - st.x) * st.y * gl + bl;
      size_t o = (size_t)(row * 256 + b) * 128 + c;
      xio[o] = y;
      xbo[o] = f2bf(y);
    }
}

// ---------------------------------------------------------------------------
// Fused FFN + residual + LN, software-pipelined: W1 double-buffered, W2
// staged during ff1 compute. 64-row tile, 16 hidden chunks of 128.
// ---------------------------------------------------------------------------
__global__ __launch_bounds__(256) void ffn_ln(
    const unsigned short* __restrict__ xbi,
    const unsigned short* __restrict__ w1, const float* __restrict__ b1,
    const unsigned short* __restrict__ w2, const float* __restrict__ b2,
    float* __restrict__ xio, unsigned short* __restrict__ xbo,
    const float* __restrict__ lng, const float* __restrict__ lnb) {
  __shared__ __align__(16) unsigned short Xs[64 * 128];       // 16 KB
  __shared__ __align__(16) unsigned short W1s[2][128 * 128];  // 64 KB
  __shared__ __align__(16) unsigned short W2s[128 * 128];     // 32 KB
  __shared__ __align__(16) unsigned short Hs[64 * 136];       // 17 KB
  __shared__ float psum[4][64], psq[4][64];
  __shared__ float2 stats[64];
  int tid = threadIdx.x, w = tid >> 6, lane = tid & 63;
  int rowBase = blockIdx.x * 64;
  int r4 = lane >> 4, cs = lane & 15;
  int fr = lane & 15, fq = lane >> 4;
  int cl = fr, quad = fq;

#pragma unroll
  for (int i = 0; i < 4; i++) {
    int issue = w * 4 + i;
    int row = issue * 4 + r4;
    int g = cs ^ (row & 7);
    gl2lds16(xbi + (size_t)(rowBase + row) * 128 + g * 8, Xs + issue * 512);
  }
#pragma unroll
  for (int i = 0; i < 8; i++) {
    int issue = w * 8 + i;
    int row = issue * 4 + r4;
    int g = cs ^ (row & 7);
    gl2lds16(w1 + (size_t)row * 128 + g * 8, W1s[0] + issue * 512);
  }
  __syncthreads();

  f32x4 acc2[4][2];
#pragma unroll
  for (int i = 0; i < 4; i++)
#pragma unroll
    for (int j = 0; j < 2; j++) acc2[i][j] = (f32x4){0.f, 0.f, 0.f, 0.f};

  for (int c = 0; c < 16; c++) {
    const unsigned short* W1cur = W1s[c & 1];
#pragma unroll
    for (int i = 0; i < 8; i++) {
      int issue = w * 8 + i;
      int row = issue * 4 + r4;
      int g = cs ^ (row & 7);
      gl2lds16(w2 + (size_t)row * 2048 + c * 128 + g * 8, W2s + issue * 512);
    }

    f32x4 acc1[4][2];
#pragma unroll
    for (int i = 0; i < 4; i++)
#pragma unroll
      for (int j = 0; j < 2; j++) acc1[i][j] = (f32x4){0.f, 0.f, 0.f, 0.f};
#pragma unroll
    for (int ks = 0; ks < 4; ks++) {
      bf16x8 af[4], bf[2];
#pragma unroll
      for (int mi = 0; mi < 4; mi++) {
        int row = mi * 16 + fr;
        int kq = (ks * 4 + fq) ^ (row & 7);
        af[mi] = *(const bf16x8*)(Xs + row * 128 + kq * 8);
      }
#pragma unroll
      for (int ni = 0; ni < 2; ni++) {
        int row = w * 32 + ni * 16 + fr;
        int kq = (ks * 4 + fq) ^ (row & 7);
        bf[ni] = *(const bf16x8*)(W1cur + row * 128 + kq * 8);
      }
#pragma unroll
      for (int mi = 0; mi < 4; mi++)
#pragma unroll
        for (int ni = 0; ni < 2; ni++)
          acc1[mi][ni] = __builtin_amdgcn_mfma_f32_16x16x32_bf16(
              af[mi], bf[ni], acc1[mi][ni], 0, 0, 0);
    }

    if (c < 15) {
#pragma unroll
      for (int i = 0; i < 8; i++) {
        int issue = w * 8 + i;
        int row = issue * 4 + r4;
        int g = cs ^ (row & 7);
        gl2lds16(w1 + (size_t)(c * 128 + 128 + row) * 128 + g * 8,
                 W1s[(c + 1) & 1] + issue * 512);
      }
    }

#pragma unroll
    for (int ni = 0; ni < 2; ni++) {
      int col = w * 32 + ni * 16 + cl;
      float bv = b1[c * 128 + col];
#pragma unroll
      for (int mi = 0; mi < 4; mi++)
#pragma unroll
        for (int r = 0; r < 4; r++) {
          int row = mi * 16 + quad * 4 + r;
          Hs[row * 136 + col] = f2bf(fmaxf(acc1[mi][ni][r] + bv, 0.f));
        }
    }
    __syncthreads();

#pragma unroll
    for (int ks = 0; ks < 4; ks++) {
      bf16x8 af[4], bf[2];
#pragma unroll
      for (int mi = 0; mi < 4; mi++) {
        int row = mi * 16 + fr;
        af[mi] = *(const bf16x8*)(Hs + row * 136 + ks * 32 + fq * 8);
      }
#pragma unroll
      for (int ni = 0; ni < 2; ni++) {
        int row = w * 32 + ni * 16 + fr;
        int kq = (ks * 4 + fq) ^ (row & 7);
        bf[ni] = *(const bf16x8*)(W2s + row * 128 + kq * 8);
      }
#pragma unroll
      for (int mi = 0; mi < 4; mi++)
#pragma unroll
        for (int ni = 0; ni < 2; ni++)
          acc2[mi][ni] = __builtin_amdgcn_mfma_f32_16x16x32_bf16(
              af[mi], bf[ni], acc2[mi][ni], 0, 0, 0);
    }
    __syncthreads();
  }

  float vv[4][2][4];
#pragma unroll
  for (int ni = 0; ni < 2; ni++) {
    int col = w * 32 + ni * 16 + cl;
    float bv = b2[col];
#pragma unroll
    for (int mi = 0; mi < 4; mi++)
#pragma unroll
      for (int r = 0; r < 4; r++) {
        int row = mi * 16 + quad * 4 + r;
        vv[mi][ni][r] =
            acc2[mi][ni][r] + bv + xio[(size_t)(rowBase + row) * 128 + col];
      }
  }
  float sums[4][4], sqs[4][4];
#pragma unroll
  for (int mi = 0; mi < 4; mi++)
#pragma unroll
    for (int r = 0; r < 4; r++) {
      float a = vv[mi][0][r], b = vv[mi][1][r];
      sums[mi][r] = a + b;
      sqs[mi][r] = a * a + b * b;
    }
#pragma unroll
  for (int d = 1; d < 16; d <<= 1) {
#pragma unroll
    for (int mi = 0; mi < 4; mi++)
#pragma unroll
      for (int r = 0; r < 4; r++) {
        sums[mi][r] += __shfl_xor(sums[mi][r], d, 64);
        sqs[mi][r] += __shfl_xor(sqs[mi][r], d, 64);
      }
  }
  if (cl == 0) {
#pragma unroll
    for (int mi = 0; mi < 4; mi++)
#pragma unroll
      for (int r = 0; r < 4; r++) {
        int row = mi * 16 + quad * 4 + r;
        psum[w][row] = sums[mi][r];
        psq[w][row] = sqs[mi][r];
      }
  }
  __syncthreads();
  if (tid < 64) {
    float S = psum[0][tid] + psum[1][tid] + psum[2][tid] + psum[3][tid];
    float Q = psq[0][tid] + psq[1][tid] + psq[2][tid] + psq[3][tid];
    float m = S * (1.f / 128.f);
    float var = Q * (1.f / 128.f) - m * m;
    stats[tid] = make_float2(m, rsqrtf(var + 1e-5f));
  }
  __syncthreads();
#pragma unroll
  for (int ni = 0; ni < 2; ni++) {
    int col = w * 32 + ni * 16 + cl;
    float gl = lng[col], bl = lnb[col];
#pragma unroll
    for (int mi = 0; mi < 4; mi++)
#pragma unroll
      for (int r = 0; r < 4; r++) {
        int row = mi * 16 + quad * 4 + r;
        float2 st = stats[row];
        float y = (vv[mi][ni][r] - st.x) * st.y * gl + bl;
        size_t o = (size_t)(rowBase + row) * 128 + col;
        xio[o] = y;
        xbo[o] = f2bf(y);
      }
  }
}

// ---------------------------------------------------------------------------
// Set2Set (6 steps) + memory LSTM + lin1 + lin3. One 512-thread block per
// segment. f16 path: wih/whh rows live in per-thread REGISTERS (48 uint4),
// q_star packed f16 in LDS (broadcast reads), fdot2 fp32 accumulation.
// ---------------------------------------------------------------------------
__global__ __launch_bounds__(512, 2) void s2s_kernel(
    const unsigned short* __restrict__ xb,
    const unsigned short* __restrict__ wihh,
    const unsigned short* __restrict__ whhh,
    const float* __restrict__ bih, const float* __restrict__ bhh,
    const unsigned short* __restrict__ mwihh,
    const float* __restrict__ mbih, const float* __restrict__ mbhh,
    const float* __restrict__ l1w, const float* __restrict__ l1b,
    const float* __restrict__ l3w, const float* __restrict__ l3b,
    float* __restrict__ out) {
  __shared__ __align__(16) unsigned xl[256 * 65];
  __shared__ __align__(16) unsigned qu[128];
  __shared__ __align__(16) float cst[128];
  __shared__ __align__(16) float gates[512];
  __shared__ __align__(16) float red[256];
  __shared__ __align__(16) float aw[256];
  int s = blockIdx.x, t = threadIdx.x, lane = t & 63, w = t >> 6;

  uint4 wreg[32], ureg[16];
  {
    const uint4* wp = (const uint4*)(wihh + (size_t)t * 256);
#pragma unroll
    for (int i = 0; i < 32; i++) wreg[i] = wp[i];
    const uint4* up = (const uint4*)(whhh + (size_t)t * 128);
#pragma unroll
    for (int i = 0; i < 16; i++) ureg[i] = up[i];
  }

  const uint4* xs4 = (const uint4*)(xb + (size_t)s * 32768);
#pragma unroll
  for (int it = 0; it < 8; it++) {
    int f = it * 512 + t;
    uint4 v = xs4[f];
    int n = f >> 4, jc = (f & 15) * 4;
    unsigned* dst = xl + n * 65 + jc;
    dst[0] = packh(uplo(v.x), uphi(v.x));
    dst[1] = packh(uplo(v.y), uphi(v.y));
    dst[2] = packh(uplo(v.z), uphi(v.z));
    dst[3] = packh(uplo(v.w), uphi(v.w));
  }
  if (t < 128) cst[t] = 0.f;
  __syncthreads();

  const uint4* q4 = (const uint4*)qu;
  float bsum = bih[t] + bhh[t];

  for (int step = 0; step < 6; step++) {
    if (step > 0) {
      float a0 = 0.f, a1 = 0.f, a2 = 0.f, a3 = 0.f;
#pragma unroll
      for (int i = 0; i < 16; i++) {
        uint4 qv = q4[i];
        a0 = fdot2u(wreg[i].x, qv.x, a0);
        a1 = fdot2u(wreg[i].y, qv.y, a1);
        a2 = fdot2u(wreg[i].z, qv.z, a2);
        a3 = fdot2u(wreg[i].w, qv.w, a3);
        a0 = fdot2u(ureg[i].x, qv.x, a0);
        a1 = fdot2u(ureg[i].y, qv.y, a1);
        a2 = fdot2u(ureg[i].z, qv.z, a2);
        a3 = fdot2u(ureg[i].w, qv.w, a3);
      }
#pragma unroll
      for (int i = 16; i < 32; i++) {
        uint4 qv = q4[i];
        a0 = fdot2u(wreg[i].x, qv.x, a0);
        a1 = fdot2u(wreg[i].y, qv.y, a1);
        a2 = fdot2u(wreg[i].z, qv.z, a2);
        a3 = fdot2u(wreg[i].w, qv.w, a3);
      }
      gates[t] = bsum + ((a0 + a1) + (a2 + a3));
    } else {
      gates[t] = bsum;
    }
    __syncthreads();
    if (t < 128) {
      float ig = sigf(gates[t]), fg = sigf(gates[128 + t]);
      float gg = tanhf(gates[256 + t]), og = sigf(gates[384 + t]);
      float cn = fg * cst[t] + ig * gg;
      cst[t] = cn;
      float hn = og * tanhf(cn);
      float hp = __shfl_xor(hn, 1, 64);
      if ((t & 1) == 0) qu[t >> 1] = packh(hn, hp);
    }
    __syncthreads();
    if (step > 0) {
      int n = t >> 1, p = t & 1;
      const unsigned* xr = xl + n * 65 + p * 32;
      float e0 = 0.f, e1 = 0.f;
#pragma unroll 8
      for (int i = 0; i < 32; i += 2) {
        e0 = fdot2u(xr[i], qu[p * 32 + i], e0);
        e1 = fdot2u(xr[i + 1], qu[p * 32 + i + 1], e1);
      }
      float e = e0 + e1;
      e += __shfl_xor(e, 1, 64);
      if (p == 0) red[n] = e;
      __syncthreads();
      float v0 = red[lane], v1 = red[64 + lane];
      float v2 = red[128 + lane], v3 = red[192 + lane];
      float m = fmaxf(fmaxf(v0, v1), fmaxf(v2, v3));
#pragma unroll
      for (int d = 1; d < 64; d <<= 1) m = fmaxf(m, __shfl_xor(m, d, 64));
      float p0 = expf(v0 - m), p1 = expf(v1 - m);
      float p2 = expf(v2 - m), p3 = expf(v3 - m);
      float ss = p0 + p1 + p2 + p3;
#pragma unroll
      for (int d = 1; d < 64; d <<= 1) ss += __shfl_xor(ss, d, 64);
      float Sinv = 1.f / ss;
      if (w == 0) {
        aw[lane] = p0 * Sinv; aw[64 + lane] = p1 * Sinv;
        aw[128 + lane] = p2 * Sinv; aw[192 + lane] = p3 * Sinv;
      }
    } else {
      if (t < 256) aw[t] = 1.f / 256.f;
    }
    __syncthreads();
    {
      int d = t & 127, grp = t >> 7;
      const unsigned* xc = xl + grp * 64 * 65 + (d >> 1);
      int hi = d & 1;
      const float* ap = aw + grp * 64;
      float r = 0.f;
#pragma unroll 8
      for (int n2 = 0; n2 < 64; n2++) {
        unsigned u = xc[n2 * 65];
        r += ap[n2] * (hi ? hhi(u) : hlo(u));
      }
      gates[t] = r;
    }
    __syncthreads();
    if (t < 128) {
      float rd = gates[t] + gates[128 + t] + gates[256 + t] + gates[384 + t];
      float rp = __shfl_xor(rd, 1, 64);
      if ((t & 1) == 0) qu[64 + (t >> 1)] = packh(rd, rp);
    }
    __syncthreads();
  }
  {
    float a0 = 0.f, a1 = 0.f, a2 = 0.f, a3 = 0.f;
    const uint4* mp = (const uint4*)(mwihh + (size_t)t * 256);
#pragma unroll 8
    for (int i = 0; i < 32; i++) {
      uint4 wv = mp[i], qv = q4[i];
      a0 = fdot2u(wv.x, qv.x, a0);
      a1 = fdot2u(wv.y, qv.y, a1);
      a2 = fdot2u(wv.z, qv.z, a2);
      a3 = fdot2u(wv.w, qv.w, a3);
    }
    gates[t] = mbih[t] + mbhh[t] + ((a0 + a1) + (a2 + a3));
  }
  __syncthreads();
  if (t < 128) {
    float ig = sigf(gates[t]);
    float gg = tanhf(gates[256 + t]);
    float og = sigf(gates[384 + t]);
    float cx = ig * gg;
    float hx = og * tanhf(cx);
    cst[t] = hx;
    out[64 + s * 128 + t] = hx;
    out[64 + 8192 + s * 128 + t] = cx;
  }
  __syncthreads();
  if (t < 128) {
    float acc = l1b[t];
    const float4* w4 = (const float4*)(l1w + (size_t)t * 128);
    const float4* h4 = (const float4*)cst;
#pragma unroll 8
    for (int k = 0; k < 32; k++) {
      float4 a = w4[k], b = h4[k];
      acc += a.x * b.x + a.y * b.y + a.z * b.z + a.w * b.w;
    }
    red[t] = fmaxf(acc, 0.f) * l3w[t];
  } else if (t < 256) {
    red[t] = 0.f;
  }
  __syncthreads();
  for (int off = 128; off; off >>= 1) {
    if (t < off) red[t] += red[t + off];
    __syncthreads();
  }
  if (t == 0) out[s] = red[0] + l3b[0];
}

// ---------------------------------------------------------------------------
extern "C" void kernel_launch(void* const* d_in, const int* in_sizes, int n_in,
                              void* d_out, int out_size, void* d_ws,
                              size_t ws_size, hipStream_t stream) {
  const float* data       = (const float*)d_in[0];
  const float* lin0_w     = (const float*)d_in[1];
  const float* lin0_b     = (const float*)d_in[2];
  const float* attn_in_w  = (const float*)d_in[3];
  const float* attn_in_b  = (const float*)d_in[4];
  const float* attn_out_w = (const float*)d_in[5];
  const float* attn_out_b = (const float*)d_in[6];
  const float* ln1_g      = (const float*)d_in[7];
  const float* ln1_b      = (const float*)d_in[8];
  const float* ff_w1      = (const float*)d_in[9];
  const float* ff_b1      = (const float*)d_in[10];
  const float* ff_w2      = (const float*)d_in[11];
  const float* ff_b2      = (const float*)d_in[12];
  const float* ln2_g      = (const float*)d_in[13];
  const float* ln2_b      = (const float*)d_in[14];
  const float* s2s_wih    = (const float*)d_in[15];
  const float* s2s_whh    = (const float*)d_in[16];
  const float* s2s_bih    = (const float*)d_in[17];
  const float* s2s_bhh    = (const float*)d_in[18];
  const float* mem_wih    = (const float*)d_in[19];
  const float* mem_bih    = (const float*)d_in[21];
  const float* mem_bhh    = (const float*)d_in[22];
  const float* lin1_w     = (const float*)d_in[23];
  const float* lin1_b     = (const float*)d_in[24];
  const float* lin3_w     = (const float*)d_in[25];
  const float* lin3_b     = (const float*)d_in[26];
  float* out = (float*)d_out;

  char* p = (char*)d_ws;
  float* x = (float*)p;                      p += (size_t)16384 * 128 * 4;
  unsigned short* xb = (unsigned short*)p;   p += (size_t)16384 * 128 * 2;
  unsigned short* wqkv = (unsigned short*)p; p += (size_t)294912 * 2;
  unsigned short* wout = (unsigned short*)p; p += (size_t)98304 * 2;
  unsigned short* w1b = (unsigned short*)p;  p += (size_t)1572864 * 2;
  unsigned short* w2b = (unsigned short*)p;  p += (size_t)1572864 * 2;
  unsigned short* wihh = (unsigned short*)p; p += (size_t)131072 * 2;
  unsigned short* whhh = (unsigned short*)p; p += (size_t)65536 * 2;
  unsigned short* mwihh = (unsigned short*)p; p += (size_t)131072 * 2;

  convw_kernel<<<15104, 256, 0, stream>>>(
      attn_in_w, attn_out_w, ff_w1, ff_w2, s2s_wih, s2s_whh, mem_wih,
      wqkv, wout, w1b, w2b, wihh, whhh, mwihh);
  lin0_kernel<<<8192, 256, 0, stream>>>(data, lin0_w, lin0_b, x, xb);

  for (int l = 0; l < 6; l++) {
    attn_fused<<<256, 512, 0, stream>>>(
        xb, wqkv + (size_t)l * 49152, attn_in_b + l * 384,
        wout + (size_t)l * 16384, attn_out_b + l * 128,
        ln1_g + l * 128, ln1_b + l * 128, x, xb);
    ffn_ln<<<256, 256, 0, stream>>>(
        xb, w1b + (size_t)l * 262144, ff_b1 + l * 2048,
        w2b + (size_t)l * 262144, ff_b2 + l * 128, x, xb,
        ln2_g + l * 128, ln2_b + l * 128);
  }

  s2s_kernel<<<64, 512, 0, stream>>>(
      xb, wihh, whhh, s2s_bih, s2s_bhh,
      mwihh, mem_bih, mem_bhh, lin1_w, lin1_b, lin3_w, lin3_b, out);
}

// Round 7
// 504.017 us; speedup vs baseline: 4.9476x; 1.1448x over previous
//
#include <hip/hip_runtime.h>
#include <math.h>

// S=64 segments(seq), B=256 atoms(batch), N=16384 rows, D=128, H=8, HD=16,
// DFF=2048, NL=6.  One fused kernel per transformer layer (attn+FFN), bf16
// MFMA 16x16x32 fp32-accum; s2s tail f16 fdot2 with register-resident weights.

typedef __attribute__((ext_vector_type(8))) short bf16x8;
typedef __attribute__((ext_vector_type(4))) float f32x4;
typedef _Float16 __attribute__((ext_vector_type(2))) h16x2;

__device__ __forceinline__ unsigned short f2bf(float f) {
  union { float f; unsigned u; } x; x.f = f;
  unsigned r = x.u + 0x7fff + ((x.u >> 16) & 1);
  return (unsigned short)(r >> 16);
}
__device__ __forceinline__ float uplo(unsigned u) {
  union { unsigned u; float f; } x; x.u = u << 16; return x.f;
}
__device__ __forceinline__ float uphi(unsigned u) {
  union { unsigned u; float f; } x; x.u = u & 0xffff0000u; return x.f;
}
__device__ __forceinline__ unsigned short f2h(float f) {
  union { _Float16 h; unsigned short s; } x; x.h = (_Float16)f; return x.s;
}
__device__ __forceinline__ unsigned packh(float a, float b) {
  return (unsigned)f2h(a) | ((unsigned)f2h(b) << 16);
}
__device__ __forceinline__ float hlo(unsigned u) {
  union { unsigned short s; _Float16 h; } x; x.s = (unsigned short)(u & 0xffff);
  return (float)x.h;
}
__device__ __forceinline__ float hhi(unsigned u) {
  union { unsigned short s; _Float16 h; } x; x.s = (unsigned short)(u >> 16);
  return (float)x.h;
}
__device__ __forceinline__ float fdot2u(unsigned a, unsigned b, float c) {
#if __has_builtin(__builtin_amdgcn_fdot2)
  union U { unsigned u; h16x2 h; };
  U x, y; x.u = a; y.u = b;
  return __builtin_amdgcn_fdot2(x.h, y.h, c, false);
#else
  return c + hlo(a) * hlo(b) + hhi(a) * hhi(b);
#endif
}
__device__ __forceinline__ float sigf(float x) { return 1.f / (1.f + expf(-x)); }

// async 16B global->LDS; LDS base wave-uniform (+ lane*16 implicit).
__device__ __forceinline__ void gl2lds16(const void* g, void* l) {
  __builtin_amdgcn_global_load_lds(
      (const __attribute__((address_space(1))) unsigned int*)g,
      (__attribute__((address_space(3))) unsigned int*)l, 16, 0, 0);
}

// ---------------------------------------------------------------------------
// weight conversion: bf16 for MFMA GEMMs, f16 for the s2s tail.
// aiw 294912 | aow 98304 | w1 1572864 | w2 1572864 (bf16)
// | wih 131072 | whh 65536 | mwih 131072 (f16)   -> total 3866624
// ---------------------------------------------------------------------------
__global__ __launch_bounds__(256) void convw_kernel(
    const float* __restrict__ aiw, const float* __restrict__ aow,
    const float* __restrict__ w1, const float* __restrict__ w2,
    const float* __restrict__ wih, const float* __restrict__ whh,
    const float* __restrict__ mwih,
    unsigned short* __restrict__ o0, unsigned short* __restrict__ o1,
    unsigned short* __restrict__ o2, unsigned short* __restrict__ o3,
    unsigned short* __restrict__ o4, unsigned short* __restrict__ o5,
    unsigned short* __restrict__ o6) {
  int i = blockIdx.x * 256 + threadIdx.x;
  if (i < 294912) {
    o0[i] = f2bf(aiw[i]);
  } else if (i < 393216) {
    int j = i - 294912; o1[j] = f2bf(aow[j]);
  } else if (i < 1966080) {
    int j = i - 393216; o2[j] = f2bf(w1[j]);
  } else if (i < 3538944) {
    int j = i - 1966080; o3[j] = f2bf(w2[j]);
  } else if (i < 3670016) {
    int j = i - 3538944; o4[j] = f2h(wih[j]);
  } else if (i < 3735552) {
    int j = i - 3670016; o5[j] = f2h(whh[j]);
  } else {
    int j = i - 3735552; o6[j] = f2h(mwih[j]);
  }
}

// ---------------------------------------------------------------------------
// lin0: x = relu(data @ w^T + b), writes fp32 x and bf16 xb
// ---------------------------------------------------------------------------
__global__ __launch_bounds__(256) void lin0_kernel(
    const float* __restrict__ data, const float* __restrict__ w,
    const float* __restrict__ b, float* __restrict__ x,
    unsigned short* __restrict__ xb) {
  int i = blockIdx.x * 256 + threadIdx.x;
  int n = i >> 7, d = i & 127;
  float v = b[d] + data[n * 3 + 0] * w[d * 3 + 0]
                 + data[n * 3 + 1] * w[d * 3 + 1]
                 + data[n * 3 + 2] * w[d * 3 + 2];
  v = fmaxf(v, 0.0f);
  x[i] = v;
  xb[i] = f2bf(v);
}

// ---------------------------------------------------------------------------
// Fused transformer LAYER: block = atom b (256 blocks), 512 threads, 8 waves.
// Block b owns rows {s*256+b, s=0..63} for BOTH attention and FFN:
//   qkv GEMM -> per-head MFMA attention -> ao@Wout + resid + LN1 (regs+Xs)
//   -> ff1+relu -> ff2 + register-residual + LN2 -> global.
// LDS overlays: Ws 64KB (Wqk / P-bufs / W1 dbuf), U1 32KB (Q,K / W2),
// U2 32KB (VT,AO / Hs), Xs 16KB (x tile, then LN1 output).
// ---------------------------------------------------------------------------
__global__ __launch_bounds__(512) void layer_kernel(
    const unsigned short* __restrict__ xbg,
    const unsigned short* __restrict__ wqkv, const float* __restrict__ bqkv,
    const unsigned short* __restrict__ wout, const float* __restrict__ bout,
    const float* __restrict__ ln1g, const float* __restrict__ ln1b,
    const unsigned short* __restrict__ w1, const float* __restrict__ b1,
    const unsigned short* __restrict__ w2, const float* __restrict__ b2,
    const float* __restrict__ ln2g, const float* __restrict__ ln2b,
    float* __restrict__ xio, unsigned short* __restrict__ xbo) {
  __shared__ __align__(16) unsigned short Xs[64 * 128];   // 16 KB
  __shared__ __align__(16) unsigned short Ws[256 * 128];  // 64 KB
  __shared__ __align__(16) unsigned short U1[128 * 128];  // 32 KB
  __shared__ __align__(16) unsigned short U2[128 * 128];  // 32 KB
  __shared__ __align__(16) uint4 zchunk;
  __shared__ float psum[8][64], psq[8][64];
  __shared__ float2 stats[64];

  unsigned short* Qs = U1;            // 64x128
  unsigned short* Ks2 = U1 + 8192;    // 64x128
  unsigned short* VT = U2;            // 128x64
  unsigned short* AOs = U2 + 8192;    // 64x128
  unsigned short* Hs = U2;            // 64x136 (FFN)

  int tid = threadIdx.x, w = tid >> 6, lane = tid & 63;
  int b = blockIdx.x;
  int r4 = lane >> 4, cs = lane & 15;
  int fr = lane & 15, fq = lane >> 4;

  if (tid == 0) zchunk = make_uint4(0u, 0u, 0u, 0u);

  // ---- phase 0: stage x tile + Wq+Wk (wqkv rows 0..255) ----
#pragma unroll
  for (int i = 0; i < 2; i++) {
    int issue = w * 2 + i;
    int row = issue * 4 + r4;  // s index
    int g = cs ^ (row & 7);
    gl2lds16(xbg + (size_t)(row * 256 + b) * 128 + g * 8,
             (char*)Xs + issue * 1024);
  }
#pragma unroll
  for (int i = 0; i < 8; i++) {
    int issue = w * 8 + i;
    int row = issue * 4 + r4;
    int g = cs ^ (row & 7);
    gl2lds16(wqkv + (size_t)row * 128 + g * 8, (char*)Ws + issue * 1024);
  }
  __syncthreads();

  // ---- phase 1: Q,K = x @ Wqk^T + bias -> Qs/Ks2 ----
  {
    f32x4 acc[4][2];
#pragma unroll
    for (int i = 0; i < 4; i++)
#pragma unroll
      for (int j = 0; j < 2; j++) acc[i][j] = (f32x4){0.f, 0.f, 0.f, 0.f};
#pragma unroll
    for (int ks = 0; ks < 4; ks++) {
      bf16x8 af[4], bf[2];
#pragma unroll
      for (int mi = 0; mi < 4; mi++) {
        int row = mi * 16 + fr;
        int kq = (ks * 4 + fq) ^ (row & 7);
        af[mi] = *(const bf16x8*)(Xs + row * 128 + kq * 8);
      }
#pragma unroll
      for (int ni = 0; ni < 2; ni++) {
        int wr = (w * 2 + ni) * 16 + fr;
        int kq = (ks * 4 + fq) ^ (wr & 7);
        bf[ni] = *(const bf16x8*)(Ws + wr * 128 + kq * 8);
      }
#pragma unroll
      for (int mi = 0; mi < 4; mi++)
#pragma unroll
        for (int ni = 0; ni < 2; ni++)
          acc[mi][ni] = __builtin_amdgcn_mfma_f32_16x16x32_bf16(
              af[mi], bf[ni], acc[mi][ni], 0, 0, 0);
    }
#pragma unroll
    for (int ni = 0; ni < 2; ni++) {
      int c = (w * 2 + ni) * 16 + fr;  // 0..255
      float bv = bqkv[c];
      unsigned short* dst = (c < 128) ? Qs : Ks2;
      int cc = c & 127;
#pragma unroll
      for (int mi = 0; mi < 4; mi++)
#pragma unroll
        for (int r = 0; r < 4; r++) {
          int row = mi * 16 + fq * 4 + r;
          dst[row * 128 + (((cc >> 3) ^ (row & 7)) << 3) + (cc & 7)] =
              f2bf(acc[mi][ni][r] + bv);
        }
    }
  }
  __syncthreads();

  // ---- stage Wv (wqkv rows 256..383) into Ws rows 0..127 ----
#pragma unroll
  for (int i = 0; i < 4; i++) {
    int issue = w * 4 + i;
    int row = issue * 4 + r4;
    int g = cs ^ (row & 7);
    gl2lds16(wqkv + (size_t)(256 + row) * 128 + g * 8, (char*)Ws + issue * 1024);
  }
  __syncthreads();

  // ---- phase 2: V = x @ Wv^T + bias -> VT[feature][s] ----
  {
    f32x4 acc[4];
#pragma unroll
    for (int i = 0; i < 4; i++) acc[i] = (f32x4){0.f, 0.f, 0.f, 0.f};
#pragma unroll
    for (int ks = 0; ks < 4; ks++) {
      bf16x8 af[4], bf;
#pragma unroll
      for (int mi = 0; mi < 4; mi++) {
        int row = mi * 16 + fr;
        int kq = (ks * 4 + fq) ^ (row & 7);
        af[mi] = *(const bf16x8*)(Xs + row * 128 + kq * 8);
      }
      {
        int wr = w * 16 + fr;
        int kq = (ks * 4 + fq) ^ (wr & 7);
        bf = *(const bf16x8*)(Ws + wr * 128 + kq * 8);
      }
#pragma unroll
      for (int mi = 0; mi < 4; mi++)
        acc[mi] = __builtin_amdgcn_mfma_f32_16x16x32_bf16(af[mi], bf, acc[mi],
                                                          0, 0, 0);
    }
    int f = w * 16 + fr;
    float bv = bqkv[256 + f];
#pragma unroll
    for (int mi = 0; mi < 4; mi++)
#pragma unroll
      for (int r = 0; r < 4; r++) {
        int srow = mi * 16 + fq * 4 + r;
        VT[f * 64 + (((srow >> 3) ^ (f & 7)) << 3) + (srow & 7)] =
            f2bf(acc[mi][r] + bv);
      }
  }
  __syncthreads();

  // ---- phase 3: per-wave head attention (head h = w), P in Ws ----
  {
    int h = w;
    unsigned short* Pb = Ws + w * 4096;  // 8 KB per wave
    f32x4 sc[4][4];
#pragma unroll
    for (int i = 0; i < 4; i++)
#pragma unroll
      for (int j = 0; j < 4; j++) sc[i][j] = (f32x4){0.f, 0.f, 0.f, 0.f};
    {
      bf16x8 af[4], bf[4];
#pragma unroll
      for (int mi = 0; mi < 4; mi++) {
        int row = mi * 16 + fr;
        const unsigned short* pa =
            (fq < 2) ? (Qs + row * 128 + (((h * 2 + fq) ^ (row & 7)) << 3))
                     : (const unsigned short*)&zchunk;
        af[mi] = *(const bf16x8*)pa;
      }
#pragma unroll
      for (int ti = 0; ti < 4; ti++) {
        int trow = ti * 16 + fr;
        const unsigned short* pb =
            (fq < 2) ? (Ks2 + trow * 128 + (((h * 2 + fq) ^ (trow & 7)) << 3))
                     : (const unsigned short*)&zchunk;
        bf[ti] = *(const bf16x8*)pb;
      }
#pragma unroll
      for (int mi = 0; mi < 4; mi++)
#pragma unroll
        for (int ti = 0; ti < 4; ti++)
          sc[mi][ti] = __builtin_amdgcn_mfma_f32_16x16x32_bf16(
              af[mi], bf[ti], sc[mi][ti], 0, 0, 0);
    }
#pragma unroll
    for (int mi = 0; mi < 4; mi++) {
#pragma unroll
      for (int r = 0; r < 4; r++) {
        float m = -1e30f;
#pragma unroll
        for (int ti = 0; ti < 4; ti++) m = fmaxf(m, sc[mi][ti][r]);
        m = fmaxf(m, __shfl_xor(m, 1, 64));
        m = fmaxf(m, __shfl_xor(m, 2, 64));
        m = fmaxf(m, __shfl_xor(m, 4, 64));
        m = fmaxf(m, __shfl_xor(m, 8, 64));
        m *= 0.25f;
        float ss = 0.f;
#pragma unroll
        for (int ti = 0; ti < 4; ti++) {
          float p = expf(sc[mi][ti][r] * 0.25f - m);
          sc[mi][ti][r] = p;
          ss += p;
        }
        ss += __shfl_xor(ss, 1, 64);
        ss += __shfl_xor(ss, 2, 64);
        ss += __shfl_xor(ss, 4, 64);
        ss += __shfl_xor(ss, 8, 64);
        float inv = 1.f / ss;
        int prow = mi * 16 + fq * 4 + r;
#pragma unroll
        for (int ti = 0; ti < 4; ti++) {
          int t = ti * 16 + fr;
          Pb[prow * 64 + (((t >> 3) ^ (prow & 7)) << 3) + (t & 7)] =
              f2bf(sc[mi][ti][r] * inv);
        }
      }
    }
    // PV
    f32x4 po[4];
#pragma unroll
    for (int i = 0; i < 4; i++) po[i] = (f32x4){0.f, 0.f, 0.f, 0.f};
#pragma unroll
    for (int ks2 = 0; ks2 < 2; ks2++) {
      bf16x8 af[4], bf;
#pragma unroll
      for (int si = 0; si < 4; si++) {
        int prow = si * 16 + fr;
        int kq = (ks2 * 4 + fq) ^ (prow & 7);
        af[si] = *(const bf16x8*)(Pb + prow * 64 + kq * 8);
      }
      {
        int vrow = h * 16 + fr;
        int kq = (ks2 * 4 + fq) ^ (vrow & 7);
        bf = *(const bf16x8*)(VT + vrow * 64 + kq * 8);
      }
#pragma unroll
      for (int si = 0; si < 4; si++)
        po[si] = __builtin_amdgcn_mfma_f32_16x16x32_bf16(af[si], bf, po[si],
                                                         0, 0, 0);
    }
#pragma unroll
    for (int si = 0; si < 4; si++)
#pragma unroll
      for (int r = 0; r < 4; r++) {
        int arow = si * 16 + fq * 4 + r;
        int c = h * 16 + fr;
        AOs[arow * 128 + (((c >> 3) ^ (arow & 7)) << 3) + (c & 7)] =
            f2bf(po[si][r]);
      }
  }
  __syncthreads();

  // ---- stage Wout into Ws rows 0..127 ----
#pragma unroll
  for (int i = 0; i < 4; i++) {
    int issue = w * 4 + i;
    int row = issue * 4 + r4;
    int g = cs ^ (row & 7);
    gl2lds16(wout + (size_t)row * 128 + g * 8, (char*)Ws + issue * 1024);
  }
  __syncthreads();

  // ---- phase 4: v = x + ao @ Wout^T + bias ; LN1 -> regs + Xs ----
  float vvl[4][4];  // LN1 output, this thread's (row=si*16+fq*4+r, col=w*16+fr)
  {
    f32x4 acc[4];
#pragma unroll
    for (int i = 0; i < 4; i++) acc[i] = (f32x4){0.f, 0.f, 0.f, 0.f};
#pragma unroll
    for (int ks = 0; ks < 4; ks++) {
      bf16x8 af[4], bf;
#pragma unroll
      for (int si = 0; si < 4; si++) {
        int row = si * 16 + fr;
        int kq = (ks * 4 + fq) ^ (row & 7);
        af[si] = *(const bf16x8*)(AOs + row * 128 + kq * 8);
      }
      {
        int wr = w * 16 + fr;
        int kq = (ks * 4 + fq) ^ (wr & 7);
        bf = *(const bf16x8*)(Ws + wr * 128 + kq * 8);
      }
#pragma unroll
      for (int si = 0; si < 4; si++)
        acc[si] = __builtin_amdgcn_mfma_f32_16x16x32_bf16(af[si], bf, acc[si],
                                                          0, 0, 0);
    }
    int c = w * 16 + fr;
    float bv = bout[c];
    float sums[4][4], sqs[4][4];
#pragma unroll
    for (int si = 0; si < 4; si++)
#pragma unroll
      for (int r = 0; r < 4; r++) {
        int row = si * 16 + fq * 4 + r;
        float v = acc[si][r] + bv + xio[(size_t)(row * 256 + b) * 128 + c];
        vvl[si][r] = v;
        sums[si][r] = v;
        sqs[si][r] = v * v;
      }
#pragma unroll
    for (int d = 1; d < 16; d <<= 1) {
#pragma unroll
      for (int si = 0; si < 4; si++)
#pragma unroll
        for (int r = 0; r < 4; r++) {
          sums[si][r] += __shfl_xor(sums[si][r], d, 64);
          sqs[si][r] += __shfl_xor(sqs[si][r], d, 64);
        }
    }
    if (fr == 0) {
#pragma unroll
      for (int si = 0; si < 4; si++)
#pragma unroll
        for (int r = 0; r < 4; r++) {
          int row = si * 16 + fq * 4 + r;
          psum[w][row] = sums[si][r];
          psq[w][row] = sqs[si][r];
        }
    }
    __syncthreads();
    if (tid < 64) {
      float S = 0.f, Q = 0.f;
#pragma unroll
      for (int ww = 0; ww < 8; ww++) { S += psum[ww][tid]; Q += psq[ww][tid]; }
      float m = S * (1.f / 128.f);
      float var = Q * (1.f / 128.f) - m * m;
      stats[tid] = make_float2(m, rsqrtf(var + 1e-5f));
    }
    __syncthreads();
    float gl = ln1g[c], bl = ln1b[c];
#pragma unroll
    for (int si = 0; si < 4; si++)
#pragma unroll
      for (int r = 0; r < 4; r++) {
        int row = si * 16 + fq * 4 + r;
        float2 st = stats[row];
        float y = (vvl[si][r] - st.x) * st.y * gl + bl;
        vvl[si][r] = y;  // residual for LN2, stays in regs
        Xs[row * 128 + (((c >> 3) ^ (row & 7)) << 3) + (c & 7)] = f2bf(y);
      }
  }

  // ---- FFN prologue: stage W1(0)->Ws buf0, W2(0)->U1 ----
#pragma unroll
  for (int i = 0; i < 4; i++) {
    int issue = w * 4 + i;
    int row = issue * 4 + r4;
    int g = cs ^ (row & 7);
    gl2lds16(w1 + (size_t)row * 128 + g * 8, (char*)Ws + issue * 1024);
    gl2lds16(w2 + (size_t)row * 2048 + g * 8, (char*)U1 + issue * 1024);
  }
  __syncthreads();  // publishes Xs; drains W1(0)/W2(0)

  // ---- FFN chunk loop: 16 chunks of 128 hidden, 8 waves x 16 cols ----
  f32x4 acc2[4];
#pragma unroll
  for (int i = 0; i < 4; i++) acc2[i] = (f32x4){0.f, 0.f, 0.f, 0.f};

  for (int c = 0; c < 16; c++) {
    const unsigned short* W1cur = Ws + (c & 1) * 16384;
    // ff1: wave w -> hidden cols [w*16, w*16+16)
    f32x4 acc1[4];
#pragma unroll
    for (int i = 0; i < 4; i++) acc1[i] = (f32x4){0.f, 0.f, 0.f, 0.f};
#pragma unroll
    for (int ks = 0; ks < 4; ks++) {
      bf16x8 af[4], bf;
#pragma unroll
      for (int mi = 0; mi < 4; mi++) {
        int row = mi * 16 + fr;
        int kq = (ks * 4 + fq) ^ (row & 7);
        af[mi] = *(const bf16x8*)(Xs + row * 128 + kq * 8);
      }
      {
        int row = w * 16 + fr;
        int kq = (ks * 4 + fq) ^ (row & 7);
        bf = *(const bf16x8*)(W1cur + row * 128 + kq * 8);
      }
#pragma unroll
      for (int mi = 0; mi < 4; mi++)
        acc1[mi] = __builtin_amdgcn_mfma_f32_16x16x32_bf16(af[mi], bf, acc1[mi],
                                                           0, 0, 0);
    }
    // prefetch W1(c+1)
    if (c < 15) {
#pragma unroll
      for (int i = 0; i < 4; i++) {
        int issue = w * 4 + i;
        int row = issue * 4 + r4;
        int g = cs ^ (row & 7);
        gl2lds16(w1 + (size_t)((c + 1) * 128 + row) * 128 + g * 8,
                 (char*)Ws + ((c + 1) & 1) * 32768 + issue * 1024);
      }
    }
    // bias + relu -> Hs
    {
      int col = w * 16 + fr;
      float bv = b1[c * 128 + col];
#pragma unroll
      for (int mi = 0; mi < 4; mi++)
#pragma unroll
        for (int r = 0; r < 4; r++) {
          int row = mi * 16 + fq * 4 + r;
          Hs[row * 136 + col] = f2bf(fmaxf(acc1[mi][r] + bv, 0.f));
        }
    }
    __syncthreads();  // B1: Hs visible; drains W2(c)/W1(c+1)

    // ff2: wave w -> out cols [w*16, w*16+16)
#pragma unroll
    for (int ks = 0; ks < 4; ks++) {
      bf16x8 af[4], bf;
#pragma unroll
      for (int si = 0; si < 4; si++) {
        int row = si * 16 + fr;
        af[si] = *(const bf16x8*)(Hs + row * 136 + ks * 32 + fq * 8);
      }
      {
        int row = w * 16 + fr;
        int kq = (ks * 4 + fq) ^ (row & 7);
        bf = *(const bf16x8*)(U1 + row * 128 + kq * 8);
      }
#pragma unroll
      for (int si = 0; si < 4; si++)
        acc2[si] = __builtin_amdgcn_mfma_f32_16x16x32_bf16(af[si], bf, acc2[si],
                                                           0, 0, 0);
    }
    __syncthreads();  // B2: U1/Hs reusable
    // stage W2(c+1) (overlaps next ff1)
    if (c < 15) {
#pragma unroll
      for (int i = 0; i < 4; i++) {
        int issue = w * 4 + i;
        int row = issue * 4 + r4;
        int g = cs ^ (row & 7);
        gl2lds16(w2 + (size_t)row * 2048 + (c + 1) * 128 + g * 8,
                 (char*)U1 + issue * 1024);
      }
    }
  }

  // ---- FFN epilogue: +b2 + register residual, LN2, write global ----
  {
    int c = w * 16 + fr;
    float bv = b2[c];
    float sums[4][4], sqs[4][4];
#pragma unroll
    for (int si = 0; si < 4; si++)
#pragma unroll
      for (int r = 0; r < 4; r++) {
        float v = acc2[si][r] + bv + vvl[si][r];
        vvl[si][r] = v;
        sums[si][r] = v;
        sqs[si][r] = v * v;
      }
#pragma unroll
    for (int d = 1; d < 16; d <<= 1) {
#pragma unroll
      for (int si = 0; si < 4; si++)
#pragma unroll
        for (int r = 0; r < 4; r++) {
          sums[si][r] += __shfl_xor(sums[si][r], d, 64);
          sqs[si][r] += __shfl_xor(sqs[si][r], d, 64);
        }
    }
    if (fr == 0) {
#pragma unroll
      for (int si = 0; si < 4; si++)
#pragma unroll
        for (int r = 0; r < 4; r++) {
          int row = si * 16 + fq * 4 + r;
          psum[w][row] = sums[si][r];
          psq[w][row] = sqs[si][r];
        }
    }
    __syncthreads();
    if (tid < 64) {
      float S = 0.f, Q = 0.f;
#pragma unroll
      for (int ww = 0; ww < 8; ww++) { S += psum[ww][tid]; Q += psq[ww][tid]; }
      float m = S * (1.f / 128.f);
      float var = Q * (1.f / 128.f) - m * m;
      stats[tid] = make_float2(m, rsqrtf(var + 1e-5f));
    }
    __syncthreads();
    float gl = ln2g[c], bl = ln2b[c];
#pragma unroll
    for (int si = 0; si < 4; si++)
#pragma unroll
      for (int r = 0; r < 4; r++) {
        int row = si * 16 + fq * 4 + r;
        float2 st = stats[row];
        float y = (vvl[si][r] - st.x) * st.y * gl + bl;
        size_t o = (size_t)(row * 256 + b) * 128 + c;
        xio[o] = y;
        xbo[o] = f2bf(y);
      }
  }
}

// ---------------------------------------------------------------------------
// Set2Set (6 steps) + memory LSTM + lin1 + lin3. One 512-thread block per
// segment (64 blocks -> 1/CU). __launch_bounds__(512,1): 256-VGPR cap so the
// 48 uint4 of gate weights STAY in registers (R6's (512,2) capped at 128 and
// spilled them -> L2 reload every step).
// ---------------------------------------------------------------------------
__global__ __launch_bounds__(512, 1) void s2s_kernel(
    const unsigned short* __restrict__ xb,
    const unsigned short* __restrict__ wihh,
    const unsigned short* __restrict__ whhh,
    const float* __restrict__ bih, const float* __restrict__ bhh,
    const unsigned short* __restrict__ mwihh,
    const float* __restrict__ mbih, const float* __restrict__ mbhh,
    const float* __restrict__ l1w, const float* __restrict__ l1b,
    const float* __restrict__ l3w, const float* __restrict__ l3b,
    float* __restrict__ out) {
  __shared__ __align__(16) unsigned xl[256 * 65];
  __shared__ __align__(16) unsigned qu[128];
  __shared__ __align__(16) float cst[128];
  __shared__ __align__(16) float gates[512];
  __shared__ __align__(16) float red[256];
  __shared__ __align__(16) float aw[256];
  int s = blockIdx.x, t = threadIdx.x, lane = t & 63, w = t >> 6;

  uint4 wreg[32], ureg[16];
  {
    const uint4* wp = (const uint4*)(wihh + (size_t)t * 256);
#pragma unroll
    for (int i = 0; i < 32; i++) wreg[i] = wp[i];
    const uint4* up = (const uint4*)(whhh + (size_t)t * 128);
#pragma unroll
    for (int i = 0; i < 16; i++) ureg[i] = up[i];
  }

  const uint4* xs4 = (const uint4*)(xb + (size_t)s * 32768);
#pragma unroll
  for (int it = 0; it < 8; it++) {
    int f = it * 512 + t;
    uint4 v = xs4[f];
    int n = f >> 4, jc = (f & 15) * 4;
    unsigned* dst = xl + n * 65 + jc;
    dst[0] = packh(uplo(v.x), uphi(v.x));
    dst[1] = packh(uplo(v.y), uphi(v.y));
    dst[2] = packh(uplo(v.z), uphi(v.z));
    dst[3] = packh(uplo(v.w), uphi(v.w));
  }
  if (t < 128) cst[t] = 0.f;
  __syncthreads();

  const uint4* q4 = (const uint4*)qu;
  float bsum = bih[t] + bhh[t];

  for (int step = 0; step < 6; step++) {
    if (step > 0) {
      float a0 = 0.f, a1 = 0.f, a2 = 0.f, a3 = 0.f;
#pragma unroll
      for (int i = 0; i < 16; i++) {
        uint4 qv = q4[i];
        a0 = fdot2u(wreg[i].x, qv.x, a0);
        a1 = fdot2u(wreg[i].y, qv.y, a1);
        a2 = fdot2u(wreg[i].z, qv.z, a2);
        a3 = fdot2u(wreg[i].w, qv.w, a3);
        a0 = fdot2u(ureg[i].x, qv.x, a0);
        a1 = fdot2u(ureg[i].y, qv.y, a1);
        a2 = fdot2u(ureg[i].z, qv.z, a2);
        a3 = fdot2u(ureg[i].w, qv.w, a3);
      }
#pragma unroll
      for (int i = 16; i < 32; i++) {
        uint4 qv = q4[i];
        a0 = fdot2u(wreg[i].x, qv.x, a0);
        a1 = fdot2u(wreg[i].y, qv.y, a1);
        a2 = fdot2u(wreg[i].z, qv.z, a2);
        a3 = fdot2u(wreg[i].w, qv.w, a3);
      }
      gates[t] = bsum + ((a0 + a1) + (a2 + a3));
    } else {
      gates[t] = bsum;
    }
    __syncthreads();
    if (t < 128) {
      float ig = sigf(gates[t]), fg = sigf(gates[128 + t]);
      float gg = tanhf(gates[256 + t]), og = sigf(gates[384 + t]);
      float cn = fg * cst[t] + ig * gg;
      cst[t] = cn;
      float hn = og * tanhf(cn);
      float hp = __shfl_xor(hn, 1, 64);
      if ((t & 1) == 0) qu[t >> 1] = packh(hn, hp);
    }
    __syncthreads();
    if (step > 0) {
      int n = t >> 1, p = t & 1;
      const unsigned* xr = xl + n * 65 + p * 32;
      float e0 = 0.f, e1 = 0.f;
#pragma unroll 8
      for (int i = 0; i < 32; i += 2) {
        e0 = fdot2u(xr[i], qu[p * 32 + i], e0);
        e1 = fdot2u(xr[i + 1], qu[p * 32 + i + 1], e1);
      }
      float e = e0 + e1;
      e += __shfl_xor(e, 1, 64);
      if (p == 0) red[n] = e;
      __syncthreads();
      float v0 = red[lane], v1 = red[64 + lane];
      float v2 = red[128 + lane], v3 = red[192 + lane];
      float m = fmaxf(fmaxf(v0, v1), fmaxf(v2, v3));
#pragma unroll
      for (int d = 1; d < 64; d <<= 1) m = fmaxf(m, __shfl_xor(m, d, 64));
      float p0 = expf(v0 - m), p1 = expf(v1 - m);
      float p2 = expf(v2 - m), p3 = expf(v3 - m);
      float ss = p0 + p1 + p2 + p3;
#pragma unroll
      for (int d = 1; d < 64; d <<= 1) ss += __shfl_xor(ss, d, 64);
      float Sinv = 1.f / ss;
      if (w == 0) {
        aw[lane] = p0 * Sinv; aw[64 + lane] = p1 * Sinv;
        aw[128 + lane] = p2 * Sinv; aw[192 + lane] = p3 * Sinv;
      }
    } else {
      if (t < 256) aw[t] = 1.f / 256.f;
    }
    __syncthreads();
    {
      int d = t & 127, grp = t >> 7;
      const unsigned* xc = xl + grp * 64 * 65 + (d >> 1);
      int hi = d & 1;
      const float* ap = aw + grp * 64;
      float r = 0.f;
#pragma unroll 8
      for (int n2 = 0; n2 < 64; n2++) {
        unsigned u = xc[n2 * 65];
        r += ap[n2] * (hi ? hhi(u) : hlo(u));
      }
      gates[t] = r;
    }
    __syncthreads();
    if (t < 128) {
      float rd = gates[t] + gates[128 + t] + gates[256 + t] + gates[384 + t];
      float rp = __shfl_xor(rd, 1, 64);
      if ((t & 1) == 0) qu[64 + (t >> 1)] = packh(rd, rp);
    }
    __syncthreads();
  }
  {
    float a0 = 0.f, a1 = 0.f, a2 = 0.f, a3 = 0.f;
    const uint4* mp = (const uint4*)(mwihh + (size_t)t * 256);
#pragma unroll 8
    for (int i = 0; i < 32; i++) {
      uint4 wv = mp[i], qv = q4[i];
      a0 = fdot2u(wv.x, qv.x, a0);
      a1 = fdot2u(wv.y, qv.y, a1);
      a2 = fdot2u(wv.z, qv.z, a2);
      a3 = fdot2u(wv.w, qv.w, a3);
    }
    gates[t] = mbih[t] + mbhh[t] + ((a0 + a1) + (a2 + a3));
  }
  __syncthreads();
  if (t < 128) {
    float ig = sigf(gates[t]);
    float gg = tanhf(gates[256 + t]);
    float og = sigf(gates[384 + t]);
    float cx = ig * gg;
    float hx = og * tanhf(cx);
    cst[t] = hx;
    out[64 + s * 128 + t] = hx;
    out[64 + 8192 + s * 128 + t] = cx;
  }
  __syncthreads();
  if (t < 128) {
    float acc = l1b[t];
    const float4* w4 = (const float4*)(l1w + (size_t)t * 128);
    const float4* h4 = (const float4*)cst;
#pragma unroll 8
    for (int k = 0; k < 32; k++) {
      float4 a = w4[k], b = h4[k];
      acc += a.x * b.x + a.y * b.y + a.z * b.z + a.w * b.w;
    }
    red[t] = fmaxf(acc, 0.f) * l3w[t];
  } else if (t < 256) {
    red[t] = 0.f;
  }
  __syncthreads();
  for (int off = 128; off; off >>= 1) {
    if (t < off) red[t] += red[t + off];
    __syncthreads();
  }
  if (t == 0) out[s] = red[0] + l3b[0];
}

// ---------------------------------------------------------------------------
extern "C" void kernel_launch(void* const* d_in, const int* in_sizes, int n_in,
                              void* d_out, int out_size, void* d_ws,
                              size_t ws_size, hipStream_t stream) {
  const float* data       = (const float*)d_in[0];
  const float* lin0_w     = (const float*)d_in[1];
  const float* lin0_b     = (const float*)d_in[2];
  const float* attn_in_w  = (const float*)d_in[3];
  const float* attn_in_b  = (const float*)d_in[4];
  const float* attn_out_w = (const float*)d_in[5];
  const float* attn_out_b = (const float*)d_in[6];
  const float* ln1_g      = (const float*)d_in[7];
  const float* ln1_b      = (const float*)d_in[8];
  const float* ff_w1      = (const float*)d_in[9];
  const float* ff_b1      = (const float*)d_in[10];
  const float* ff_w2      = (const float*)d_in[11];
  const float* ff_b2      = (const float*)d_in[12];
  const float* ln2_g      = (const float*)d_in[13];
  const float* ln2_b      = (const float*)d_in[14];
  const float* s2s_wih    = (const float*)d_in[15];
  const float* s2s_whh    = (const float*)d_in[16];
  const float* s2s_bih    = (const float*)d_in[17];
  const float* s2s_bhh    = (const float*)d_in[18];
  const float* mem_wih    = (const float*)d_in[19];
  const float* mem_bih    = (const float*)d_in[21];
  const float* mem_bhh    = (const float*)d_in[22];
  const float* lin1_w     = (const float*)d_in[23];
  const float* lin1_b     = (const float*)d_in[24];
  const float* lin3_w     = (const float*)d_in[25];
  const float* lin3_b     = (const float*)d_in[26];
  float* out = (float*)d_out;

  char* p = (char*)d_ws;
  float* x = (float*)p;                      p += (size_t)16384 * 128 * 4;
  unsigned short* xb = (unsigned short*)p;   p += (size_t)16384 * 128 * 2;
  unsigned short* wqkv = (unsigned short*)p; p += (size_t)294912 * 2;
  unsigned short* wout = (unsigned short*)p; p += (size_t)98304 * 2;
  unsigned short* w1b = (unsigned short*)p;  p += (size_t)1572864 * 2;
  unsigned short* w2b = (unsigned short*)p;  p += (size_t)1572864 * 2;
  unsigned short* wihh = (unsigned short*)p; p += (size_t)131072 * 2;
  unsigned short* whhh = (unsigned short*)p; p += (size_t)65536 * 2;
  unsigned short* mwihh = (unsigned short*)p; p += (size_t)131072 * 2;

  convw_kernel<<<15104, 256, 0, stream>>>(
      attn_in_w, attn_out_w, ff_w1, ff_w2, s2s_wih, s2s_whh, mem_wih,
      wqkv, wout, w1b, w2b, wihh, whhh, mwihh);
  lin0_kernel<<<8192, 256, 0, stream>>>(data, lin0_w, lin0_b, x, xb);

  for (int l = 0; l < 6; l++) {
    layer_kernel<<<256, 512, 0, stream>>>(
        xb, wqkv + (size_t)l * 49152, attn_in_b + l * 384,
        wout + (size_t)l * 16384, attn_out_b + l * 128,
        ln1_g + l * 128, ln1_b + l * 128,
        w1b + (size_t)l * 262144, ff_b1 + l * 2048,
        w2b + (size_t)l * 262144, ff_b2 + l * 128,
        ln2_g + l * 128, ln2_b + l * 128, x, xb);
  }

  s2s_kernel<<<64, 512, 0, stream>>>(
      xb, wihh, whhh, s2s_bih, s2s_bhh,
      mwihh, mem_bih, mem_bhh, lin1_w, lin1_b, lin3_w, lin3_b, out);
}